// Round 2
// 1120.451 us; speedup vs baseline: 1.0061x; 1.0061x over previous
//
#include <hip/hip_runtime.h>
#include <math.h>

typedef __attribute__((ext_vector_type(8))) short bf16x8;
typedef __attribute__((ext_vector_type(4))) float f32x4;

// ---------- bf16 helpers ----------
__device__ __forceinline__ float bf2f(unsigned short u) {
    union { unsigned int i; float f; } c;
    c.i = ((unsigned int)u) << 16;
    return c.f;
}
__device__ __forceinline__ unsigned short f2bf(float f) {
    union { float f; unsigned int i; } c;
    c.f = f;
    unsigned int b = c.i + 0x7FFFu + ((c.i >> 16) & 1u);  // round-nearest-even
    return (unsigned short)(b >> 16);
}
__device__ __forceinline__ float eluf(float v) {   // jax.nn.elu, alpha=1
    return v > 0.f ? v : (__expf(v) - 1.f);
}
__device__ __forceinline__ float lrelu(float v) {  // leaky_relu slope 0.2
    return v >= 0.f ? v : 0.2f * v;
}

// ---------- 0. input dtype detection: 1 = bf16, 0 = f32 ----------
__global__ void detect_kernel(const unsigned int* __restrict__ w, int nwords,
                              int* __restrict__ flag)
{
    __shared__ int cnt_s;
    if (threadIdx.x == 0) cnt_s = 0;
    __syncthreads();
    int sane = 0;
    for (int i = threadIdx.x; i < nwords; i += 256) {
        unsigned int lo = w[i] & 0xffffu;
        int e = (int)((lo >> 7) & 0xffu);
        if (e >= 114 && e <= 136) sane++;
    }
    atomicAdd(&cnt_s, sane);
    __syncthreads();
    if (threadIdx.x == 0) *flag = (2 * cnt_s > nwords) ? 1 : 0;
}

// ---------- 1a. W fragment pre-pack for MFMA (bf16 path only) ----------
// Wfrag chunk ch = (ks*8 + t)*64 + l holds 8 bf16: B[k = ks*32 + (l>>4)*8 + j][col = t*16 + (l&15)]
// where B = [Wsrc | Wdst] (D x 128), row-major per source array (D x 64 each).
__global__ __launch_bounds__(256) void wfrag_kernel(
    const unsigned short* __restrict__ Wsrc, const unsigned short* __restrict__ Wdst,
    const int* __restrict__ flag, unsigned short* __restrict__ Wfrag)
{
    if (!*flag) return;
    const int nch = 8 * 8 * 64;   // D=256 -> 8 K-steps
    for (int ch = blockIdx.x * 256 + threadIdx.x; ch < nch; ch += gridDim.x * 256) {
        int l  = ch & 63;
        int t  = (ch >> 6) & 7;
        int ks = ch >> 9;
        int col = t * 16 + (l & 15);
        int k0  = ks * 32 + (l >> 4) * 8;
        const unsigned short* W = (col < 64) ? (Wsrc + col) : (Wdst + (col - 64));
#pragma unroll
        for (int j = 0; j < 8; ++j)
            Wfrag[(size_t)ch * 8 + j] = W[(size_t)(k0 + j) * 64];
    }
}

// ---------- 1b. MFMA fused elu+GEMM+att-projection (bf16 path, D==256, HC==64) ----------
// Block: 256 thr = 4 waves; tile 64 rows x 128 cols; wave w owns rows w*16..w*16+15.
// A frag (16x16x32): row = l&15, k = (l>>4)*8 + j.  B frag: col = l&15, k = (l>>4)*8 + j.
// C/D:  col = l&15, row = (l>>4)*4 + reg   [verified layout, learn_hip m89]
__global__ __launch_bounds__(256) void gemm_mfma_kernel(
    const void* __restrict__ xh, const void* __restrict__ xt,
    const unsigned short* __restrict__ Wfrag,
    const void* __restrict__ att_src, const void* __restrict__ att_dst,
    const int* __restrict__ flag,
    float* __restrict__ P, float* __restrict__ as_all, float* __restrict__ ad_all,
    int N)
{
    if (!*flag) return;
    const unsigned short* xv = (const unsigned short*)((blockIdx.y == 0) ? xh : xt);
    float* Pout = P + (size_t)blockIdx.y * (size_t)N * 128u;
    float* asO  = as_all + (size_t)blockIdx.y * (size_t)N * 2u;
    float* adO  = ad_all + (size_t)blockIdx.y * (size_t)N * 2u;
    const int tid = threadIdx.x;
    const int w   = tid >> 6;
    const int l   = tid & 63;
    const int l15 = l & 15;
    const int lhi = l >> 4;
    const int rowA = blockIdx.x * 64 + w * 16 + l15;
    const bool rv = rowA < N;

    // preload A fragments for all 8 K-steps, elu applied in-register
    bf16x8 a[8];
#pragma unroll
    for (int ks = 0; ks < 8; ++ks) {
        union { bf16x8 v; unsigned int u[4]; } o;
        if (rv) {
            uint4 raw = *(const uint4*)(xv + (size_t)rowA * 256 + ks * 32 + lhi * 8);
            unsigned int wsr[4] = {raw.x, raw.y, raw.z, raw.w};
#pragma unroll
            for (int i = 0; i < 4; ++i) {
                float lo = eluf(bf2f((unsigned short)(wsr[i] & 0xffffu)));
                float hi = eluf(bf2f((unsigned short)(wsr[i] >> 16)));
                o.u[i] = (unsigned int)f2bf(lo) | ((unsigned int)f2bf(hi) << 16);
            }
        } else {
            o.u[0] = o.u[1] = o.u[2] = o.u[3] = 0u;
        }
        a[ks] = o.v;
    }

    f32x4 acc[8];
#pragma unroll
    for (int t = 0; t < 8; ++t) acc[t] = (f32x4){0.f, 0.f, 0.f, 0.f};

    const bf16x8* wf = (const bf16x8*)Wfrag;
#pragma unroll
    for (int ks = 0; ks < 8; ++ks) {
#pragma unroll
        for (int t = 0; t < 8; ++t) {
            bf16x8 b = wf[(ks * 8 + t) * 64 + l];
            acc[t] = __builtin_amdgcn_mfma_f32_16x16x32_bf16(a[ks], b, acc[t], 0, 0, 0);
        }
    }

    // epilogue: store P (f32) + fused att_src/att_dst projections
    float asv[4], adv[4];
#pragma unroll
    for (int t = 0; t < 4; ++t) {
        asv[t] = bf2f(((const unsigned short*)att_src)[t * 16 + l15]);
        adv[t] = bf2f(((const unsigned short*)att_dst)[t * 16 + l15]);
    }
    const int rbase = blockIdx.x * 64 + w * 16 + lhi * 4;
#pragma unroll
    for (int reg = 0; reg < 4; ++reg) {
        int row = rbase + reg;
        bool ok = row < N;
        if (ok) {
            float* p = Pout + (size_t)row * 128 + l15;
#pragma unroll
            for (int t = 0; t < 8; ++t) p[t * 16] = acc[t][reg];
        }
        // head 0: cols 0..31 (tiles 0,1);  head 1: cols 32..63 (tiles 2,3)
        float s0 = acc[0][reg] * asv[0] + acc[1][reg] * asv[1];
        float s1 = acc[2][reg] * asv[2] + acc[3][reg] * asv[3];
        float d0 = acc[4][reg] * adv[0] + acc[5][reg] * adv[1];
        float d1 = acc[6][reg] * adv[2] + acc[7][reg] * adv[3];
#pragma unroll
        for (int o2 = 8; o2 >= 1; o2 >>= 1) {
            s0 += __shfl_xor(s0, o2, 64);
            s1 += __shfl_xor(s1, o2, 64);
            d0 += __shfl_xor(d0, o2, 64);
            d1 += __shfl_xor(d1, o2, 64);
        }
        if (ok && l15 == 0) {
            asO[(size_t)row * 2 + 0] = s0;
            asO[(size_t)row * 2 + 1] = s1;
            adO[(size_t)row * 2 + 0] = d0;
            adO[(size_t)row * 2 + 1] = d1;
        }
    }
}

// ---------- 1c. fallback fused elu + GEMM (f32 path) ----------
__global__ __launch_bounds__(256) void gemm_elu_kernel(
    const void* __restrict__ xh, const void* __restrict__ xt,
    const void* __restrict__ Wsrc, const void* __restrict__ Wdst,
    const int* __restrict__ flag,
    float* __restrict__ P, int N, int D, int skip_bf)
{
    const int isbf = *flag;
    if (skip_bf && isbf) return;   // bf16 handled by MFMA kernel
    __shared__ float xs[64][33];
    __shared__ float wt[32][128];
    const void* xv = (blockIdx.y == 0) ? xh : xt;
    float* Pout = P + (size_t)blockIdx.y * (size_t)N * 128u;
    const int rowBase = blockIdx.x * 64;
    const int tid = threadIdx.x;
    const int tcx = tid & 15;
    const int tcy = tid >> 4;

    float acc[4][8];
#pragma unroll
    for (int r = 0; r < 4; ++r)
#pragma unroll
        for (int c = 0; c < 8; ++c) acc[r][c] = 0.f;

    for (int kc = 0; kc < D; kc += 32) {
        {
            int row = tid >> 2;
            int kq  = (tid & 3) * 8;
            int r = rowBase + row;
            float v[8];
            if (r < N) {
                if (isbf) {
                    const unsigned short* xb = (const unsigned short*)xv;
                    uint4 raw = *(const uint4*)(xb + (size_t)r * D + kc + kq);
                    unsigned int ws[4] = {raw.x, raw.y, raw.z, raw.w};
#pragma unroll
                    for (int i = 0; i < 4; ++i) {
                        v[2 * i]     = bf2f((unsigned short)(ws[i] & 0xffffu));
                        v[2 * i + 1] = bf2f((unsigned short)(ws[i] >> 16));
                    }
                } else {
                    const float* xf = (const float*)xv;
                    const float4* p4 = (const float4*)(xf + (size_t)r * D + kc + kq);
                    float4 f0 = p4[0], f1 = p4[1];
                    v[0] = f0.x; v[1] = f0.y; v[2] = f0.z; v[3] = f0.w;
                    v[4] = f1.x; v[5] = f1.y; v[6] = f1.z; v[7] = f1.w;
                }
#pragma unroll
                for (int i = 0; i < 8; ++i) v[i] = eluf(v[i]);
            } else {
#pragma unroll
                for (int i = 0; i < 8; ++i) v[i] = 0.f;
            }
#pragma unroll
            for (int i = 0; i < 8; ++i) xs[row][kq + i] = v[i];
        }
#pragma unroll
        for (int i = 0; i < 2; ++i) {
            int f = (tid + i * 256) * 8;
            int k = f >> 7;
            int c = f & 127;
            float v[8];
            if (isbf) {
                const unsigned short* Wp = (c < 64)
                    ? ((const unsigned short*)Wsrc + (size_t)(kc + k) * 64 + c)
                    : ((const unsigned short*)Wdst + (size_t)(kc + k) * 64 + (c - 64));
                uint4 raw = *(const uint4*)Wp;
                unsigned int ws[4] = {raw.x, raw.y, raw.z, raw.w};
#pragma unroll
                for (int q = 0; q < 4; ++q) {
                    v[2 * q]     = bf2f((unsigned short)(ws[q] & 0xffffu));
                    v[2 * q + 1] = bf2f((unsigned short)(ws[q] >> 16));
                }
            } else {
                const float* Wp = (c < 64)
                    ? ((const float*)Wsrc + (size_t)(kc + k) * 64 + c)
                    : ((const float*)Wdst + (size_t)(kc + k) * 64 + (c - 64));
                const float4* p4 = (const float4*)Wp;
                float4 f0 = p4[0], f1 = p4[1];
                v[0] = f0.x; v[1] = f0.y; v[2] = f0.z; v[3] = f0.w;
                v[4] = f1.x; v[5] = f1.y; v[6] = f1.z; v[7] = f1.w;
            }
#pragma unroll
            for (int q = 0; q < 8; ++q) wt[k][c + q] = v[q];
        }
        __syncthreads();
#pragma unroll 8
        for (int k = 0; k < 32; ++k) {
            float xr[4];
#pragma unroll
            for (int r = 0; r < 4; ++r) xr[r] = xs[tcy * 4 + r][k];
            float4 w0 = *(const float4*)&wt[k][tcx * 8];
            float4 w1 = *(const float4*)&wt[k][tcx * 8 + 4];
#pragma unroll
            for (int r = 0; r < 4; ++r) {
                acc[r][0] += xr[r] * w0.x; acc[r][1] += xr[r] * w0.y;
                acc[r][2] += xr[r] * w0.z; acc[r][3] += xr[r] * w0.w;
                acc[r][4] += xr[r] * w1.x; acc[r][5] += xr[r] * w1.y;
                acc[r][6] += xr[r] * w1.z; acc[r][7] += xr[r] * w1.w;
            }
        }
        __syncthreads();
    }
#pragma unroll
    for (int r = 0; r < 4; ++r) {
        int row = rowBase + tcy * 4 + r;
        if (row < N) {
            float* p = Pout + (size_t)row * 128 + tcx * 8;
            *(float4*)p       = make_float4(acc[r][0], acc[r][1], acc[r][2], acc[r][3]);
            *(float4*)(p + 4) = make_float4(acc[r][4], acc[r][5], acc[r][6], acc[r][7]);
        }
    }
}

// ---------- 2. per-node attention scalars (f32 fallback path only when skip_bf) ----------
__global__ __launch_bounds__(256) void a_proj_kernel(
    const float* __restrict__ P,
    const void* __restrict__ att_src, const void* __restrict__ att_dst,
    const int* __restrict__ flag,
    float* __restrict__ as_all, float* __restrict__ ad_all, int M, int skip_bf)
{
    const int isbf = *flag;
    if (skip_bf && isbf) return;   // fused into MFMA epilogue
    int lane = threadIdx.x & 63;
    float asv = isbf ? bf2f(((const unsigned short*)att_src)[lane])
                     : ((const float*)att_src)[lane];
    float adv = isbf ? bf2f(((const unsigned short*)att_dst)[lane])
                     : ((const float*)att_dst)[lane];
    int step = (gridDim.x * 256) >> 6;
    for (int wv = (blockIdx.x * 256 + threadIdx.x) >> 6; wv < M; wv += step) {
        const float* row = P + (size_t)wv * 128;
        float vs = row[lane]      * asv;
        float vd = row[64 + lane] * adv;
#pragma unroll
        for (int o = 16; o >= 1; o >>= 1) {
            vs += __shfl_xor(vs, o, 64);
            vd += __shfl_xor(vd, o, 64);
        }
        if ((lane & 31) == 0) {
            int h = lane >> 5;
            as_all[(size_t)wv * 2 + h] = vs;
            ad_all[(size_t)wv * 2 + h] = vd;
        }
    }
}

// ---------- 3a. degree histogram (dir1 by dst, dir2 by src) ----------
__global__ void count_kernel(const int* __restrict__ srce, const int* __restrict__ dste,
                             int* __restrict__ cnt, int N, int E)
{
    int e = blockIdx.x * blockDim.x + threadIdx.x;
    if (e >= E) return;
    atomicAdd(&cnt[dste[e]], 1);
    atomicAdd(&cnt[N + srce[e]], 1);
}

// ---------- 3b. multi-block scan: stage 1 ----------
__global__ __launch_bounds__(256) void scan_bsum_kernel(
    const int* __restrict__ cnt, int M, int chunk, int* __restrict__ bsum)
{
    __shared__ int r[4];
    int beg = blockIdx.x * chunk;
    int end = beg + chunk; if (end > M) end = M;
    int s = 0;
    for (int i = beg + threadIdx.x; i < end; i += 256) s += cnt[i];
#pragma unroll
    for (int o = 32; o >= 1; o >>= 1) s += __shfl_down(s, o, 64);
    int lane = threadIdx.x & 63, wv = threadIdx.x >> 6;
    if (lane == 0) r[wv] = s;
    __syncthreads();
    if (threadIdx.x == 0) bsum[blockIdx.x] = r[0] + r[1] + r[2] + r[3];
}

// ---------- stage 2 ----------
__global__ __launch_bounds__(256) void scan_boff_kernel(
    const int* __restrict__ bsum, int NB, int* __restrict__ boff)
{
    __shared__ int s[256];
    int t = threadIdx.x;
    int v = (t < NB) ? bsum[t] : 0;
    s[t] = v;
    __syncthreads();
    for (int o = 1; o < 256; o <<= 1) {
        int x = (t >= o) ? s[t - o] : 0;
        __syncthreads();
        s[t] += x;
        __syncthreads();
    }
    if (t < NB) boff[t] = s[t] - v;
}

// ---------- stage 3 ----------
__global__ __launch_bounds__(256) void scan_write_kernel(
    const int* __restrict__ cnt, int M, int chunk,
    const int* __restrict__ boff, int* __restrict__ off)
{
    __shared__ int s[256];
    int t = threadIdx.x;
    int beg = blockIdx.x * chunk;
    int end = beg + chunk; if (end > M) end = M;
    if (beg >= M) return;
    int running = boff[blockIdx.x];
    for (int base = beg; base < end; base += 256) {
        int i = base + t;
        int v = (i < end) ? cnt[i] : 0;
        s[t] = v;
        __syncthreads();
        for (int o = 1; o < 256; o <<= 1) {
            int x = (t >= o) ? s[t - o] : 0;
            __syncthreads();
            s[t] += x;
            __syncthreads();
        }
        if (i < end) off[i] = running + s[t] - v;
        int total = s[255];
        __syncthreads();
        running += total;
    }
    if (end == M && t == 0) off[M] = running;
}

// ---------- 3c. CSR fill ----------
__global__ void fill_kernel(const int* __restrict__ srce, const int* __restrict__ dste,
                            const int* __restrict__ off, int* __restrict__ cur,
                            int* __restrict__ idx, int N, int E)
{
    int e = blockIdx.x * blockDim.x + threadIdx.x;
    if (e >= E) return;
    int s = srce[e], d = dste[e];
    int p  = atomicAdd(&cur[d], 1);
    idx[off[d] + p] = s;
    int p2 = atomicAdd(&cur[N + s], 1);
    idx[off[N + s] + p2] = d;
}

// ---------- 4. enrichment softmax sums ----------
__global__ __launch_bounds__(256) void enrich_kernel(
    const void* __restrict__ ew, const int* __restrict__ flag,
    float* __restrict__ S, int E)
{
    __shared__ float r1[4], r2[4];
    const int isbf = *flag;
    float e1 = 0.f, e2 = 0.f;
    for (int i = blockIdx.x * 256 + threadIdx.x; i < E; i += gridDim.x * 256) {
        float c = isbf ? bf2f(((const unsigned short*)ew)[i]) : ((const float*)ew)[i];
        c = fminf(fmaxf(c, 0.3f), 3.0f);
        float ex = __expf(c);
        e1 += ex;
        e2 += c * ex;
    }
#pragma unroll
    for (int o = 32; o >= 1; o >>= 1) {
        e1 += __shfl_down(e1, o, 64);
        e2 += __shfl_down(e2, o, 64);
    }
    int lane = threadIdx.x & 63;
    int wv = threadIdx.x >> 6;
    if (lane == 0) { r1[wv] = e1; r2[wv] = e2; }
    __syncthreads();
    if (threadIdx.x == 0) {
        atomicAdd(&S[0], r1[0] + r1[1] + r1[2] + r1[3]);
        atomicAdd(&S[1], r2[0] + r2[1] + r2[2] + r2[3]);
    }
}

// ---------- 5. per-dst-node online-softmax aggregation, both directions in one launch ----------
__global__ __launch_bounds__(256) void agg_kernel(
    const int* __restrict__ off, const int* __restrict__ idx,
    const float* __restrict__ as_all, const float* __restrict__ ad_all,
    const float* __restrict__ Pall,
    const void* __restrict__ bias,
    const float* __restrict__ S,
    const void* __restrict__ esc,
    const int* __restrict__ flag,
    void* __restrict__ out, int N)
{
    const int isbf = *flag;
    int q = (blockIdx.x * 256 + threadIdx.x) >> 6;
    int lane = threadIdx.x & 63;     // lane = h*32 + c
    if (q >= 2 * N) return;
    int dir = (q >= N) ? 1 : 0;
    int n = q - dir * N;
    // dir0 (h->t): src scalars from h rows, dst scalars from t rows, msgs = Ph, out = t_rep
    // dir1 (t->h): src scalars from t rows, dst scalars from h rows, msgs = Pt, out = h_rep
    const float* a_s  = as_all + (size_t)dir * 2u * (size_t)N;
    const float* a_d  = ad_all + (size_t)(1 - dir) * 2u * (size_t)N;
    const float* Psrc = Pall + (size_t)dir * (size_t)N * 128u;
    size_t outOff = dir ? 0u : (size_t)N * 64u;
    int h = lane >> 5;
    int jb = off[q], je = off[q + 1];
    float adv = a_d[(size_t)n * 2 + h];
    float m = lrelu(a_s[(size_t)n * 2 + h] + adv);
    float z = 1.f;
    float acc = Psrc[(size_t)n * 128 + lane];
    for (int j = jb; j < je; ++j) {
        int sidx = idx[j];
        float alf = lrelu(a_s[(size_t)sidx * 2 + h] + adv);
        float msg = Psrc[(size_t)sidx * 128 + lane];
        if (alf <= m) {
            float p = __expf(alf - m);
            z += p;
            acc += p * msg;
        } else {
            float sc = __expf(m - alf);
            acc = acc * sc + msg;
            z   = z * sc + 1.f;
            m = alf;
        }
    }
    float escv = isbf ? bf2f(((const unsigned short*)esc)[0]) : ((const float*)esc)[0];
    float bv   = isbf ? bf2f(((const unsigned short*)bias)[lane]) : ((const float*)bias)[lane];
    float weighted = S[1] / S[0];
    float factor = 1.f + 0.5f * tanhf(escv) * (weighted - 1.f);
    float o = (acc / (z + 1e-16f) + bv) * factor;
    size_t oi = outOff + (size_t)n * 64 + lane;
    if (isbf) ((unsigned short*)out)[oi] = f2bf(o);
    else      ((float*)out)[oi] = o;
}

extern "C" void kernel_launch(void* const* d_in, const int* in_sizes, int n_in,
                              void* d_out, int out_size, void* d_ws, size_t ws_size,
                              hipStream_t stream)
{
    const void* hx      = d_in[0];
    const void* tx      = d_in[1];
    const int*  eidx    = (const int*)d_in[2];
    const void* ew      = d_in[3];
    const void* Wsrc    = d_in[4];
    const void* Wdst    = d_in[5];
    const void* att_src = d_in[6];
    const void* att_dst = d_in[7];
    const void* bias    = d_in[8];
    const void* esc     = d_in[9];

    const int HC = in_sizes[6];       // 64
    const int D  = in_sizes[4] / HC;  // 256
    const int N  = in_sizes[0] / D;   // 100000
    const int E  = in_sizes[3];       // 1600000
    const int* srce = eidx;
    const int* dste = eidx + E;

    // MFMA path requires exactly the reference geometry
    const bool canM = (D == 256) && (HC == 64);
    const int skipBf = canM ? 1 : 0;

    char* wsb = (char*)d_ws;
    size_t o = 0;
    auto alloc = [&](size_t bytes) -> void* {
        void* p = wsb + o;
        o += (bytes + 255) & ~(size_t)255;
        return p;
    };
    float* Pall   = (float*)alloc((size_t)2 * N * 128 * 4);   // [Ph; Pt], f32
    float* as_all = (float*)alloc((size_t)2 * N * 2 * 4);
    float* ad_all = (float*)alloc((size_t)2 * N * 2 * 4);
    float* S      = (float*)alloc(2 * 4);
    int*   cnt    = (int*)alloc((size_t)2 * N * 4);
    int*   offp   = (int*)alloc(((size_t)2 * N + 1) * 4);
    int*   cur    = (int*)alloc((size_t)2 * N * 4);
    int*   idx    = (int*)alloc((size_t)2 * E * 4);
    int*   flag   = (int*)alloc(256);
    int*   bsum   = (int*)alloc(256 * 4);
    int*   boff   = (int*)alloc(256 * 4);
    unsigned short* Wfrag = (unsigned short*)alloc((size_t)8 * 8 * 64 * 8 * 2);  // 64KB

    hipMemsetAsync(cnt, 0, (size_t)2 * N * 4, stream);
    hipMemsetAsync(cur, 0, (size_t)2 * N * 4, stream);
    hipMemsetAsync(S, 0, 2 * 4, stream);

    detect_kernel<<<1, 256, 0, stream>>>((const unsigned int*)hx, 65536, flag);

    dim3 gGemm((N + 63) / 64, 2);
    if (canM) {
        wfrag_kernel<<<16, 256, 0, stream>>>((const unsigned short*)Wsrc,
                                             (const unsigned short*)Wdst, flag, Wfrag);
        gemm_mfma_kernel<<<gGemm, 256, 0, stream>>>(hx, tx, Wfrag, att_src, att_dst,
                                                    flag, Pall, as_all, ad_all, N);
    }
    gemm_elu_kernel<<<gGemm, 256, 0, stream>>>(hx, tx, Wsrc, Wdst, flag, Pall, N, D, skipBf);
    a_proj_kernel<<<2048, 256, 0, stream>>>(Pall, att_src, att_dst, flag,
                                            as_all, ad_all, 2 * N, skipBf);
    count_kernel<<<(E + 255) / 256, 256, 0, stream>>>(srce, dste, cnt, N, E);

    const int M = 2 * N;
    int chunk = (M + 255) / 256;
    chunk = (chunk + 255) & ~255;
    const int NB = (M + chunk - 1) / chunk;
    scan_bsum_kernel<<<NB, 256, 0, stream>>>(cnt, M, chunk, bsum);
    scan_boff_kernel<<<1, 256, 0, stream>>>(bsum, NB, boff);
    scan_write_kernel<<<NB, 256, 0, stream>>>(cnt, M, chunk, boff, offp);

    fill_kernel<<<(E + 255) / 256, 256, 0, stream>>>(srce, dste, offp, cur, idx, N, E);
    enrich_kernel<<<512, 256, 0, stream>>>(ew, flag, S, E);

    agg_kernel<<<(2 * N + 3) / 4, 256, 0, stream>>>(offp, idx, as_all, ad_all,
                                                    Pall, bias, S, esc, flag,
                                                    d_out, N);
}

// Round 3
// 1087.514 us; speedup vs baseline: 1.0366x; 1.0303x over previous
//
#include <hip/hip_runtime.h>
#include <math.h>

typedef __attribute__((ext_vector_type(8))) short bf16x8;
typedef __attribute__((ext_vector_type(4))) float f32x4;

// ---------- bf16 helpers ----------
__device__ __forceinline__ float bf2f(unsigned short u) {
    union { unsigned int i; float f; } c;
    c.i = ((unsigned int)u) << 16;
    return c.f;
}
__device__ __forceinline__ unsigned short f2bf(float f) {
    union { float f; unsigned int i; } c;
    c.f = f;
    unsigned int b = c.i + 0x7FFFu + ((c.i >> 16) & 1u);  // round-nearest-even
    return (unsigned short)(b >> 16);
}
__device__ __forceinline__ float eluf(float v) {   // jax.nn.elu, alpha=1
    return v > 0.f ? v : (__expf(v) - 1.f);
}
__device__ __forceinline__ float lrelu(float v) {  // leaky_relu slope 0.2
    return v >= 0.f ? v : 0.2f * v;
}

// ---------- 0. input dtype detection: 1 = bf16, 0 = f32 ----------
__global__ void detect_kernel(const unsigned int* __restrict__ w, int nwords,
                              int* __restrict__ flag)
{
    __shared__ int cnt_s;
    if (threadIdx.x == 0) cnt_s = 0;
    __syncthreads();
    int sane = 0;
    for (int i = threadIdx.x; i < nwords; i += 256) {
        unsigned int lo = w[i] & 0xffffu;
        int e = (int)((lo >> 7) & 0xffu);
        if (e >= 114 && e <= 136) sane++;
    }
    atomicAdd(&cnt_s, sane);
    __syncthreads();
    if (threadIdx.x == 0) *flag = (2 * cnt_s > nwords) ? 1 : 0;
}

// ---------- 1a. W fragment pre-pack for MFMA (bf16 path only) ----------
__global__ __launch_bounds__(256) void wfrag_kernel(
    const unsigned short* __restrict__ Wsrc, const unsigned short* __restrict__ Wdst,
    const int* __restrict__ flag, unsigned short* __restrict__ Wfrag)
{
    if (!*flag) return;
    const int nch = 8 * 8 * 64;   // D=256 -> 8 K-steps
    for (int ch = blockIdx.x * 256 + threadIdx.x; ch < nch; ch += gridDim.x * 256) {
        int l  = ch & 63;
        int t  = (ch >> 6) & 7;
        int ks = ch >> 9;
        int col = t * 16 + (l & 15);
        int k0  = ks * 32 + (l >> 4) * 8;
        const unsigned short* W = (col < 64) ? (Wsrc + col) : (Wdst + (col - 64));
#pragma unroll
        for (int j = 0; j < 8; ++j)
            Wfrag[(size_t)ch * 8 + j] = W[(size_t)(k0 + j) * 64];
    }
}

// ---------- 1b. MFMA fused elu+GEMM+att-projection (bf16 path, D==256, HC==64) ----------
// P now stores ONLY the hs half: [N][64] f32 per direction.
__global__ __launch_bounds__(256) void gemm_mfma_kernel(
    const void* __restrict__ xh, const void* __restrict__ xt,
    const unsigned short* __restrict__ Wfrag,
    const void* __restrict__ att_src, const void* __restrict__ att_dst,
    const int* __restrict__ flag,
    float* __restrict__ P, float* __restrict__ as_all, float* __restrict__ ad_all,
    int N)
{
    if (!*flag) return;
    const unsigned short* xv = (const unsigned short*)((blockIdx.y == 0) ? xh : xt);
    float* Pout = P + (size_t)blockIdx.y * (size_t)N * 64u;
    float* asO  = as_all + (size_t)blockIdx.y * (size_t)N * 2u;
    float* adO  = ad_all + (size_t)blockIdx.y * (size_t)N * 2u;
    const int tid = threadIdx.x;
    const int w   = tid >> 6;
    const int l   = tid & 63;
    const int l15 = l & 15;
    const int lhi = l >> 4;
    const int rowA = blockIdx.x * 64 + w * 16 + l15;
    const bool rv = rowA < N;

    // preload A fragments for all 8 K-steps, elu applied in-register
    bf16x8 a[8];
#pragma unroll
    for (int ks = 0; ks < 8; ++ks) {
        union { bf16x8 v; unsigned int u[4]; } o;
        if (rv) {
            uint4 raw = *(const uint4*)(xv + (size_t)rowA * 256 + ks * 32 + lhi * 8);
            unsigned int wsr[4] = {raw.x, raw.y, raw.z, raw.w};
#pragma unroll
            for (int i = 0; i < 4; ++i) {
                float lo = eluf(bf2f((unsigned short)(wsr[i] & 0xffffu)));
                float hi = eluf(bf2f((unsigned short)(wsr[i] >> 16)));
                o.u[i] = (unsigned int)f2bf(lo) | ((unsigned int)f2bf(hi) << 16);
            }
        } else {
            o.u[0] = o.u[1] = o.u[2] = o.u[3] = 0u;
        }
        a[ks] = o.v;
    }

    f32x4 acc[8];
#pragma unroll
    for (int t = 0; t < 8; ++t) acc[t] = (f32x4){0.f, 0.f, 0.f, 0.f};

    const bf16x8* wf = (const bf16x8*)Wfrag;
#pragma unroll
    for (int ks = 0; ks < 8; ++ks) {
#pragma unroll
        for (int t = 0; t < 8; ++t) {
            bf16x8 b = wf[(ks * 8 + t) * 64 + l];
            acc[t] = __builtin_amdgcn_mfma_f32_16x16x32_bf16(a[ks], b, acc[t], 0, 0, 0);
        }
    }

    // epilogue: store hs half of P + fused att_src/att_dst projections
    float asv[4], adv[4];
#pragma unroll
    for (int t = 0; t < 4; ++t) {
        asv[t] = bf2f(((const unsigned short*)att_src)[t * 16 + l15]);
        adv[t] = bf2f(((const unsigned short*)att_dst)[t * 16 + l15]);
    }
    const int rbase = blockIdx.x * 64 + w * 16 + lhi * 4;
#pragma unroll
    for (int reg = 0; reg < 4; ++reg) {
        int row = rbase + reg;
        bool ok = row < N;
        if (ok) {
            float* p = Pout + (size_t)row * 64 + l15;
#pragma unroll
            for (int t = 0; t < 4; ++t) p[t * 16] = acc[t][reg];
        }
        // head 0: cols 0..31 (tiles 0,1);  head 1: cols 32..63 (tiles 2,3)
        float s0 = acc[0][reg] * asv[0] + acc[1][reg] * asv[1];
        float s1 = acc[2][reg] * asv[2] + acc[3][reg] * asv[3];
        float d0 = acc[4][reg] * adv[0] + acc[5][reg] * adv[1];
        float d1 = acc[6][reg] * adv[2] + acc[7][reg] * adv[3];
#pragma unroll
        for (int o2 = 8; o2 >= 1; o2 >>= 1) {
            s0 += __shfl_xor(s0, o2, 64);
            s1 += __shfl_xor(s1, o2, 64);
            d0 += __shfl_xor(d0, o2, 64);
            d1 += __shfl_xor(d1, o2, 64);
        }
        if (ok && l15 == 0) {
            asO[(size_t)row * 2 + 0] = s0;
            asO[(size_t)row * 2 + 1] = s1;
            adO[(size_t)row * 2 + 0] = d0;
            adO[(size_t)row * 2 + 1] = d1;
        }
    }
}

// ---------- 1c. fallback fused elu + GEMM + projections (f32 path) ----------
__global__ __launch_bounds__(256) void gemm_elu_kernel(
    const void* __restrict__ xh, const void* __restrict__ xt,
    const void* __restrict__ Wsrc, const void* __restrict__ Wdst,
    const void* __restrict__ att_src, const void* __restrict__ att_dst,
    const int* __restrict__ flag,
    float* __restrict__ P, float* __restrict__ as_all, float* __restrict__ ad_all,
    int N, int D, int skip_bf)
{
    const int isbf = *flag;
    if (skip_bf && isbf) return;   // bf16 handled by MFMA kernel
    __shared__ float xs[64][33];
    __shared__ float wt[32][128];
    const void* xv = (blockIdx.y == 0) ? xh : xt;
    float* Pout = P + (size_t)blockIdx.y * (size_t)N * 64u;
    float* asO  = as_all + (size_t)blockIdx.y * (size_t)N * 2u;
    float* adO  = ad_all + (size_t)blockIdx.y * (size_t)N * 2u;
    const int rowBase = blockIdx.x * 64;
    const int tid = threadIdx.x;
    const int tcx = tid & 15;
    const int tcy = tid >> 4;

    float acc[4][8];
#pragma unroll
    for (int r = 0; r < 4; ++r)
#pragma unroll
        for (int c = 0; c < 8; ++c) acc[r][c] = 0.f;

    for (int kc = 0; kc < D; kc += 32) {
        {
            int row = tid >> 2;
            int kq  = (tid & 3) * 8;
            int r = rowBase + row;
            float v[8];
            if (r < N) {
                if (isbf) {
                    const unsigned short* xb = (const unsigned short*)xv;
                    uint4 raw = *(const uint4*)(xb + (size_t)r * D + kc + kq);
                    unsigned int ws[4] = {raw.x, raw.y, raw.z, raw.w};
#pragma unroll
                    for (int i = 0; i < 4; ++i) {
                        v[2 * i]     = bf2f((unsigned short)(ws[i] & 0xffffu));
                        v[2 * i + 1] = bf2f((unsigned short)(ws[i] >> 16));
                    }
                } else {
                    const float* xf = (const float*)xv;
                    const float4* p4 = (const float4*)(xf + (size_t)r * D + kc + kq);
                    float4 f0 = p4[0], f1 = p4[1];
                    v[0] = f0.x; v[1] = f0.y; v[2] = f0.z; v[3] = f0.w;
                    v[4] = f1.x; v[5] = f1.y; v[6] = f1.z; v[7] = f1.w;
                }
#pragma unroll
                for (int i = 0; i < 8; ++i) v[i] = eluf(v[i]);
            } else {
#pragma unroll
                for (int i = 0; i < 8; ++i) v[i] = 0.f;
            }
#pragma unroll
            for (int i = 0; i < 8; ++i) xs[row][kq + i] = v[i];
        }
#pragma unroll
        for (int i = 0; i < 2; ++i) {
            int f = (tid + i * 256) * 8;
            int k = f >> 7;
            int c = f & 127;
            float v[8];
            if (isbf) {
                const unsigned short* Wp = (c < 64)
                    ? ((const unsigned short*)Wsrc + (size_t)(kc + k) * 64 + c)
                    : ((const unsigned short*)Wdst + (size_t)(kc + k) * 64 + (c - 64));
                uint4 raw = *(const uint4*)Wp;
                unsigned int ws[4] = {raw.x, raw.y, raw.z, raw.w};
#pragma unroll
                for (int q = 0; q < 4; ++q) {
                    v[2 * q]     = bf2f((unsigned short)(ws[q] & 0xffffu));
                    v[2 * q + 1] = bf2f((unsigned short)(ws[q] >> 16));
                }
            } else {
                const float* Wp = (c < 64)
                    ? ((const float*)Wsrc + (size_t)(kc + k) * 64 + c)
                    : ((const float*)Wdst + (size_t)(kc + k) * 64 + (c - 64));
                const float4* p4 = (const float4*)Wp;
                float4 f0 = p4[0], f1 = p4[1];
                v[0] = f0.x; v[1] = f0.y; v[2] = f0.z; v[3] = f0.w;
                v[4] = f1.x; v[5] = f1.y; v[6] = f1.z; v[7] = f1.w;
            }
#pragma unroll
            for (int q = 0; q < 8; ++q) wt[k][c + q] = v[q];
        }
        __syncthreads();
#pragma unroll 8
        for (int k = 0; k < 32; ++k) {
            float xr[4];
#pragma unroll
            for (int r = 0; r < 4; ++r) xr[r] = xs[tcy * 4 + r][k];
            float4 w0 = *(const float4*)&wt[k][tcx * 8];
            float4 w1 = *(const float4*)&wt[k][tcx * 8 + 4];
#pragma unroll
            for (int r = 0; r < 4; ++r) {
                acc[r][0] += xr[r] * w0.x; acc[r][1] += xr[r] * w0.y;
                acc[r][2] += xr[r] * w0.z; acc[r][3] += xr[r] * w0.w;
                acc[r][4] += xr[r] * w1.x; acc[r][5] += xr[r] * w1.y;
                acc[r][6] += xr[r] * w1.z; acc[r][7] += xr[r] * w1.w;
            }
        }
        __syncthreads();
    }

    // att values for this thread's 8 columns
    float attv[8];
#pragma unroll
    for (int q = 0; q < 8; ++q) {
        int c = tcx * 8 + q;
        if (isbf) attv[q] = (c < 64) ? bf2f(((const unsigned short*)att_src)[c])
                                     : bf2f(((const unsigned short*)att_dst)[c - 64]);
        else      attv[q] = (c < 64) ? ((const float*)att_src)[c]
                                     : ((const float*)att_dst)[c - 64];
    }

#pragma unroll
    for (int r = 0; r < 4; ++r) {
        int row = rowBase + tcy * 4 + r;
        bool ok = row < N;
        if (ok && tcx < 8) {   // store only hs half (cols 0..63)
            float* p = Pout + (size_t)row * 64 + tcx * 8;
            *(float4*)p       = make_float4(acc[r][0], acc[r][1], acc[r][2], acc[r][3]);
            *(float4*)(p + 4) = make_float4(acc[r][4], acc[r][5], acc[r][6], acc[r][7]);
        }
        // fused projection: partial dot over this thread's 8 cols, reduce over 4-thread groups
        float part = 0.f;
#pragma unroll
        for (int q = 0; q < 8; ++q) part += acc[r][q] * attv[q];
        part += __shfl_xor(part, 1, 64);
        part += __shfl_xor(part, 2, 64);
        if (ok && (tcx & 3) == 0) {
            // tcx==0: as h0 | tcx==4: as h1 | tcx==8: ad h0 | tcx==12: ad h1
            if (tcx == 0)       asO[(size_t)row * 2 + 0] = part;
            else if (tcx == 4)  asO[(size_t)row * 2 + 1] = part;
            else if (tcx == 8)  adO[(size_t)row * 2 + 0] = part;
            else                adO[(size_t)row * 2 + 1] = part;
        }
    }
}

// ---------- 3a. degree histogram (dir1 by dst, dir2 by src) ----------
__global__ void count_kernel(const int* __restrict__ srce, const int* __restrict__ dste,
                             int* __restrict__ cnt, int N, int E)
{
    int e = blockIdx.x * blockDim.x + threadIdx.x;
    if (e >= E) return;
    atomicAdd(&cnt[dste[e]], 1);
    atomicAdd(&cnt[N + srce[e]], 1);
}

// ---------- 3b. multi-block scan: stage 1 ----------
__global__ __launch_bounds__(256) void scan_bsum_kernel(
    const int* __restrict__ cnt, int M, int chunk, int* __restrict__ bsum)
{
    __shared__ int r[4];
    int beg = blockIdx.x * chunk;
    int end = beg + chunk; if (end > M) end = M;
    int s = 0;
    for (int i = beg + threadIdx.x; i < end; i += 256) s += cnt[i];
#pragma unroll
    for (int o = 32; o >= 1; o >>= 1) s += __shfl_down(s, o, 64);
    int lane = threadIdx.x & 63, wv = threadIdx.x >> 6;
    if (lane == 0) r[wv] = s;
    __syncthreads();
    if (threadIdx.x == 0) bsum[blockIdx.x] = r[0] + r[1] + r[2] + r[3];
}

// ---------- stage 2 ----------
__global__ __launch_bounds__(256) void scan_boff_kernel(
    const int* __restrict__ bsum, int NB, int* __restrict__ boff)
{
    __shared__ int s[256];
    int t = threadIdx.x;
    int v = (t < NB) ? bsum[t] : 0;
    s[t] = v;
    __syncthreads();
    for (int o = 1; o < 256; o <<= 1) {
        int x = (t >= o) ? s[t - o] : 0;
        __syncthreads();
        s[t] += x;
        __syncthreads();
    }
    if (t < NB) boff[t] = s[t] - v;
}

// ---------- stage 3 ----------
__global__ __launch_bounds__(256) void scan_write_kernel(
    const int* __restrict__ cnt, int M, int chunk,
    const int* __restrict__ boff, int* __restrict__ off)
{
    __shared__ int s[256];
    int t = threadIdx.x;
    int beg = blockIdx.x * chunk;
    int end = beg + chunk; if (end > M) end = M;
    if (beg >= M) return;
    int running = boff[blockIdx.x];
    for (int base = beg; base < end; base += 256) {
        int i = base + t;
        int v = (i < end) ? cnt[i] : 0;
        s[t] = v;
        __syncthreads();
        for (int o = 1; o < 256; o <<= 1) {
            int x = (t >= o) ? s[t - o] : 0;
            __syncthreads();
            s[t] += x;
            __syncthreads();
        }
        if (i < end) off[i] = running + s[t] - v;
        int total = s[255];
        __syncthreads();
        running += total;
    }
    if (end == M && t == 0) off[M] = running;
}

// ---------- 3c. CSR fill ----------
__global__ void fill_kernel(const int* __restrict__ srce, const int* __restrict__ dste,
                            const int* __restrict__ off, int* __restrict__ cur,
                            int* __restrict__ idx, int N, int E)
{
    int e = blockIdx.x * blockDim.x + threadIdx.x;
    if (e >= E) return;
    int s = srce[e], d = dste[e];
    int p  = atomicAdd(&cur[d], 1);
    idx[off[d] + p] = s;
    int p2 = atomicAdd(&cur[N + s], 1);
    idx[off[N + s] + p2] = d;
}

// ---------- 4. enrichment softmax sums ----------
__global__ __launch_bounds__(256) void enrich_kernel(
    const void* __restrict__ ew, const int* __restrict__ flag,
    float* __restrict__ S, int E)
{
    __shared__ float r1[4], r2[4];
    const int isbf = *flag;
    float e1 = 0.f, e2 = 0.f;
    for (int i = blockIdx.x * 256 + threadIdx.x; i < E; i += gridDim.x * 256) {
        float c = isbf ? bf2f(((const unsigned short*)ew)[i]) : ((const float*)ew)[i];
        c = fminf(fmaxf(c, 0.3f), 3.0f);
        float ex = __expf(c);
        e1 += ex;
        e2 += c * ex;
    }
#pragma unroll
    for (int o = 32; o >= 1; o >>= 1) {
        e1 += __shfl_down(e1, o, 64);
        e2 += __shfl_down(e2, o, 64);
    }
    int lane = threadIdx.x & 63;
    int wv = threadIdx.x >> 6;
    if (lane == 0) { r1[wv] = e1; r2[wv] = e2; }
    __syncthreads();
    if (threadIdx.x == 0) {
        atomicAdd(&S[0], r1[0] + r1[1] + r1[2] + r1[3]);
        atomicAdd(&S[1], r2[0] + r2[1] + r2[2] + r2[3]);
    }
}

// ---------- 5. per-dst-node two-phase softmax aggregation, both directions ----------
// One wave per (dir, node). Phase 1: lane-parallel max over edges (both heads).
// Phase 2: branch-free accumulate with independent iterations.
__global__ __launch_bounds__(256) void agg_kernel(
    const int* __restrict__ off, const int* __restrict__ idx,
    const float* __restrict__ as_all, const float* __restrict__ ad_all,
    const float* __restrict__ Pall,
    const void* __restrict__ bias,
    const float* __restrict__ S,
    const void* __restrict__ esc,
    const int* __restrict__ flag,
    void* __restrict__ out, int N)
{
    const int isbf = *flag;
    int q = (blockIdx.x * 256 + threadIdx.x) >> 6;
    int lane = threadIdx.x & 63;     // lane = h*32 + c
    if (q >= 2 * N) return;
    int dir = (q >= N) ? 1 : 0;
    int n = q - dir * N;
    const float* a_s  = as_all + (size_t)dir * 2u * (size_t)N;
    const float* a_d  = ad_all + (size_t)(1 - dir) * 2u * (size_t)N;
    const float* Psrc = Pall + (size_t)dir * (size_t)N * 64u;
    size_t outOff = dir ? 0u : (size_t)N * 64u;
    const int jb = off[q], je = off[q + 1];

    float2 adv2 = *(const float2*)(a_d + (size_t)n * 2);
    float2 ass2 = *(const float2*)(a_s + (size_t)n * 2);
    float self0 = lrelu(ass2.x + adv2.x);
    float self1 = lrelu(ass2.y + adv2.y);

    // ---- phase 1: per-head max, lane-parallel over edges ----
    float m0 = self0, m1 = self1;
    for (int j = jb + lane; j < je; j += 64) {
        int sidx = idx[j];
        float2 as2 = *(const float2*)(a_s + (size_t)sidx * 2);
        m0 = fmaxf(m0, lrelu(as2.x + adv2.x));
        m1 = fmaxf(m1, lrelu(as2.y + adv2.y));
    }
#pragma unroll
    for (int o = 32; o >= 1; o >>= 1) {
        m0 = fmaxf(m0, __shfl_xor(m0, o, 64));
        m1 = fmaxf(m1, __shfl_xor(m1, o, 64));
    }

    // ---- phase 2: branch-free accumulate ----
    const int hi = lane >> 5;
    const float m    = hi ? m1 : m0;
    const float adv  = hi ? adv2.y : adv2.x;
    const float pSelf = __expf((hi ? self1 : self0) - m);
    float z   = pSelf;
    float acc = pSelf * Psrc[(size_t)n * 64 + lane];
    for (int j = jb; j < je; ++j) {
        int sidx = idx[j];
        float2 as2 = *(const float2*)(a_s + (size_t)sidx * 2);
        float alf = lrelu((hi ? as2.y : as2.x) + adv);
        float p = __expf(alf - m);
        z += p;
        acc = fmaf(p, Psrc[(size_t)sidx * 64 + lane], acc);
    }

    float escv = isbf ? bf2f(((const unsigned short*)esc)[0]) : ((const float*)esc)[0];
    float bv   = isbf ? bf2f(((const unsigned short*)bias)[lane]) : ((const float*)bias)[lane];
    float weighted = S[1] / S[0];
    float factor = 1.f + 0.5f * tanhf(escv) * (weighted - 1.f);
    float o = (acc / (z + 1e-16f) + bv) * factor;
    size_t oi = outOff + (size_t)n * 64 + lane;
    if (isbf) ((unsigned short*)out)[oi] = f2bf(o);
    else      ((float*)out)[oi] = o;
}

extern "C" void kernel_launch(void* const* d_in, const int* in_sizes, int n_in,
                              void* d_out, int out_size, void* d_ws, size_t ws_size,
                              hipStream_t stream)
{
    const void* hx      = d_in[0];
    const void* tx      = d_in[1];
    const int*  eidx    = (const int*)d_in[2];
    const void* ew      = d_in[3];
    const void* Wsrc    = d_in[4];
    const void* Wdst    = d_in[5];
    const void* att_src = d_in[6];
    const void* att_dst = d_in[7];
    const void* bias    = d_in[8];
    const void* esc     = d_in[9];

    const int HC = in_sizes[6];       // 64
    const int D  = in_sizes[4] / HC;  // 256
    const int N  = in_sizes[0] / D;   // 100000
    const int E  = in_sizes[3];       // 1600000
    const int* srce = eidx;
    const int* dste = eidx + E;

    const bool canM = (D == 256) && (HC == 64);
    const int skipBf = canM ? 1 : 0;

    char* wsb = (char*)d_ws;
    size_t o = 0;
    auto alloc = [&](size_t bytes) -> void* {
        void* p = wsb + o;
        o += (bytes + 255) & ~(size_t)255;
        return p;
    };
    float* Pall   = (float*)alloc((size_t)2 * N * 64 * 4);    // [Ph; Pt] hs-only, f32
    float* as_all = (float*)alloc((size_t)2 * N * 2 * 4);
    float* ad_all = (float*)alloc((size_t)2 * N * 2 * 4);
    float* S      = (float*)alloc(2 * 4);
    int*   cnt    = (int*)alloc((size_t)2 * N * 4);
    int*   offp   = (int*)alloc(((size_t)2 * N + 1) * 4);
    int*   cur    = (int*)alloc((size_t)2 * N * 4);
    int*   idx    = (int*)alloc((size_t)2 * E * 4);
    int*   flag   = (int*)alloc(256);
    int*   bsum   = (int*)alloc(256 * 4);
    int*   boff   = (int*)alloc(256 * 4);
    unsigned short* Wfrag = (unsigned short*)alloc((size_t)8 * 8 * 64 * 8 * 2);  // 64KB

    hipMemsetAsync(cnt, 0, (size_t)2 * N * 4, stream);
    hipMemsetAsync(cur, 0, (size_t)2 * N * 4, stream);
    hipMemsetAsync(S, 0, 2 * 4, stream);

    detect_kernel<<<1, 256, 0, stream>>>((const unsigned int*)hx, 65536, flag);

    dim3 gGemm((N + 63) / 64, 2);
    if (canM) {
        wfrag_kernel<<<16, 256, 0, stream>>>((const unsigned short*)Wsrc,
                                             (const unsigned short*)Wdst, flag, Wfrag);
        gemm_mfma_kernel<<<gGemm, 256, 0, stream>>>(hx, tx, Wfrag, att_src, att_dst,
                                                    flag, Pall, as_all, ad_all, N);
    }
    gemm_elu_kernel<<<gGemm, 256, 0, stream>>>(hx, tx, Wsrc, Wdst, att_src, att_dst,
                                               flag, Pall, as_all, ad_all, N, D, skipBf);
    count_kernel<<<(E + 255) / 256, 256, 0, stream>>>(srce, dste, cnt, N, E);

    const int M = 2 * N;
    int chunk = (M + 255) / 256;
    chunk = (chunk + 255) & ~255;
    const int NB = (M + chunk - 1) / chunk;
    scan_bsum_kernel<<<NB, 256, 0, stream>>>(cnt, M, chunk, bsum);
    scan_boff_kernel<<<1, 256, 0, stream>>>(bsum, NB, boff);
    scan_write_kernel<<<NB, 256, 0, stream>>>(cnt, M, chunk, boff, offp);

    fill_kernel<<<(E + 255) / 256, 256, 0, stream>>>(srce, dste, offp, cur, idx, N, E);
    enrich_kernel<<<512, 256, 0, stream>>>(ew, flag, S, E);

    agg_kernel<<<(2 * N + 3) / 4, 256, 0, stream>>>(offp, idx, as_all, ad_all,
                                                    Pall, bias, S, esc, flag,
                                                    d_out, N);
}

// Round 4
// 1008.336 us; speedup vs baseline: 1.1180x; 1.0785x over previous
//
#include <hip/hip_runtime.h>
#include <hip/hip_fp16.h>
#include <math.h>

typedef __attribute__((ext_vector_type(8))) short bf16x8;
typedef __attribute__((ext_vector_type(4))) float f32x4;

// ---------- bf16 helpers ----------
__device__ __forceinline__ float bf2f(unsigned short u) {
    union { unsigned int i; float f; } c;
    c.i = ((unsigned int)u) << 16;
    return c.f;
}
__device__ __forceinline__ unsigned short f2bf(float f) {
    union { float f; unsigned int i; } c;
    c.f = f;
    unsigned int b = c.i + 0x7FFFu + ((c.i >> 16) & 1u);  // round-nearest-even
    return (unsigned short)(b >> 16);
}
__device__ __forceinline__ float eluf(float v) {   // jax.nn.elu, alpha=1
    return v > 0.f ? v : (__expf(v) - 1.f);
}
__device__ __forceinline__ float lrelu(float v) {  // leaky_relu slope 0.2
    return v >= 0.f ? v : 0.2f * v;
}
// order-preserving float<->uint encoding for atomicMax
__device__ __forceinline__ unsigned int fenc(float f) {
    union { float f; unsigned int u; } c; c.f = f;
    return (c.u & 0x80000000u) ? ~c.u : (c.u | 0x80000000u);
}
__device__ __forceinline__ float fdec(unsigned int k) {
    union { float f; unsigned int u; } c;
    c.u = (k & 0x80000000u) ? (k ^ 0x80000000u) : ~k;
    return c.f;
}

// ---------- 0. input dtype detection: 1 = bf16, 0 = f32 ----------
__global__ void detect_kernel(const unsigned int* __restrict__ w, int nwords,
                              int* __restrict__ flag)
{
    __shared__ int cnt_s;
    if (threadIdx.x == 0) cnt_s = 0;
    __syncthreads();
    int sane = 0;
    for (int i = threadIdx.x; i < nwords; i += 256) {
        unsigned int lo = w[i] & 0xffffu;
        int e = (int)((lo >> 7) & 0xffu);
        if (e >= 114 && e <= 136) sane++;
    }
    atomicAdd(&cnt_s, sane);
    __syncthreads();
    if (threadIdx.x == 0) *flag = (2 * cnt_s > nwords) ? 1 : 0;
}

// ---------- 1a. W fragment pre-pack for MFMA (bf16 path only) ----------
__global__ __launch_bounds__(256) void wfrag_kernel(
    const unsigned short* __restrict__ Wsrc, const unsigned short* __restrict__ Wdst,
    const int* __restrict__ flag, unsigned short* __restrict__ Wfrag)
{
    if (!*flag) return;
    const int nch = 8 * 8 * 64;   // D=256 -> 8 K-steps
    for (int ch = blockIdx.x * 256 + threadIdx.x; ch < nch; ch += gridDim.x * 256) {
        int l  = ch & 63;
        int t  = (ch >> 6) & 7;
        int ks = ch >> 9;
        int col = t * 16 + (l & 15);
        int k0  = ks * 32 + (l >> 4) * 8;
        const unsigned short* W = (col < 64) ? (Wsrc + col) : (Wdst + (col - 64));
#pragma unroll
        for (int j = 0; j < 8; ++j)
            Wfrag[(size_t)ch * 8 + j] = W[(size_t)(k0 + j) * 64];
    }
}

// ---------- 1b. MFMA fused elu+GEMM+att-projection (bf16 path, D==256, HC==64) ----------
// P stores ONLY the hs half, fp16: [N][64] per direction.
__global__ __launch_bounds__(256) void gemm_mfma_kernel(
    const void* __restrict__ xh, const void* __restrict__ xt,
    const unsigned short* __restrict__ Wfrag,
    const void* __restrict__ att_src, const void* __restrict__ att_dst,
    const int* __restrict__ flag,
    __half* __restrict__ P, float* __restrict__ as_all, float* __restrict__ ad_all,
    int N)
{
    if (!*flag) return;
    const unsigned short* xv = (const unsigned short*)((blockIdx.y == 0) ? xh : xt);
    __half* Pout = P + (size_t)blockIdx.y * (size_t)N * 64u;
    float* asO  = as_all + (size_t)blockIdx.y * (size_t)N * 2u;
    float* adO  = ad_all + (size_t)blockIdx.y * (size_t)N * 2u;
    const int tid = threadIdx.x;
    const int w   = tid >> 6;
    const int l   = tid & 63;
    const int l15 = l & 15;
    const int lhi = l >> 4;
    const int rowA = blockIdx.x * 64 + w * 16 + l15;
    const bool rv = rowA < N;

    // preload A fragments for all 8 K-steps, elu applied in-register
    bf16x8 a[8];
#pragma unroll
    for (int ks = 0; ks < 8; ++ks) {
        union { bf16x8 v; unsigned int u[4]; } o;
        if (rv) {
            uint4 raw = *(const uint4*)(xv + (size_t)rowA * 256 + ks * 32 + lhi * 8);
            unsigned int wsr[4] = {raw.x, raw.y, raw.z, raw.w};
#pragma unroll
            for (int i = 0; i < 4; ++i) {
                float lo = eluf(bf2f((unsigned short)(wsr[i] & 0xffffu)));
                float hi = eluf(bf2f((unsigned short)(wsr[i] >> 16)));
                o.u[i] = (unsigned int)f2bf(lo) | ((unsigned int)f2bf(hi) << 16);
            }
        } else {
            o.u[0] = o.u[1] = o.u[2] = o.u[3] = 0u;
        }
        a[ks] = o.v;
    }

    f32x4 acc[8];
#pragma unroll
    for (int t = 0; t < 8; ++t) acc[t] = (f32x4){0.f, 0.f, 0.f, 0.f};

    const bf16x8* wf = (const bf16x8*)Wfrag;
#pragma unroll
    for (int ks = 0; ks < 8; ++ks) {
#pragma unroll
        for (int t = 0; t < 8; ++t) {
            bf16x8 b = wf[(ks * 8 + t) * 64 + l];
            acc[t] = __builtin_amdgcn_mfma_f32_16x16x32_bf16(a[ks], b, acc[t], 0, 0, 0);
        }
    }

    // epilogue: store hs half of P (fp16) + fused att_src/att_dst projections
    float asv[4], adv[4];
#pragma unroll
    for (int t = 0; t < 4; ++t) {
        asv[t] = bf2f(((const unsigned short*)att_src)[t * 16 + l15]);
        adv[t] = bf2f(((const unsigned short*)att_dst)[t * 16 + l15]);
    }
    const int rbase = blockIdx.x * 64 + w * 16 + lhi * 4;
#pragma unroll
    for (int reg = 0; reg < 4; ++reg) {
        int row = rbase + reg;
        bool ok = row < N;
        if (ok) {
            __half* p = Pout + (size_t)row * 64 + l15;
#pragma unroll
            for (int t = 0; t < 4; ++t) p[t * 16] = __float2half(acc[t][reg]);
        }
        // head 0: cols 0..31 (tiles 0,1);  head 1: cols 32..63 (tiles 2,3)
        float s0 = acc[0][reg] * asv[0] + acc[1][reg] * asv[1];
        float s1 = acc[2][reg] * asv[2] + acc[3][reg] * asv[3];
        float d0 = acc[4][reg] * adv[0] + acc[5][reg] * adv[1];
        float d1 = acc[6][reg] * adv[2] + acc[7][reg] * adv[3];
#pragma unroll
        for (int o2 = 8; o2 >= 1; o2 >>= 1) {
            s0 += __shfl_xor(s0, o2, 64);
            s1 += __shfl_xor(s1, o2, 64);
            d0 += __shfl_xor(d0, o2, 64);
            d1 += __shfl_xor(d1, o2, 64);
        }
        if (ok && l15 == 0) {
            asO[(size_t)row * 2 + 0] = s0;
            asO[(size_t)row * 2 + 1] = s1;
            adO[(size_t)row * 2 + 0] = d0;
            adO[(size_t)row * 2 + 1] = d1;
        }
    }
}

// ---------- 1c. fallback fused elu + GEMM + projections (f32 path) ----------
__global__ __launch_bounds__(256) void gemm_elu_kernel(
    const void* __restrict__ xh, const void* __restrict__ xt,
    const void* __restrict__ Wsrc, const void* __restrict__ Wdst,
    const void* __restrict__ att_src, const void* __restrict__ att_dst,
    const int* __restrict__ flag,
    __half* __restrict__ P, float* __restrict__ as_all, float* __restrict__ ad_all,
    int N, int D, int skip_bf)
{
    const int isbf = *flag;
    if (skip_bf && isbf) return;   // bf16 handled by MFMA kernel
    __shared__ float xs[64][33];
    __shared__ float wt[32][128];
    const void* xv = (blockIdx.y == 0) ? xh : xt;
    __half* Pout = P + (size_t)blockIdx.y * (size_t)N * 64u;
    float* asO  = as_all + (size_t)blockIdx.y * (size_t)N * 2u;
    float* adO  = ad_all + (size_t)blockIdx.y * (size_t)N * 2u;
    const int rowBase = blockIdx.x * 64;
    const int tid = threadIdx.x;
    const int tcx = tid & 15;
    const int tcy = tid >> 4;

    float acc[4][8];
#pragma unroll
    for (int r = 0; r < 4; ++r)
#pragma unroll
        for (int c = 0; c < 8; ++c) acc[r][c] = 0.f;

    for (int kc = 0; kc < D; kc += 32) {
        {
            int row = tid >> 2;
            int kq  = (tid & 3) * 8;
            int r = rowBase + row;
            float v[8];
            if (r < N) {
                if (isbf) {
                    const unsigned short* xb = (const unsigned short*)xv;
                    uint4 raw = *(const uint4*)(xb + (size_t)r * D + kc + kq);
                    unsigned int ws[4] = {raw.x, raw.y, raw.z, raw.w};
#pragma unroll
                    for (int i = 0; i < 4; ++i) {
                        v[2 * i]     = bf2f((unsigned short)(ws[i] & 0xffffu));
                        v[2 * i + 1] = bf2f((unsigned short)(ws[i] >> 16));
                    }
                } else {
                    const float* xf = (const float*)xv;
                    const float4* p4 = (const float4*)(xf + (size_t)r * D + kc + kq);
                    float4 f0 = p4[0], f1 = p4[1];
                    v[0] = f0.x; v[1] = f0.y; v[2] = f0.z; v[3] = f0.w;
                    v[4] = f1.x; v[5] = f1.y; v[6] = f1.z; v[7] = f1.w;
                }
#pragma unroll
                for (int i = 0; i < 8; ++i) v[i] = eluf(v[i]);
            } else {
#pragma unroll
                for (int i = 0; i < 8; ++i) v[i] = 0.f;
            }
#pragma unroll
            for (int i = 0; i < 8; ++i) xs[row][kq + i] = v[i];
        }
#pragma unroll
        for (int i = 0; i < 2; ++i) {
            int f = (tid + i * 256) * 8;
            int k = f >> 7;
            int c = f & 127;
            float v[8];
            if (isbf) {
                const unsigned short* Wp = (c < 64)
                    ? ((const unsigned short*)Wsrc + (size_t)(kc + k) * 64 + c)
                    : ((const unsigned short*)Wdst + (size_t)(kc + k) * 64 + (c - 64));
                uint4 raw = *(const uint4*)Wp;
                unsigned int ws[4] = {raw.x, raw.y, raw.z, raw.w};
#pragma unroll
                for (int q = 0; q < 4; ++q) {
                    v[2 * q]     = bf2f((unsigned short)(ws[q] & 0xffffu));
                    v[2 * q + 1] = bf2f((unsigned short)(ws[q] >> 16));
                }
            } else {
                const float* Wp = (c < 64)
                    ? ((const float*)Wsrc + (size_t)(kc + k) * 64 + c)
                    : ((const float*)Wdst + (size_t)(kc + k) * 64 + (c - 64));
                const float4* p4 = (const float4*)Wp;
                float4 f0 = p4[0], f1 = p4[1];
                v[0] = f0.x; v[1] = f0.y; v[2] = f0.z; v[3] = f0.w;
                v[4] = f1.x; v[5] = f1.y; v[6] = f1.z; v[7] = f1.w;
            }
#pragma unroll
            for (int q = 0; q < 8; ++q) wt[k][c + q] = v[q];
        }
        __syncthreads();
#pragma unroll 8
        for (int k = 0; k < 32; ++k) {
            float xr[4];
#pragma unroll
            for (int r = 0; r < 4; ++r) xr[r] = xs[tcy * 4 + r][k];
            float4 w0 = *(const float4*)&wt[k][tcx * 8];
            float4 w1 = *(const float4*)&wt[k][tcx * 8 + 4];
#pragma unroll
            for (int r = 0; r < 4; ++r) {
                acc[r][0] += xr[r] * w0.x; acc[r][1] += xr[r] * w0.y;
                acc[r][2] += xr[r] * w0.z; acc[r][3] += xr[r] * w0.w;
                acc[r][4] += xr[r] * w1.x; acc[r][5] += xr[r] * w1.y;
                acc[r][6] += xr[r] * w1.z; acc[r][7] += xr[r] * w1.w;
            }
        }
        __syncthreads();
    }

    // att values for this thread's 8 columns
    float attv[8];
#pragma unroll
    for (int q = 0; q < 8; ++q) {
        int c = tcx * 8 + q;
        if (isbf) attv[q] = (c < 64) ? bf2f(((const unsigned short*)att_src)[c])
                                     : bf2f(((const unsigned short*)att_dst)[c - 64]);
        else      attv[q] = (c < 64) ? ((const float*)att_src)[c]
                                     : ((const float*)att_dst)[c - 64];
    }

#pragma unroll
    for (int r = 0; r < 4; ++r) {
        int row = rowBase + tcy * 4 + r;
        bool ok = row < N;
        if (ok && tcx < 8) {   // store only hs half (cols 0..63), fp16
            __half* p = Pout + (size_t)row * 64 + tcx * 8;
#pragma unroll
            for (int q = 0; q < 8; ++q) p[q] = __float2half(acc[r][q]);
        }
        float part = 0.f;
#pragma unroll
        for (int q = 0; q < 8; ++q) part += acc[r][q] * attv[q];
        part += __shfl_xor(part, 1, 64);
        part += __shfl_xor(part, 2, 64);
        if (ok && (tcx & 3) == 0) {
            if (tcx == 0)       asO[(size_t)row * 2 + 0] = part;
            else if (tcx == 4)  asO[(size_t)row * 2 + 1] = part;
            else if (tcx == 8)  adO[(size_t)row * 2 + 0] = part;
            else                adO[(size_t)row * 2 + 1] = part;
        }
    }
}

// ---------- 2. global per-(dir,head) max of a_s ----------
__global__ __launch_bounds__(256) void gmax_kernel(
    const float* __restrict__ as_all, unsigned int* __restrict__ gmax, int N)
{
    unsigned int k0 = 0, k1 = 0, k2 = 0, k3 = 0;
    const int total = 2 * N;
    for (int i = blockIdx.x * 256 + threadIdx.x; i < total; i += gridDim.x * 256) {
        float2 v = *(const float2*)(as_all + (size_t)i * 2);
        unsigned int ex = fenc(v.x), ey = fenc(v.y);
        if (i < N) { k0 = max(k0, ex); k1 = max(k1, ey); }
        else       { k2 = max(k2, ex); k3 = max(k3, ey); }
    }
#pragma unroll
    for (int o = 32; o >= 1; o >>= 1) {
        k0 = max(k0, (unsigned int)__shfl_xor((int)k0, o, 64));
        k1 = max(k1, (unsigned int)__shfl_xor((int)k1, o, 64));
        k2 = max(k2, (unsigned int)__shfl_xor((int)k2, o, 64));
        k3 = max(k3, (unsigned int)__shfl_xor((int)k3, o, 64));
    }
    if ((threadIdx.x & 63) == 0) {
        atomicMax(&gmax[0], k0);
        atomicMax(&gmax[1], k1);
        atomicMax(&gmax[2], k2);
        atomicMax(&gmax[3], k3);
    }
}

// ---------- 3a. degree histogram (dir1 by dst, dir2 by src) ----------
__global__ void count_kernel(const int* __restrict__ srce, const int* __restrict__ dste,
                             int* __restrict__ cnt, int N, int E)
{
    int e = blockIdx.x * blockDim.x + threadIdx.x;
    if (e >= E) return;
    atomicAdd(&cnt[dste[e]], 1);
    atomicAdd(&cnt[N + srce[e]], 1);
}

// ---------- 3b. multi-block scan: stage 1 ----------
__global__ __launch_bounds__(256) void scan_bsum_kernel(
    const int* __restrict__ cnt, int M, int chunk, int* __restrict__ bsum)
{
    __shared__ int r[4];
    int beg = blockIdx.x * chunk;
    int end = beg + chunk; if (end > M) end = M;
    int s = 0;
    for (int i = beg + threadIdx.x; i < end; i += 256) s += cnt[i];
#pragma unroll
    for (int o = 32; o >= 1; o >>= 1) s += __shfl_down(s, o, 64);
    int lane = threadIdx.x & 63, wv = threadIdx.x >> 6;
    if (lane == 0) r[wv] = s;
    __syncthreads();
    if (threadIdx.x == 0) bsum[blockIdx.x] = r[0] + r[1] + r[2] + r[3];
}

// ---------- stage 2 ----------
__global__ __launch_bounds__(256) void scan_boff_kernel(
    const int* __restrict__ bsum, int NB, int* __restrict__ boff)
{
    __shared__ int s[256];
    int t = threadIdx.x;
    int v = (t < NB) ? bsum[t] : 0;
    s[t] = v;
    __syncthreads();
    for (int o = 1; o < 256; o <<= 1) {
        int x = (t >= o) ? s[t - o] : 0;
        __syncthreads();
        s[t] += x;
        __syncthreads();
    }
    if (t < NB) boff[t] = s[t] - v;
}

// ---------- stage 3 ----------
__global__ __launch_bounds__(256) void scan_write_kernel(
    const int* __restrict__ cnt, int M, int chunk,
    const int* __restrict__ boff, int* __restrict__ off)
{
    __shared__ int s[256];
    int t = threadIdx.x;
    int beg = blockIdx.x * chunk;
    int end = beg + chunk; if (end > M) end = M;
    if (beg >= M) return;
    int running = boff[blockIdx.x];
    for (int base = beg; base < end; base += 256) {
        int i = base + t;
        int v = (i < end) ? cnt[i] : 0;
        s[t] = v;
        __syncthreads();
        for (int o = 1; o < 256; o <<= 1) {
            int x = (t >= o) ? s[t - o] : 0;
            __syncthreads();
            s[t] += x;
            __syncthreads();
        }
        if (i < end) off[i] = running + s[t] - v;
        int total = s[255];
        __syncthreads();
        running += total;
    }
    if (end == M && t == 0) off[M] = running;
}

// ---------- 3c. CSR fill ----------
__global__ void fill_kernel(const int* __restrict__ srce, const int* __restrict__ dste,
                            const int* __restrict__ off, int* __restrict__ cur,
                            int* __restrict__ idx, int N, int E)
{
    int e = blockIdx.x * blockDim.x + threadIdx.x;
    if (e >= E) return;
    int s = srce[e], d = dste[e];
    int p  = atomicAdd(&cur[d], 1);
    idx[off[d] + p] = s;
    int p2 = atomicAdd(&cur[N + s], 1);
    idx[off[N + s] + p2] = d;
}

// ---------- 4. enrichment softmax sums ----------
__global__ __launch_bounds__(256) void enrich_kernel(
    const void* __restrict__ ew, const int* __restrict__ flag,
    float* __restrict__ S, int E)
{
    __shared__ float r1[4], r2[4];
    const int isbf = *flag;
    float e1 = 0.f, e2 = 0.f;
    for (int i = blockIdx.x * 256 + threadIdx.x; i < E; i += gridDim.x * 256) {
        float c = isbf ? bf2f(((const unsigned short*)ew)[i]) : ((const float*)ew)[i];
        c = fminf(fmaxf(c, 0.3f), 3.0f);
        float ex = __expf(c);
        e1 += ex;
        e2 += c * ex;
    }
#pragma unroll
    for (int o = 32; o >= 1; o >>= 1) {
        e1 += __shfl_down(e1, o, 64);
        e2 += __shfl_down(e2, o, 64);
    }
    int lane = threadIdx.x & 63;
    int wv = threadIdx.x >> 6;
    if (lane == 0) { r1[wv] = e1; r2[wv] = e2; }
    __syncthreads();
    if (threadIdx.x == 0) {
        atomicAdd(&S[0], r1[0] + r1[1] + r1[2] + r1[3]);
        atomicAdd(&S[1], r2[0] + r2[1] + r2[2] + r2[3]);
    }
}

// ---------- 5. single-pass softmax aggregation (global-max shift), both dirs ----------
// One wave per (dir, node). m = lrelu(gmax + adv) >= all alphas (lrelu is monotone),
// softmax is shift-invariant, exponents bounded in ~[-13, 0] -> no under/overflow.
__global__ __launch_bounds__(256) void agg_kernel(
    const int* __restrict__ off, const int* __restrict__ idx,
    const float* __restrict__ as_all, const float* __restrict__ ad_all,
    const __half* __restrict__ Pall,
    const void* __restrict__ bias,
    const float* __restrict__ S,
    const unsigned int* __restrict__ gmax,
    const void* __restrict__ esc,
    const int* __restrict__ flag,
    void* __restrict__ out, int N)
{
    const int isbf = *flag;
    int q = (blockIdx.x * 256 + threadIdx.x) >> 6;
    int lane = threadIdx.x & 63;     // lane = h*32 + c
    if (q >= 2 * N) return;
    int dir = (q >= N) ? 1 : 0;
    int n = q - dir * N;
    const float* a_s  = as_all + (size_t)dir * 2u * (size_t)N;
    const float* a_d  = ad_all + (size_t)(1 - dir) * 2u * (size_t)N;
    const __half* Psrc = Pall + (size_t)dir * (size_t)N * 64u;
    size_t outOff = dir ? 0u : (size_t)N * 64u;
    const int hi = lane >> 5;
    const int jb = off[q], je = off[q + 1];

    float2 adv2 = *(const float2*)(a_d + (size_t)n * 2);
    const float adv = hi ? adv2.y : adv2.x;
    const float gm  = fdec(gmax[dir * 2 + hi]);
    const float m   = lrelu(gm + adv);

    float2 ass2 = *(const float2*)(a_s + (size_t)n * 2);
    const float pSelf = __expf(lrelu((hi ? ass2.y : ass2.x) + adv) - m);
    float z0 = pSelf, z1 = 0.f;
    float acc0 = pSelf * __half2float(Psrc[(size_t)n * 64 + lane]);
    float acc1 = 0.f;

    int j = jb;
    for (; j + 1 < je; j += 2) {
        int s0 = idx[j], s1 = idx[j + 1];
        float2 a0 = *(const float2*)(a_s + (size_t)s0 * 2);
        float2 a1 = *(const float2*)(a_s + (size_t)s1 * 2);
        float h0 = __half2float(Psrc[(size_t)s0 * 64 + lane]);
        float h1 = __half2float(Psrc[(size_t)s1 * 64 + lane]);
        float p0 = __expf(lrelu((hi ? a0.y : a0.x) + adv) - m);
        float p1 = __expf(lrelu((hi ? a1.y : a1.x) + adv) - m);
        z0 += p0; acc0 = fmaf(p0, h0, acc0);
        z1 += p1; acc1 = fmaf(p1, h1, acc1);
    }
    if (j < je) {
        int s0 = idx[j];
        float2 a0 = *(const float2*)(a_s + (size_t)s0 * 2);
        float h0 = __half2float(Psrc[(size_t)s0 * 64 + lane]);
        float p0 = __expf(lrelu((hi ? a0.y : a0.x) + adv) - m);
        z0 += p0; acc0 = fmaf(p0, h0, acc0);
    }
    float z   = z0 + z1;
    float acc = acc0 + acc1;

    float escv = isbf ? bf2f(((const unsigned short*)esc)[0]) : ((const float*)esc)[0];
    float bv   = isbf ? bf2f(((const unsigned short*)bias)[lane]) : ((const float*)bias)[lane];
    float weighted = S[1] / S[0];
    float factor = 1.f + 0.5f * tanhf(escv) * (weighted - 1.f);
    float o = (acc / (z + 1e-16f) + bv) * factor;
    size_t oi = outOff + (size_t)n * 64 + lane;
    if (isbf) ((unsigned short*)out)[oi] = f2bf(o);
    else      ((float*)out)[oi] = o;
}

extern "C" void kernel_launch(void* const* d_in, const int* in_sizes, int n_in,
                              void* d_out, int out_size, void* d_ws, size_t ws_size,
                              hipStream_t stream)
{
    const void* hx      = d_in[0];
    const void* tx      = d_in[1];
    const int*  eidx    = (const int*)d_in[2];
    const void* ew      = d_in[3];
    const void* Wsrc    = d_in[4];
    const void* Wdst    = d_in[5];
    const void* att_src = d_in[6];
    const void* att_dst = d_in[7];
    const void* bias    = d_in[8];
    const void* esc     = d_in[9];

    const int HC = in_sizes[6];       // 64
    const int D  = in_sizes[4] / HC;  // 256
    const int N  = in_sizes[0] / D;   // 100000
    const int E  = in_sizes[3];       // 1600000
    const int* srce = eidx;
    const int* dste = eidx + E;

    const bool canM = (D == 256) && (HC == 64);
    const int skipBf = canM ? 1 : 0;

    char* wsb = (char*)d_ws;
    size_t o = 0;
    auto alloc = [&](size_t bytes) -> void* {
        void* p = wsb + o;
        o += (bytes + 255) & ~(size_t)255;
        return p;
    };
    __half* Pall  = (__half*)alloc((size_t)2 * N * 64 * 2);   // [Ph; Pt] hs-only, fp16
    float* as_all = (float*)alloc((size_t)2 * N * 2 * 4);
    float* ad_all = (float*)alloc((size_t)2 * N * 2 * 4);
    float* S      = (float*)alloc(2 * 4);
    unsigned int* gmax = (unsigned int*)alloc(4 * 4);
    int*   cnt    = (int*)alloc((size_t)2 * N * 4);
    int*   offp   = (int*)alloc(((size_t)2 * N + 1) * 4);
    int*   cur    = (int*)alloc((size_t)2 * N * 4);
    int*   idx    = (int*)alloc((size_t)2 * E * 4);
    int*   flag   = (int*)alloc(256);
    int*   bsum   = (int*)alloc(256 * 4);
    int*   boff   = (int*)alloc(256 * 4);
    unsigned short* Wfrag = (unsigned short*)alloc((size_t)8 * 8 * 64 * 8 * 2);  // 64KB

    hipMemsetAsync(cnt, 0, (size_t)2 * N * 4, stream);
    hipMemsetAsync(cur, 0, (size_t)2 * N * 4, stream);
    hipMemsetAsync(S, 0, 2 * 4, stream);
    hipMemsetAsync(gmax, 0, 4 * 4, stream);   // encoded 0 == -inf identity

    detect_kernel<<<1, 256, 0, stream>>>((const unsigned int*)hx, 65536, flag);

    dim3 gGemm((N + 63) / 64, 2);
    if (canM) {
        wfrag_kernel<<<16, 256, 0, stream>>>((const unsigned short*)Wsrc,
                                             (const unsigned short*)Wdst, flag, Wfrag);
        gemm_mfma_kernel<<<gGemm, 256, 0, stream>>>(hx, tx, Wfrag, att_src, att_dst,
                                                    flag, Pall, as_all, ad_all, N);
    }
    gemm_elu_kernel<<<gGemm, 256, 0, stream>>>(hx, tx, Wsrc, Wdst, att_src, att_dst,
                                               flag, Pall, as_all, ad_all, N, D, skipBf);
    gmax_kernel<<<256, 256, 0, stream>>>(as_all, gmax, N);
    count_kernel<<<(E + 255) / 256, 256, 0, stream>>>(srce, dste, cnt, N, E);

    const int M = 2 * N;
    int chunk = (M + 255) / 256;
    chunk = (chunk + 255) & ~255;
    const int NB = (M + chunk - 1) / chunk;
    scan_bsum_kernel<<<NB, 256, 0, stream>>>(cnt, M, chunk, bsum);
    scan_boff_kernel<<<1, 256, 0, stream>>>(bsum, NB, boff);
    scan_write_kernel<<<NB, 256, 0, stream>>>(cnt, M, chunk, boff, offp);

    fill_kernel<<<(E + 255) / 256, 256, 0, stream>>>(srce, dste, offp, cur, idx, N, E);
    enrich_kernel<<<512, 256, 0, stream>>>(ew, flag, S, E);

    agg_kernel<<<(2 * N + 3) / 4, 256, 0, stream>>>(offp, idx, as_all, ad_all,
                                                    Pall, bias, S, gmax, esc, flag,
                                                    d_out, N);
}

// Round 5
// 1006.860 us; speedup vs baseline: 1.1196x; 1.0015x over previous
//
#include <hip/hip_runtime.h>
#include <hip/hip_fp16.h>
#include <math.h>

typedef __attribute__((ext_vector_type(8))) short bf16x8;
typedef __attribute__((ext_vector_type(4))) float f32x4;

// ---------- bf16 helpers ----------
__device__ __forceinline__ float bf2f(unsigned short u) {
    union { unsigned int i; float f; } c;
    c.i = ((unsigned int)u) << 16;
    return c.f;
}
__device__ __forceinline__ unsigned short f2bf(float f) {
    union { float f; unsigned int i; } c;
    c.f = f;
    unsigned int b = c.i + 0x7FFFu + ((c.i >> 16) & 1u);  // round-nearest-even
    return (unsigned short)(b >> 16);
}
__device__ __forceinline__ float eluf(float v) {   // jax.nn.elu, alpha=1
    return v > 0.f ? v : (__expf(v) - 1.f);
}
__device__ __forceinline__ float lrelu(float v) {  // leaky_relu slope 0.2
    return v >= 0.f ? v : 0.2f * v;
}
// order-preserving float<->uint encoding for atomicMax
__device__ __forceinline__ unsigned int fenc(float f) {
    union { float f; unsigned int u; } c; c.f = f;
    return (c.u & 0x80000000u) ? ~c.u : (c.u | 0x80000000u);
}
__device__ __forceinline__ float fdec(unsigned int k) {
    union { float f; unsigned int u; } c;
    c.u = (k & 0x80000000u) ? (k ^ 0x80000000u) : ~k;
    return c.f;
}

// ---------- 0. input dtype detection: 1 = bf16, 0 = f32 ----------
__global__ void detect_kernel(const unsigned int* __restrict__ w, int nwords,
                              int* __restrict__ flag)
{
    __shared__ int cnt_s;
    if (threadIdx.x == 0) cnt_s = 0;
    __syncthreads();
    int sane = 0;
    for (int i = threadIdx.x; i < nwords; i += 256) {
        unsigned int lo = w[i] & 0xffffu;
        int e = (int)((lo >> 7) & 0xffu);
        if (e >= 114 && e <= 136) sane++;
    }
    atomicAdd(&cnt_s, sane);
    __syncthreads();
    if (threadIdx.x == 0) *flag = (2 * cnt_s > nwords) ? 1 : 0;
}

// ---------- 1a. W fragment pre-pack for MFMA (bf16 path only) ----------
// Wfrag chunk ch = (ks*8 + t)*64 + l holds 8 bf16: B[k = ks*32 + (l>>4)*8 + j][col = t*16 + (l&15)]
// where B = [Wsrc | Wdst] (256 x 128), row-major per source array (256 x 64 each).
__global__ __launch_bounds__(256) void wfrag_kernel(
    const unsigned short* __restrict__ Wsrc, const unsigned short* __restrict__ Wdst,
    const int* __restrict__ flag, unsigned short* __restrict__ Wfrag)
{
    if (!*flag) return;
    const int nch = 8 * 8 * 64;   // D=256 -> 8 K-steps
    for (int ch = blockIdx.x * 256 + threadIdx.x; ch < nch; ch += gridDim.x * 256) {
        int l  = ch & 63;
        int t  = (ch >> 6) & 7;
        int ks = ch >> 9;
        int col = t * 16 + (l & 15);
        int k0  = ks * 32 + (l >> 4) * 8;
        const unsigned short* W = (col < 64) ? (Wsrc + col) : (Wdst + (col - 64));
#pragma unroll
        for (int j = 0; j < 8; ++j)
            Wfrag[(size_t)ch * 8 + j] = W[(size_t)(k0 + j) * 64];
    }
}

// ---------- 1. ONE fused elu+GEMM+att-projection kernel, device-side dtype dispatch ----------
// Requires D==256, HC==64 (host checks geometry before launching).
// bf16 input -> MFMA path (no LDS); f32 input -> VALU path (LDS tiles).
// P stores ONLY the hs half, fp16: [N][64] per direction.
__global__ __launch_bounds__(256) void gemm_fused_kernel(
    const void* __restrict__ xh, const void* __restrict__ xt,
    const void* __restrict__ Wsrc, const void* __restrict__ Wdst,
    const unsigned short* __restrict__ Wfrag,
    const void* __restrict__ att_src, const void* __restrict__ att_dst,
    const int* __restrict__ flag,
    __half* __restrict__ P, float* __restrict__ as_all, float* __restrict__ ad_all,
    int N)
{
    __shared__ float xs[64][33];    // used by f32 path only (static alloc either way)
    __shared__ float wt[32][128];
    const int isbf = *flag;
    __half* Pout = P + (size_t)blockIdx.y * (size_t)N * 64u;
    float* asO  = as_all + (size_t)blockIdx.y * (size_t)N * 2u;
    float* adO  = ad_all + (size_t)blockIdx.y * (size_t)N * 2u;
    const int tid = threadIdx.x;

    if (isbf) {
        // ================= MFMA path (bf16) =================
        const unsigned short* xv = (const unsigned short*)((blockIdx.y == 0) ? xh : xt);
        const int w   = tid >> 6;
        const int l   = tid & 63;
        const int l15 = l & 15;
        const int lhi = l >> 4;
        const int rowA = blockIdx.x * 64 + w * 16 + l15;
        const bool rv = rowA < N;

        // A fragments for all 8 K-steps, elu applied in-register
        bf16x8 a[8];
#pragma unroll
        for (int ks = 0; ks < 8; ++ks) {
            union { bf16x8 v; unsigned int u[4]; } o;
            if (rv) {
                uint4 raw = *(const uint4*)(xv + (size_t)rowA * 256 + ks * 32 + lhi * 8);
                unsigned int wsr[4] = {raw.x, raw.y, raw.z, raw.w};
#pragma unroll
                for (int i = 0; i < 4; ++i) {
                    float lo = eluf(bf2f((unsigned short)(wsr[i] & 0xffffu)));
                    float hi = eluf(bf2f((unsigned short)(wsr[i] >> 16)));
                    o.u[i] = (unsigned int)f2bf(lo) | ((unsigned int)f2bf(hi) << 16);
                }
            } else {
                o.u[0] = o.u[1] = o.u[2] = o.u[3] = 0u;
            }
            a[ks] = o.v;
        }

        f32x4 acc[8];
#pragma unroll
        for (int t = 0; t < 8; ++t) acc[t] = (f32x4){0.f, 0.f, 0.f, 0.f};

        const bf16x8* wf = (const bf16x8*)Wfrag;
#pragma unroll
        for (int ks = 0; ks < 8; ++ks) {
#pragma unroll
            for (int t = 0; t < 8; ++t) {
                bf16x8 b = wf[(ks * 8 + t) * 64 + l];
                acc[t] = __builtin_amdgcn_mfma_f32_16x16x32_bf16(a[ks], b, acc[t], 0, 0, 0);
            }
        }

        // epilogue: store hs half of P (fp16) + fused att projections
        float asv[4], adv[4];
#pragma unroll
        for (int t = 0; t < 4; ++t) {
            asv[t] = bf2f(((const unsigned short*)att_src)[t * 16 + l15]);
            adv[t] = bf2f(((const unsigned short*)att_dst)[t * 16 + l15]);
        }
        const int rbase = blockIdx.x * 64 + w * 16 + lhi * 4;
#pragma unroll
        for (int reg = 0; reg < 4; ++reg) {
            int row = rbase + reg;
            bool ok = row < N;
            if (ok) {
                __half* p = Pout + (size_t)row * 64 + l15;
#pragma unroll
                for (int t = 0; t < 4; ++t) p[t * 16] = __float2half(acc[t][reg]);
            }
            // head 0: cols 0..31 (tiles 0,1);  head 1: cols 32..63 (tiles 2,3)
            float s0 = acc[0][reg] * asv[0] + acc[1][reg] * asv[1];
            float s1 = acc[2][reg] * asv[2] + acc[3][reg] * asv[3];
            float d0 = acc[4][reg] * adv[0] + acc[5][reg] * adv[1];
            float d1 = acc[6][reg] * adv[2] + acc[7][reg] * adv[3];
#pragma unroll
            for (int o2 = 8; o2 >= 1; o2 >>= 1) {
                s0 += __shfl_xor(s0, o2, 64);
                s1 += __shfl_xor(s1, o2, 64);
                d0 += __shfl_xor(d0, o2, 64);
                d1 += __shfl_xor(d1, o2, 64);
            }
            if (ok && l15 == 0) {
                asO[(size_t)row * 2 + 0] = s0;
                asO[(size_t)row * 2 + 1] = s1;
                adO[(size_t)row * 2 + 0] = d0;
                adO[(size_t)row * 2 + 1] = d1;
            }
        }
        return;
    }

    // ================= f32 VALU path =================
    {
        const int D = 256;
        const void* xv = (blockIdx.y == 0) ? xh : xt;
        const int rowBase = blockIdx.x * 64;
        const int tcx = tid & 15;
        const int tcy = tid >> 4;

        float acc[4][8];
#pragma unroll
        for (int r = 0; r < 4; ++r)
#pragma unroll
            for (int c = 0; c < 8; ++c) acc[r][c] = 0.f;

        for (int kc = 0; kc < D; kc += 32) {
            {
                int row = tid >> 2;
                int kq  = (tid & 3) * 8;
                int r = rowBase + row;
                float v[8];
                if (r < N) {
                    const float* xf = (const float*)xv;
                    const float4* p4 = (const float4*)(xf + (size_t)r * D + kc + kq);
                    float4 f0 = p4[0], f1 = p4[1];
                    v[0] = f0.x; v[1] = f0.y; v[2] = f0.z; v[3] = f0.w;
                    v[4] = f1.x; v[5] = f1.y; v[6] = f1.z; v[7] = f1.w;
#pragma unroll
                    for (int i = 0; i < 8; ++i) v[i] = eluf(v[i]);
                } else {
#pragma unroll
                    for (int i = 0; i < 8; ++i) v[i] = 0.f;
                }
#pragma unroll
                for (int i = 0; i < 8; ++i) xs[row][kq + i] = v[i];
            }
#pragma unroll
            for (int i = 0; i < 2; ++i) {
                int f = (tid + i * 256) * 8;
                int k = f >> 7;
                int c = f & 127;
                const float* Wp = (c < 64)
                    ? ((const float*)Wsrc + (size_t)(kc + k) * 64 + c)
                    : ((const float*)Wdst + (size_t)(kc + k) * 64 + (c - 64));
                const float4* p4 = (const float4*)Wp;
                float4 f0 = p4[0], f1 = p4[1];
                wt[k][c + 0] = f0.x; wt[k][c + 1] = f0.y;
                wt[k][c + 2] = f0.z; wt[k][c + 3] = f0.w;
                wt[k][c + 4] = f1.x; wt[k][c + 5] = f1.y;
                wt[k][c + 6] = f1.z; wt[k][c + 7] = f1.w;
            }
            __syncthreads();
#pragma unroll 8
            for (int k = 0; k < 32; ++k) {
                float xr[4];
#pragma unroll
                for (int r = 0; r < 4; ++r) xr[r] = xs[tcy * 4 + r][k];
                float4 w0 = *(const float4*)&wt[k][tcx * 8];
                float4 w1 = *(const float4*)&wt[k][tcx * 8 + 4];
#pragma unroll
                for (int r = 0; r < 4; ++r) {
                    acc[r][0] += xr[r] * w0.x; acc[r][1] += xr[r] * w0.y;
                    acc[r][2] += xr[r] * w0.z; acc[r][3] += xr[r] * w0.w;
                    acc[r][4] += xr[r] * w1.x; acc[r][5] += xr[r] * w1.y;
                    acc[r][6] += xr[r] * w1.z; acc[r][7] += xr[r] * w1.w;
                }
            }
            __syncthreads();
        }

        float attv[8];
#pragma unroll
        for (int q = 0; q < 8; ++q) {
            int c = tcx * 8 + q;
            attv[q] = (c < 64) ? ((const float*)att_src)[c]
                               : ((const float*)att_dst)[c - 64];
        }

#pragma unroll
        for (int r = 0; r < 4; ++r) {
            int row = rowBase + tcy * 4 + r;
            bool ok = row < N;
            if (ok && tcx < 8) {   // store only hs half (cols 0..63), fp16
                __half* p = Pout + (size_t)row * 64 + tcx * 8;
#pragma unroll
                for (int q = 0; q < 8; ++q) p[q] = __float2half(acc[r][q]);
            }
            float part = 0.f;
#pragma unroll
            for (int q = 0; q < 8; ++q) part += acc[r][q] * attv[q];
            part += __shfl_xor(part, 1, 64);
            part += __shfl_xor(part, 2, 64);
            if (ok && (tcx & 3) == 0) {
                if (tcx == 0)       asO[(size_t)row * 2 + 0] = part;
                else if (tcx == 4)  asO[(size_t)row * 2 + 1] = part;
                else if (tcx == 8)  adO[(size_t)row * 2 + 0] = part;
                else                adO[(size_t)row * 2 + 1] = part;
            }
        }
    }
}

// ---------- 1c. generic fallback (any D mult of 32), both dtypes — only if geometry != reference ----------
__global__ __launch_bounds__(256) void gemm_elu_kernel(
    const void* __restrict__ xh, const void* __restrict__ xt,
    const void* __restrict__ Wsrc, const void* __restrict__ Wdst,
    const void* __restrict__ att_src, const void* __restrict__ att_dst,
    const int* __restrict__ flag,
    __half* __restrict__ P, float* __restrict__ as_all, float* __restrict__ ad_all,
    int N, int D)
{
    const int isbf = *flag;
    __shared__ float xs[64][33];
    __shared__ float wt[32][128];
    const void* xv = (blockIdx.y == 0) ? xh : xt;
    __half* Pout = P + (size_t)blockIdx.y * (size_t)N * 64u;
    float* asO  = as_all + (size_t)blockIdx.y * (size_t)N * 2u;
    float* adO  = ad_all + (size_t)blockIdx.y * (size_t)N * 2u;
    const int rowBase = blockIdx.x * 64;
    const int tid = threadIdx.x;
    const int tcx = tid & 15;
    const int tcy = tid >> 4;

    float acc[4][8];
#pragma unroll
    for (int r = 0; r < 4; ++r)
#pragma unroll
        for (int c = 0; c < 8; ++c) acc[r][c] = 0.f;

    for (int kc = 0; kc < D; kc += 32) {
        {
            int row = tid >> 2;
            int kq  = (tid & 3) * 8;
            int r = rowBase + row;
            float v[8];
            if (r < N) {
                if (isbf) {
                    const unsigned short* xb = (const unsigned short*)xv;
                    uint4 raw = *(const uint4*)(xb + (size_t)r * D + kc + kq);
                    unsigned int ws[4] = {raw.x, raw.y, raw.z, raw.w};
#pragma unroll
                    for (int i = 0; i < 4; ++i) {
                        v[2 * i]     = bf2f((unsigned short)(ws[i] & 0xffffu));
                        v[2 * i + 1] = bf2f((unsigned short)(ws[i] >> 16));
                    }
                } else {
                    const float* xf = (const float*)xv;
                    const float4* p4 = (const float4*)(xf + (size_t)r * D + kc + kq);
                    float4 f0 = p4[0], f1 = p4[1];
                    v[0] = f0.x; v[1] = f0.y; v[2] = f0.z; v[3] = f0.w;
                    v[4] = f1.x; v[5] = f1.y; v[6] = f1.z; v[7] = f1.w;
                }
#pragma unroll
                for (int i = 0; i < 8; ++i) v[i] = eluf(v[i]);
            } else {
#pragma unroll
                for (int i = 0; i < 8; ++i) v[i] = 0.f;
            }
#pragma unroll
            for (int i = 0; i < 8; ++i) xs[row][kq + i] = v[i];
        }
#pragma unroll
        for (int i = 0; i < 2; ++i) {
            int f = (tid + i * 256) * 8;
            int k = f >> 7;
            int c = f & 127;
            float v[8];
            if (isbf) {
                const unsigned short* Wp = (c < 64)
                    ? ((const unsigned short*)Wsrc + (size_t)(kc + k) * 64 + c)
                    : ((const unsigned short*)Wdst + (size_t)(kc + k) * 64 + (c - 64));
                uint4 raw = *(const uint4*)Wp;
                unsigned int ws[4] = {raw.x, raw.y, raw.z, raw.w};
#pragma unroll
                for (int q = 0; q < 4; ++q) {
                    v[2 * q]     = bf2f((unsigned short)(ws[q] & 0xffffu));
                    v[2 * q + 1] = bf2f((unsigned short)(ws[q] >> 16));
                }
            } else {
                const float* Wp = (c < 64)
                    ? ((const float*)Wsrc + (size_t)(kc + k) * 64 + c)
                    : ((const float*)Wdst + (size_t)(kc + k) * 64 + (c - 64));
                const float4* p4 = (const float4*)Wp;
                float4 f0 = p4[0], f1 = p4[1];
                v[0] = f0.x; v[1] = f0.y; v[2] = f0.z; v[3] = f0.w;
                v[4] = f1.x; v[5] = f1.y; v[6] = f1.z; v[7] = f1.w;
            }
#pragma unroll
            for (int q = 0; q < 8; ++q) wt[k][c + q] = v[q];
        }
        __syncthreads();
#pragma unroll 8
        for (int k = 0; k < 32; ++k) {
            float xr[4];
#pragma unroll
            for (int r = 0; r < 4; ++r) xr[r] = xs[tcy * 4 + r][k];
            float4 w0 = *(const float4*)&wt[k][tcx * 8];
            float4 w1 = *(const float4*)&wt[k][tcx * 8 + 4];
#pragma unroll
            for (int r = 0; r < 4; ++r) {
                acc[r][0] += xr[r] * w0.x; acc[r][1] += xr[r] * w0.y;
                acc[r][2] += xr[r] * w0.z; acc[r][3] += xr[r] * w0.w;
                acc[r][4] += xr[r] * w1.x; acc[r][5] += xr[r] * w1.y;
                acc[r][6] += xr[r] * w1.z; acc[r][7] += xr[r] * w1.w;
            }
        }
        __syncthreads();
    }

    float attv[8];
#pragma unroll
    for (int q = 0; q < 8; ++q) {
        int c = tcx * 8 + q;
        if (isbf) attv[q] = (c < 64) ? bf2f(((const unsigned short*)att_src)[c])
                                     : bf2f(((const unsigned short*)att_dst)[c - 64]);
        else      attv[q] = (c < 64) ? ((const float*)att_src)[c]
                                     : ((const float*)att_dst)[c - 64];
    }

#pragma unroll
    for (int r = 0; r < 4; ++r) {
        int row = rowBase + tcy * 4 + r;
        bool ok = row < N;
        if (ok && tcx < 8) {
            __half* p = Pout + (size_t)row * 64 + tcx * 8;
#pragma unroll
            for (int q = 0; q < 8; ++q) p[q] = __float2half(acc[r][q]);
        }
        float part = 0.f;
#pragma unroll
        for (int q = 0; q < 8; ++q) part += acc[r][q] * attv[q];
        part += __shfl_xor(part, 1, 64);
        part += __shfl_xor(part, 2, 64);
        if (ok && (tcx & 3) == 0) {
            if (tcx == 0)       asO[(size_t)row * 2 + 0] = part;
            else if (tcx == 4)  asO[(size_t)row * 2 + 1] = part;
            else if (tcx == 8)  adO[(size_t)row * 2 + 0] = part;
            else                adO[(size_t)row * 2 + 1] = part;
        }
    }
}

// ---------- 2. global per-(dir,head) max of a_s ----------
__global__ __launch_bounds__(256) void gmax_kernel(
    const float* __restrict__ as_all, unsigned int* __restrict__ gmax, int N)
{
    unsigned int k0 = 0, k1 = 0, k2 = 0, k3 = 0;
    const int total = 2 * N;
    for (int i = blockIdx.x * 256 + threadIdx.x; i < total; i += gridDim.x * 256) {
        float2 v = *(const float2*)(as_all + (size_t)i * 2);
        unsigned int ex = fenc(v.x), ey = fenc(v.y);
        if (i < N) { k0 = max(k0, ex); k1 = max(k1, ey); }
        else       { k2 = max(k2, ex); k3 = max(k3, ey); }
    }
#pragma unroll
    for (int o = 32; o >= 1; o >>= 1) {
        k0 = max(k0, (unsigned int)__shfl_xor((int)k0, o, 64));
        k1 = max(k1, (unsigned int)__shfl_xor((int)k1, o, 64));
        k2 = max(k2, (unsigned int)__shfl_xor((int)k2, o, 64));
        k3 = max(k3, (unsigned int)__shfl_xor((int)k3, o, 64));
    }
    if ((threadIdx.x & 63) == 0) {
        atomicMax(&gmax[0], k0);
        atomicMax(&gmax[1], k1);
        atomicMax(&gmax[2], k2);
        atomicMax(&gmax[3], k3);
    }
}

// ---------- 3a. degree histogram (dir1 by dst, dir2 by src) ----------
__global__ void count_kernel(const int* __restrict__ srce, const int* __restrict__ dste,
                             int* __restrict__ cnt, int N, int E)
{
    int e = blockIdx.x * blockDim.x + threadIdx.x;
    if (e >= E) return;
    atomicAdd(&cnt[dste[e]], 1);
    atomicAdd(&cnt[N + srce[e]], 1);
}

// ---------- 3b. multi-block scan: stage 1 ----------
__global__ __launch_bounds__(256) void scan_bsum_kernel(
    const int* __restrict__ cnt, int M, int chunk, int* __restrict__ bsum)
{
    __shared__ int r[4];
    int beg = blockIdx.x * chunk;
    int end = beg + chunk; if (end > M) end = M;
    int s = 0;
    for (int i = beg + threadIdx.x; i < end; i += 256) s += cnt[i];
#pragma unroll
    for (int o = 32; o >= 1; o >>= 1) s += __shfl_down(s, o, 64);
    int lane = threadIdx.x & 63, wv = threadIdx.x >> 6;
    if (lane == 0) r[wv] = s;
    __syncthreads();
    if (threadIdx.x == 0) bsum[blockIdx.x] = r[0] + r[1] + r[2] + r[3];
}

// ---------- stage 2 ----------
__global__ __launch_bounds__(256) void scan_boff_kernel(
    const int* __restrict__ bsum, int NB, int* __restrict__ boff)
{
    __shared__ int s[256];
    int t = threadIdx.x;
    int v = (t < NB) ? bsum[t] : 0;
    s[t] = v;
    __syncthreads();
    for (int o = 1; o < 256; o <<= 1) {
        int x = (t >= o) ? s[t - o] : 0;
        __syncthreads();
        s[t] += x;
        __syncthreads();
    }
    if (t < NB) boff[t] = s[t] - v;
}

// ---------- stage 3 ----------
__global__ __launch_bounds__(256) void scan_write_kernel(
    const int* __restrict__ cnt, int M, int chunk,
    const int* __restrict__ boff, int* __restrict__ off)
{
    __shared__ int s[256];
    int t = threadIdx.x;
    int beg = blockIdx.x * chunk;
    int end = beg + chunk; if (end > M) end = M;
    if (beg >= M) return;
    int running = boff[blockIdx.x];
    for (int base = beg; base < end; base += 256) {
        int i = base + t;
        int v = (i < end) ? cnt[i] : 0;
        s[t] = v;
        __syncthreads();
        for (int o = 1; o < 256; o <<= 1) {
            int x = (t >= o) ? s[t - o] : 0;
            __syncthreads();
            s[t] += x;
            __syncthreads();
        }
        if (i < end) off[i] = running + s[t] - v;
        int total = s[255];
        __syncthreads();
        running += total;
    }
    if (end == M && t == 0) off[M] = running;
}

// ---------- 3c. CSR fill ----------
__global__ void fill_kernel(const int* __restrict__ srce, const int* __restrict__ dste,
                            const int* __restrict__ off, int* __restrict__ cur,
                            int* __restrict__ idx, int N, int E)
{
    int e = blockIdx.x * blockDim.x + threadIdx.x;
    if (e >= E) return;
    int s = srce[e], d = dste[e];
    int p  = atomicAdd(&cur[d], 1);
    idx[off[d] + p] = s;
    int p2 = atomicAdd(&cur[N + s], 1);
    idx[off[N + s] + p2] = d;
}

// ---------- 4. enrichment softmax sums ----------
__global__ __launch_bounds__(256) void enrich_kernel(
    const void* __restrict__ ew, const int* __restrict__ flag,
    float* __restrict__ S, int E)
{
    __shared__ float r1[4], r2[4];
    const int isbf = *flag;
    float e1 = 0.f, e2 = 0.f;
    for (int i = blockIdx.x * 256 + threadIdx.x; i < E; i += gridDim.x * 256) {
        float c = isbf ? bf2f(((const unsigned short*)ew)[i]) : ((const float*)ew)[i];
        c = fminf(fmaxf(c, 0.3f), 3.0f);
        float ex = __expf(c);
        e1 += ex;
        e2 += c * ex;
    }
#pragma unroll
    for (int o = 32; o >= 1; o >>= 1) {
        e1 += __shfl_down(e1, o, 64);
        e2 += __shfl_down(e2, o, 64);
    }
    int lane = threadIdx.x & 63;
    int wv = threadIdx.x >> 6;
    if (lane == 0) { r1[wv] = e1; r2[wv] = e2; }
    __syncthreads();
    if (threadIdx.x == 0) {
        atomicAdd(&S[0], r1[0] + r1[1] + r1[2] + r1[3]);
        atomicAdd(&S[1], r2[0] + r2[1] + r2[2] + r2[3]);
    }
}

// ---------- 5. single-pass softmax aggregation (global-max shift), both dirs ----------
__global__ __launch_bounds__(256) void agg_kernel(
    const int* __restrict__ off, const int* __restrict__ idx,
    const float* __restrict__ as_all, const float* __restrict__ ad_all,
    const __half* __restrict__ Pall,
    const void* __restrict__ bias,
    const float* __restrict__ S,
    const unsigned int* __restrict__ gmax,
    const void* __restrict__ esc,
    const int* __restrict__ flag,
    void* __restrict__ out, int N)
{
    const int isbf = *flag;
    int q = (blockIdx.x * 256 + threadIdx.x) >> 6;
    int lane = threadIdx.x & 63;     // lane = h*32 + c
    if (q >= 2 * N) return;
    int dir = (q >= N) ? 1 : 0;
    int n = q - dir * N;
    const float* a_s  = as_all + (size_t)dir * 2u * (size_t)N;
    const float* a_d  = ad_all + (size_t)(1 - dir) * 2u * (size_t)N;
    const __half* Psrc = Pall + (size_t)dir * (size_t)N * 64u;
    size_t outOff = dir ? 0u : (size_t)N * 64u;
    const int hi = lane >> 5;
    const int jb = off[q], je = off[q + 1];

    float2 adv2 = *(const float2*)(a_d + (size_t)n * 2);
    const float adv = hi ? adv2.y : adv2.x;
    const float gm  = fdec(gmax[dir * 2 + hi]);
    const float m   = lrelu(gm + adv);

    float2 ass2 = *(const float2*)(a_s + (size_t)n * 2);
    const float pSelf = __expf(lrelu((hi ? ass2.y : ass2.x) + adv) - m);
    float z0 = pSelf, z1 = 0.f;
    float acc0 = pSelf * __half2float(Psrc[(size_t)n * 64 + lane]);
    float acc1 = 0.f;

    int j = jb;
    for (; j + 1 < je; j += 2) {
        int s0 = idx[j], s1 = idx[j + 1];
        float2 a0 = *(const float2*)(a_s + (size_t)s0 * 2);
        float2 a1 = *(const float2*)(a_s + (size_t)s1 * 2);
        float h0 = __half2float(Psrc[(size_t)s0 * 64 + lane]);
        float h1 = __half2float(Psrc[(size_t)s1 * 64 + lane]);
        float p0 = __expf(lrelu((hi ? a0.y : a0.x) + adv) - m);
        float p1 = __expf(lrelu((hi ? a1.y : a1.x) + adv) - m);
        z0 += p0; acc0 = fmaf(p0, h0, acc0);
        z1 += p1; acc1 = fmaf(p1, h1, acc1);
    }
    if (j < je) {
        int s0 = idx[j];
        float2 a0 = *(const float2*)(a_s + (size_t)s0 * 2);
        float h0 = __half2float(Psrc[(size_t)s0 * 64 + lane]);
        float p0 = __expf(lrelu((hi ? a0.y : a0.x) + adv) - m);
        z0 += p0; acc0 = fmaf(p0, h0, acc0);
    }
    float z   = z0 + z1;
    float acc = acc0 + acc1;

    float escv = isbf ? bf2f(((const unsigned short*)esc)[0]) : ((const float*)esc)[0];
    float bv   = isbf ? bf2f(((const unsigned short*)bias)[lane]) : ((const float*)bias)[lane];
    float weighted = S[1] / S[0];
    float factor = 1.f + 0.5f * tanhf(escv) * (weighted - 1.f);
    float o = (acc / (z + 1e-16f) + bv) * factor;
    size_t oi = outOff + (size_t)n * 64 + lane;
    if (isbf) ((unsigned short*)out)[oi] = f2bf(o);
    else      ((float*)out)[oi] = o;
}

extern "C" void kernel_launch(void* const* d_in, const int* in_sizes, int n_in,
                              void* d_out, int out_size, void* d_ws, size_t ws_size,
                              hipStream_t stream)
{
    const void* hx      = d_in[0];
    const void* tx      = d_in[1];
    const int*  eidx    = (const int*)d_in[2];
    const void* ew      = d_in[3];
    const void* Wsrc    = d_in[4];
    const void* Wdst    = d_in[5];
    const void* att_src = d_in[6];
    const void* att_dst = d_in[7];
    const void* bias    = d_in[8];
    const void* esc     = d_in[9];

    const int HC = in_sizes[6];       // 64
    const int D  = in_sizes[4] / HC;  // 256
    const int N  = in_sizes[0] / D;   // 100000
    const int E  = in_sizes[3];       // 1600000
    const int* srce = eidx;
    const int* dste = eidx + E;

    const bool canM = (D == 256) && (HC == 64);

    char* wsb = (char*)d_ws;
    size_t o = 0;
    auto alloc = [&](size_t bytes) -> void* {
        void* p = wsb + o;
        o += (bytes + 255) & ~(size_t)255;
        return p;
    };
    __half* Pall  = (__half*)alloc((size_t)2 * N * 64 * 2);   // [Ph; Pt] hs-only, fp16
    float* as_all = (float*)alloc((size_t)2 * N * 2 * 4);
    float* ad_all = (float*)alloc((size_t)2 * N * 2 * 4);
    float* S      = (float*)alloc(2 * 4);
    unsigned int* gmax = (unsigned int*)alloc(4 * 4);
    int*   cnt    = (int*)alloc((size_t)2 * N * 4);
    int*   offp   = (int*)alloc(((size_t)2 * N + 1) * 4);
    int*   cur    = (int*)alloc((size_t)2 * N * 4);
    int*   idx    = (int*)alloc((size_t)2 * E * 4);
    int*   flag   = (int*)alloc(256);
    int*   bsum   = (int*)alloc(256 * 4);
    int*   boff   = (int*)alloc(256 * 4);
    unsigned short* Wfrag = (unsigned short*)alloc((size_t)8 * 8 * 64 * 8 * 2);  // 64KB

    hipMemsetAsync(cnt, 0, (size_t)2 * N * 4, stream);
    hipMemsetAsync(cur, 0, (size_t)2 * N * 4, stream);
    hipMemsetAsync(S, 0, 2 * 4, stream);
    hipMemsetAsync(gmax, 0, 4 * 4, stream);   // encoded 0 == -inf identity

    detect_kernel<<<1, 256, 0, stream>>>((const unsigned int*)hx, 65536, flag);

    dim3 gGemm((N + 63) / 64, 2);
    if (canM) {
        wfrag_kernel<<<16, 256, 0, stream>>>((const unsigned short*)Wsrc,
                                             (const unsigned short*)Wdst, flag, Wfrag);
        gemm_fused_kernel<<<gGemm, 256, 0, stream>>>(hx, tx, Wsrc, Wdst, Wfrag,
                                                     att_src, att_dst, flag,
                                                     Pall, as_all, ad_all, N);
    } else {
        gemm_elu_kernel<<<gGemm, 256, 0, stream>>>(hx, tx, Wsrc, Wdst, att_src, att_dst,
                                                   flag, Pall, as_all, ad_all, N, D);
    }
    gmax_kernel<<<256, 256, 0, stream>>>(as_all, gmax, N);
    count_kernel<<<(E + 255) / 256, 256, 0, stream>>>(srce, dste, cnt, N, E);

    const int M = 2 * N;
    int chunk = (M + 255) / 256;
    chunk = (chunk + 255) & ~255;
    const int NB = (M + chunk - 1) / chunk;
    scan_bsum_kernel<<<NB, 256, 0, stream>>>(cnt, M, chunk, bsum);
    scan_boff_kernel<<<1, 256, 0, stream>>>(bsum, NB, boff);
    scan_write_kernel<<<NB, 256, 0, stream>>>(cnt, M, chunk, boff, offp);

    fill_kernel<<<(E + 255) / 256, 256, 0, stream>>>(srce, dste, offp, cur, idx, N, E);
    enrich_kernel<<<512, 256, 0, stream>>>(ew, flag, S, E);

    agg_kernel<<<(2 * N + 3) / 4, 256, 0, stream>>>(offp, idx, as_all, ad_all,
                                                    Pall, bias, S, gmax, esc, flag,
                                                    d_out, N);
}

// Round 6
// 960.024 us; speedup vs baseline: 1.1742x; 1.0488x over previous
//
#include <hip/hip_runtime.h>
#include <hip/hip_fp16.h>
#include <math.h>

typedef __attribute__((ext_vector_type(8))) short bf16x8;
typedef __attribute__((ext_vector_type(4))) float f32x4;

// ---------- bf16 helpers ----------
__device__ __forceinline__ float bf2f(unsigned short u) {
    union { unsigned int i; float f; } c;
    c.i = ((unsigned int)u) << 16;
    return c.f;
}
__device__ __forceinline__ unsigned short f2bf(float f) {
    union { float f; unsigned int i; } c;
    c.f = f;
    unsigned int b = c.i + 0x7FFFu + ((c.i >> 16) & 1u);  // round-nearest-even
    return (unsigned short)(b >> 16);
}
__device__ __forceinline__ float eluf(float v) {   // jax.nn.elu, alpha=1
    return v > 0.f ? v : (__expf(v) - 1.f);
}
__device__ __forceinline__ float lrelu(float v) {  // leaky_relu slope 0.2
    return v >= 0.f ? v : 0.2f * v;
}
// order-preserving float<->uint encoding for atomicMax
__device__ __forceinline__ unsigned int fenc(float f) {
    union { float f; unsigned int u; } c; c.f = f;
    return (c.u & 0x80000000u) ? ~c.u : (c.u | 0x80000000u);
}
__device__ __forceinline__ float fdec(unsigned int k) {
    union { float f; unsigned int u; } c;
    c.u = (k & 0x80000000u) ? (k ^ 0x80000000u) : ~k;
    return c.f;
}

// ---------- 0. input dtype detection: 1 = bf16, 0 = f32 ----------
__global__ void detect_kernel(const unsigned int* __restrict__ w, int nwords,
                              int* __restrict__ flag)
{
    __shared__ int cnt_s;
    if (threadIdx.x == 0) cnt_s = 0;
    __syncthreads();
    int sane = 0;
    for (int i = threadIdx.x; i < nwords; i += 256) {
        unsigned int lo = w[i] & 0xffffu;
        int e = (int)((lo >> 7) & 0xffu);
        if (e >= 114 && e <= 136) sane++;
    }
    atomicAdd(&cnt_s, sane);
    __syncthreads();
    if (threadIdx.x == 0) *flag = (2 * cnt_s > nwords) ? 1 : 0;
}

// ---------- 1a. W fragment pre-pack (hi/lo split for f32 inputs) ----------
// chunk ch = (ks*8 + t)*64 + l holds 8 bf16: B[k = ks*32 + (l>>4)*8 + j][col = t*16 + (l&15)]
// B = [Wsrc | Wdst] (256 x 128).  f32 source: Whi = bf16(w), Wlo = bf16(w - Whi).
__global__ __launch_bounds__(256) void wfrag_kernel(
    const void* __restrict__ Wsrc, const void* __restrict__ Wdst,
    const int* __restrict__ flag,
    unsigned short* __restrict__ Whi, unsigned short* __restrict__ Wlo)
{
    const int isbf = *flag;
    const int nch = 8 * 8 * 64;   // D=256 -> 8 K-steps
    for (int ch = blockIdx.x * 256 + threadIdx.x; ch < nch; ch += gridDim.x * 256) {
        int l  = ch & 63;
        int t  = (ch >> 6) & 7;
        int ks = ch >> 9;
        int col = t * 16 + (l & 15);
        int k0  = ks * 32 + (l >> 4) * 8;
        if (isbf) {
            const unsigned short* W = (col < 64)
                ? ((const unsigned short*)Wsrc + col)
                : ((const unsigned short*)Wdst + (col - 64));
#pragma unroll
            for (int j = 0; j < 8; ++j) {
                Whi[(size_t)ch * 8 + j] = W[(size_t)(k0 + j) * 64];
                Wlo[(size_t)ch * 8 + j] = 0;
            }
        } else {
            const float* W = (col < 64)
                ? ((const float*)Wsrc + col)
                : ((const float*)Wdst + (col - 64));
#pragma unroll
            for (int j = 0; j < 8; ++j) {
                float wv = W[(size_t)(k0 + j) * 64];
                unsigned short h = f2bf(wv);
                Whi[(size_t)ch * 8 + j] = h;
                Wlo[(size_t)ch * 8 + j] = f2bf(wv - bf2f(h));
            }
        }
    }
}

// ---------- 1. MFMA fused elu+GEMM+att-projection (both dtypes, D==256, HC==64) ----------
// bf16 input: 1-term MFMA.  f32 input: split-bf16 3-term MFMA (hi*Whi + lo*Whi + hi*Wlo),
// residual lo*Wlo ~ 2^-18 relative -> near-f32 accuracy.  No LDS.
// A frag (16x16x32): row = l&15, k = (l>>4)*8 + j.  B frag: col = l&15, same k.
// C/D: col = l&15, row = (l>>4)*4 + reg.
// P stores ONLY the hs half, fp16: [N][64] per direction.
__global__ __launch_bounds__(256) void gemm_fused_kernel(
    const void* __restrict__ xh, const void* __restrict__ xt,
    const unsigned short* __restrict__ Whi, const unsigned short* __restrict__ Wlo,
    const void* __restrict__ att_src, const void* __restrict__ att_dst,
    const int* __restrict__ flag,
    __half* __restrict__ P, float* __restrict__ as_all, float* __restrict__ ad_all,
    int N)
{
    const int isbf = *flag;
    __half* Pout = P + (size_t)blockIdx.y * (size_t)N * 64u;
    float* asO  = as_all + (size_t)blockIdx.y * (size_t)N * 2u;
    float* adO  = ad_all + (size_t)blockIdx.y * (size_t)N * 2u;
    const int tid = threadIdx.x;
    const int w   = tid >> 6;
    const int l   = tid & 63;
    const int l15 = l & 15;
    const int lhi = l >> 4;
    const int rowA = blockIdx.x * 64 + w * 16 + l15;
    const bool rv = rowA < N;

    bf16x8 ahi[8], alo[8];
    if (isbf) {
        const unsigned short* xv = (const unsigned short*)((blockIdx.y == 0) ? xh : xt);
#pragma unroll
        for (int ks = 0; ks < 8; ++ks) {
            union { bf16x8 v; unsigned int u[4]; } o;
            if (rv) {
                uint4 raw = *(const uint4*)(xv + (size_t)rowA * 256 + ks * 32 + lhi * 8);
                unsigned int wsr[4] = {raw.x, raw.y, raw.z, raw.w};
#pragma unroll
                for (int i = 0; i < 4; ++i) {
                    float lo = eluf(bf2f((unsigned short)(wsr[i] & 0xffffu)));
                    float hi = eluf(bf2f((unsigned short)(wsr[i] >> 16)));
                    o.u[i] = (unsigned int)f2bf(lo) | ((unsigned int)f2bf(hi) << 16);
                }
            } else {
                o.u[0] = o.u[1] = o.u[2] = o.u[3] = 0u;
            }
            ahi[ks] = o.v;
            alo[ks] = o.v;   // unused on bf16 path
        }
    } else {
        const float* xv = (const float*)((blockIdx.y == 0) ? xh : xt);
#pragma unroll
        for (int ks = 0; ks < 8; ++ks) {
            union { bf16x8 v; unsigned int u[4]; } oh, ol;
            if (rv) {
                const float4* px = (const float4*)(xv + (size_t)rowA * 256 + ks * 32 + lhi * 8);
                float4 f0 = px[0], f1 = px[1];
                float v[8] = {f0.x, f0.y, f0.z, f0.w, f1.x, f1.y, f1.z, f1.w};
#pragma unroll
                for (int i = 0; i < 8; ++i) v[i] = eluf(v[i]);
#pragma unroll
                for (int i = 0; i < 4; ++i) {
                    unsigned short h0 = f2bf(v[2 * i]);
                    unsigned short h1 = f2bf(v[2 * i + 1]);
                    unsigned short l0 = f2bf(v[2 * i]     - bf2f(h0));
                    unsigned short l1 = f2bf(v[2 * i + 1] - bf2f(h1));
                    oh.u[i] = (unsigned int)h0 | ((unsigned int)h1 << 16);
                    ol.u[i] = (unsigned int)l0 | ((unsigned int)l1 << 16);
                }
            } else {
                oh.u[0] = oh.u[1] = oh.u[2] = oh.u[3] = 0u;
                ol.u[0] = ol.u[1] = ol.u[2] = ol.u[3] = 0u;
            }
            ahi[ks] = oh.v;
            alo[ks] = ol.v;
        }
    }

    f32x4 acc[8];
#pragma unroll
    for (int t = 0; t < 8; ++t) acc[t] = (f32x4){0.f, 0.f, 0.f, 0.f};

    const bf16x8* wfh = (const bf16x8*)Whi;
    const bf16x8* wfl = (const bf16x8*)Wlo;
    if (isbf) {
#pragma unroll
        for (int ks = 0; ks < 8; ++ks) {
#pragma unroll
            for (int t = 0; t < 8; ++t) {
                bf16x8 b = wfh[(ks * 8 + t) * 64 + l];
                acc[t] = __builtin_amdgcn_mfma_f32_16x16x32_bf16(ahi[ks], b, acc[t], 0, 0, 0);
            }
        }
    } else {
#pragma unroll
        for (int ks = 0; ks < 8; ++ks) {
#pragma unroll
            for (int t = 0; t < 8; ++t) {
                bf16x8 bh = wfh[(ks * 8 + t) * 64 + l];
                bf16x8 bl = wfl[(ks * 8 + t) * 64 + l];
                acc[t] = __builtin_amdgcn_mfma_f32_16x16x32_bf16(ahi[ks], bh, acc[t], 0, 0, 0);
                acc[t] = __builtin_amdgcn_mfma_f32_16x16x32_bf16(alo[ks], bh, acc[t], 0, 0, 0);
                acc[t] = __builtin_amdgcn_mfma_f32_16x16x32_bf16(ahi[ks], bl, acc[t], 0, 0, 0);
            }
        }
    }

    // epilogue: store hs half of P (fp16) + fused att projections
    float asv[4], adv[4];
#pragma unroll
    for (int t = 0; t < 4; ++t) {
        if (isbf) {
            asv[t] = bf2f(((const unsigned short*)att_src)[t * 16 + l15]);
            adv[t] = bf2f(((const unsigned short*)att_dst)[t * 16 + l15]);
        } else {
            asv[t] = ((const float*)att_src)[t * 16 + l15];
            adv[t] = ((const float*)att_dst)[t * 16 + l15];
        }
    }
    const int rbase = blockIdx.x * 64 + w * 16 + lhi * 4;
#pragma unroll
    for (int reg = 0; reg < 4; ++reg) {
        int row = rbase + reg;
        bool ok = row < N;
        if (ok) {
            __half* p = Pout + (size_t)row * 64 + l15;
#pragma unroll
            for (int t = 0; t < 4; ++t) p[t * 16] = __float2half(acc[t][reg]);
        }
        // head 0: cols 0..31 (tiles 0,1);  head 1: cols 32..63 (tiles 2,3)
        float s0 = acc[0][reg] * asv[0] + acc[1][reg] * asv[1];
        float s1 = acc[2][reg] * asv[2] + acc[3][reg] * asv[3];
        float d0 = acc[4][reg] * adv[0] + acc[5][reg] * adv[1];
        float d1 = acc[6][reg] * adv[2] + acc[7][reg] * adv[3];
#pragma unroll
        for (int o2 = 8; o2 >= 1; o2 >>= 1) {
            s0 += __shfl_xor(s0, o2, 64);
            s1 += __shfl_xor(s1, o2, 64);
            d0 += __shfl_xor(d0, o2, 64);
            d1 += __shfl_xor(d1, o2, 64);
        }
        if (ok && l15 == 0) {
            asO[(size_t)row * 2 + 0] = s0;
            asO[(size_t)row * 2 + 1] = s1;
            adO[(size_t)row * 2 + 0] = d0;
            adO[(size_t)row * 2 + 1] = d1;
        }
    }
}

// ---------- 1c. generic fallback (any D mult of 32), both dtypes — non-reference geometry ----------
__global__ __launch_bounds__(256) void gemm_elu_kernel(
    const void* __restrict__ xh, const void* __restrict__ xt,
    const void* __restrict__ Wsrc, const void* __restrict__ Wdst,
    const void* __restrict__ att_src, const void* __restrict__ att_dst,
    const int* __restrict__ flag,
    __half* __restrict__ P, float* __restrict__ as_all, float* __restrict__ ad_all,
    int N, int D)
{
    const int isbf = *flag;
    __shared__ float xs[64][33];
    __shared__ float wt[32][128];
    const void* xv = (blockIdx.y == 0) ? xh : xt;
    __half* Pout = P + (size_t)blockIdx.y * (size_t)N * 64u;
    float* asO  = as_all + (size_t)blockIdx.y * (size_t)N * 2u;
    float* adO  = ad_all + (size_t)blockIdx.y * (size_t)N * 2u;
    const int rowBase = blockIdx.x * 64;
    const int tid = threadIdx.x;
    const int tcx = tid & 15;
    const int tcy = tid >> 4;

    float acc[4][8];
#pragma unroll
    for (int r = 0; r < 4; ++r)
#pragma unroll
        for (int c = 0; c < 8; ++c) acc[r][c] = 0.f;

    for (int kc = 0; kc < D; kc += 32) {
        {
            int row = tid >> 2;
            int kq  = (tid & 3) * 8;
            int r = rowBase + row;
            float v[8];
            if (r < N) {
                if (isbf) {
                    const unsigned short* xb = (const unsigned short*)xv;
                    uint4 raw = *(const uint4*)(xb + (size_t)r * D + kc + kq);
                    unsigned int ws[4] = {raw.x, raw.y, raw.z, raw.w};
#pragma unroll
                    for (int i = 0; i < 4; ++i) {
                        v[2 * i]     = bf2f((unsigned short)(ws[i] & 0xffffu));
                        v[2 * i + 1] = bf2f((unsigned short)(ws[i] >> 16));
                    }
                } else {
                    const float* xf = (const float*)xv;
                    const float4* p4 = (const float4*)(xf + (size_t)r * D + kc + kq);
                    float4 f0 = p4[0], f1 = p4[1];
                    v[0] = f0.x; v[1] = f0.y; v[2] = f0.z; v[3] = f0.w;
                    v[4] = f1.x; v[5] = f1.y; v[6] = f1.z; v[7] = f1.w;
                }
#pragma unroll
                for (int i = 0; i < 8; ++i) v[i] = eluf(v[i]);
            } else {
#pragma unroll
                for (int i = 0; i < 8; ++i) v[i] = 0.f;
            }
#pragma unroll
            for (int i = 0; i < 8; ++i) xs[row][kq + i] = v[i];
        }
#pragma unroll
        for (int i = 0; i < 2; ++i) {
            int f = (tid + i * 256) * 8;
            int k = f >> 7;
            int c = f & 127;
            float v[8];
            if (isbf) {
                const unsigned short* Wp = (c < 64)
                    ? ((const unsigned short*)Wsrc + (size_t)(kc + k) * 64 + c)
                    : ((const unsigned short*)Wdst + (size_t)(kc + k) * 64 + (c - 64));
                uint4 raw = *(const uint4*)Wp;
                unsigned int ws[4] = {raw.x, raw.y, raw.z, raw.w};
#pragma unroll
                for (int q = 0; q < 4; ++q) {
                    v[2 * q]     = bf2f((unsigned short)(ws[q] & 0xffffu));
                    v[2 * q + 1] = bf2f((unsigned short)(ws[q] >> 16));
                }
            } else {
                const float* Wp = (c < 64)
                    ? ((const float*)Wsrc + (size_t)(kc + k) * 64 + c)
                    : ((const float*)Wdst + (size_t)(kc + k) * 64 + (c - 64));
                const float4* p4 = (const float4*)Wp;
                float4 f0 = p4[0], f1 = p4[1];
                v[0] = f0.x; v[1] = f0.y; v[2] = f0.z; v[3] = f0.w;
                v[4] = f1.x; v[5] = f1.y; v[6] = f1.z; v[7] = f1.w;
            }
#pragma unroll
            for (int q = 0; q < 8; ++q) wt[k][c + q] = v[q];
        }
        __syncthreads();
#pragma unroll 8
        for (int k = 0; k < 32; ++k) {
            float xr[4];
#pragma unroll
            for (int r = 0; r < 4; ++r) xr[r] = xs[tcy * 4 + r][k];
            float4 w0 = *(const float4*)&wt[k][tcx * 8];
            float4 w1 = *(const float4*)&wt[k][tcx * 8 + 4];
#pragma unroll
            for (int r = 0; r < 4; ++r) {
                acc[r][0] += xr[r] * w0.x; acc[r][1] += xr[r] * w0.y;
                acc[r][2] += xr[r] * w0.z; acc[r][3] += xr[r] * w0.w;
                acc[r][4] += xr[r] * w1.x; acc[r][5] += xr[r] * w1.y;
                acc[r][6] += xr[r] * w1.z; acc[r][7] += xr[r] * w1.w;
            }
        }
        __syncthreads();
    }

    float attv[8];
#pragma unroll
    for (int q = 0; q < 8; ++q) {
        int c = tcx * 8 + q;
        if (isbf) attv[q] = (c < 64) ? bf2f(((const unsigned short*)att_src)[c])
                                     : bf2f(((const unsigned short*)att_dst)[c - 64]);
        else      attv[q] = (c < 64) ? ((const float*)att_src)[c]
                                     : ((const float*)att_dst)[c - 64];
    }

#pragma unroll
    for (int r = 0; r < 4; ++r) {
        int row = rowBase + tcy * 4 + r;
        bool ok = row < N;
        if (ok && tcx < 8) {
            __half* p = Pout + (size_t)row * 64 + tcx * 8;
#pragma unroll
            for (int q = 0; q < 8; ++q) p[q] = __float2half(acc[r][q]);
        }
        float part = 0.f;
#pragma unroll
        for (int q = 0; q < 8; ++q) part += acc[r][q] * attv[q];
        part += __shfl_xor(part, 1, 64);
        part += __shfl_xor(part, 2, 64);
        if (ok && (tcx & 3) == 0) {
            if (tcx == 0)       asO[(size_t)row * 2 + 0] = part;
            else if (tcx == 4)  asO[(size_t)row * 2 + 1] = part;
            else if (tcx == 8)  adO[(size_t)row * 2 + 0] = part;
            else                adO[(size_t)row * 2 + 1] = part;
        }
    }
}

// ---------- 2. global per-(dir,head) max of a_s ----------
__global__ __launch_bounds__(256) void gmax_kernel(
    const float* __restrict__ as_all, unsigned int* __restrict__ gmax, int N)
{
    unsigned int k0 = 0, k1 = 0, k2 = 0, k3 = 0;
    const int total = 2 * N;
    for (int i = blockIdx.x * 256 + threadIdx.x; i < total; i += gridDim.x * 256) {
        float2 v = *(const float2*)(as_all + (size_t)i * 2);
        unsigned int ex = fenc(v.x), ey = fenc(v.y);
        if (i < N) { k0 = max(k0, ex); k1 = max(k1, ey); }
        else       { k2 = max(k2, ex); k3 = max(k3, ey); }
    }
#pragma unroll
    for (int o = 32; o >= 1; o >>= 1) {
        k0 = max(k0, (unsigned int)__shfl_xor((int)k0, o, 64));
        k1 = max(k1, (unsigned int)__shfl_xor((int)k1, o, 64));
        k2 = max(k2, (unsigned int)__shfl_xor((int)k2, o, 64));
        k3 = max(k3, (unsigned int)__shfl_xor((int)k3, o, 64));
    }
    if ((threadIdx.x & 63) == 0) {
        atomicMax(&gmax[0], k0);
        atomicMax(&gmax[1], k1);
        atomicMax(&gmax[2], k2);
        atomicMax(&gmax[3], k3);
    }
}

// ---------- 3a. degree histogram (dir1 by dst, dir2 by src) ----------
__global__ void count_kernel(const int* __restrict__ srce, const int* __restrict__ dste,
                             int* __restrict__ cnt, int N, int E)
{
    int e = blockIdx.x * blockDim.x + threadIdx.x;
    if (e >= E) return;
    atomicAdd(&cnt[dste[e]], 1);
    atomicAdd(&cnt[N + srce[e]], 1);
}

// ---------- 3b. multi-block scan: stage 1 ----------
__global__ __launch_bounds__(256) void scan_bsum_kernel(
    const int* __restrict__ cnt, int M, int chunk, int* __restrict__ bsum)
{
    __shared__ int r[4];
    int beg = blockIdx.x * chunk;
    int end = beg + chunk; if (end > M) end = M;
    int s = 0;
    for (int i = beg + threadIdx.x; i < end; i += 256) s += cnt[i];
#pragma unroll
    for (int o = 32; o >= 1; o >>= 1) s += __shfl_down(s, o, 64);
    int lane = threadIdx.x & 63, wv = threadIdx.x >> 6;
    if (lane == 0) r[wv] = s;
    __syncthreads();
    if (threadIdx.x == 0) bsum[blockIdx.x] = r[0] + r[1] + r[2] + r[3];
}

// ---------- stage 2 ----------
__global__ __launch_bounds__(256) void scan_boff_kernel(
    const int* __restrict__ bsum, int NB, int* __restrict__ boff)
{
    __shared__ int s[256];
    int t = threadIdx.x;
    int v = (t < NB) ? bsum[t] : 0;
    s[t] = v;
    __syncthreads();
    for (int o = 1; o < 256; o <<= 1) {
        int x = (t >= o) ? s[t - o] : 0;
        __syncthreads();
        s[t] += x;
        __syncthreads();
    }
    if (t < NB) boff[t] = s[t] - v;
}

// ---------- stage 3 ----------
__global__ __launch_bounds__(256) void scan_write_kernel(
    const int* __restrict__ cnt, int M, int chunk,
    const int* __restrict__ boff, int* __restrict__ off)
{
    __shared__ int s[256];
    int t = threadIdx.x;
    int beg = blockIdx.x * chunk;
    int end = beg + chunk; if (end > M) end = M;
    if (beg >= M) return;
    int running = boff[blockIdx.x];
    for (int base = beg; base < end; base += 256) {
        int i = base + t;
        int v = (i < end) ? cnt[i] : 0;
        s[t] = v;
        __syncthreads();
        for (int o = 1; o < 256; o <<= 1) {
            int x = (t >= o) ? s[t - o] : 0;
            __syncthreads();
            s[t] += x;
            __syncthreads();
        }
        if (i < end) off[i] = running + s[t] - v;
        int total = s[255];
        __syncthreads();
        running += total;
    }
    if (end == M && t == 0) off[M] = running;
}

// ---------- 3c. CSR fill ----------
__global__ void fill_kernel(const int* __restrict__ srce, const int* __restrict__ dste,
                            const int* __restrict__ off, int* __restrict__ cur,
                            int* __restrict__ idx, int N, int E)
{
    int e = blockIdx.x * blockDim.x + threadIdx.x;
    if (e >= E) return;
    int s = srce[e], d = dste[e];
    int p  = atomicAdd(&cur[d], 1);
    idx[off[d] + p] = s;
    int p2 = atomicAdd(&cur[N + s], 1);
    idx[off[N + s] + p2] = d;
}

// ---------- 4. enrichment softmax sums ----------
__global__ __launch_bounds__(256) void enrich_kernel(
    const void* __restrict__ ew, const int* __restrict__ flag,
    float* __restrict__ S, int E)
{
    __shared__ float r1[4], r2[4];
    const int isbf = *flag;
    float e1 = 0.f, e2 = 0.f;
    for (int i = blockIdx.x * 256 + threadIdx.x; i < E; i += gridDim.x * 256) {
        float c = isbf ? bf2f(((const unsigned short*)ew)[i]) : ((const float*)ew)[i];
        c = fminf(fmaxf(c, 0.3f), 3.0f);
        float ex = __expf(c);
        e1 += ex;
        e2 += c * ex;
    }
#pragma unroll
    for (int o = 32; o >= 1; o >>= 1) {
        e1 += __shfl_down(e1, o, 64);
        e2 += __shfl_down(e2, o, 64);
    }
    int lane = threadIdx.x & 63;
    int wv = threadIdx.x >> 6;
    if (lane == 0) { r1[wv] = e1; r2[wv] = e2; }
    __syncthreads();
    if (threadIdx.x == 0) {
        atomicAdd(&S[0], r1[0] + r1[1] + r1[2] + r1[3]);
        atomicAdd(&S[1], r2[0] + r2[1] + r2[2] + r2[3]);
    }
}

// ---------- 5. single-pass softmax aggregation (global-max shift), both dirs ----------
__global__ __launch_bounds__(256) void agg_kernel(
    const int* __restrict__ off, const int* __restrict__ idx,
    const float* __restrict__ as_all, const float* __restrict__ ad_all,
    const __half* __restrict__ Pall,
    const void* __restrict__ bias,
    const float* __restrict__ S,
    const unsigned int* __restrict__ gmax,
    const void* __restrict__ esc,
    const int* __restrict__ flag,
    void* __restrict__ out, int N)
{
    const int isbf = *flag;
    int q = (blockIdx.x * 256 + threadIdx.x) >> 6;
    int lane = threadIdx.x & 63;     // lane = h*32 + c
    if (q >= 2 * N) return;
    int dir = (q >= N) ? 1 : 0;
    int n = q - dir * N;
    const float* a_s  = as_all + (size_t)dir * 2u * (size_t)N;
    const float* a_d  = ad_all + (size_t)(1 - dir) * 2u * (size_t)N;
    const __half* Psrc = Pall + (size_t)dir * (size_t)N * 64u;
    size_t outOff = dir ? 0u : (size_t)N * 64u;
    const int hi = lane >> 5;
    const int jb = off[q], je = off[q + 1];

    float2 adv2 = *(const float2*)(a_d + (size_t)n * 2);
    const float adv = hi ? adv2.y : adv2.x;
    const float gm  = fdec(gmax[dir * 2 + hi]);
    const float m   = lrelu(gm + adv);

    float2 ass2 = *(const float2*)(a_s + (size_t)n * 2);
    const float pSelf = __expf(lrelu((hi ? ass2.y : ass2.x) + adv) - m);
    float z0 = pSelf, z1 = 0.f;
    float acc0 = pSelf * __half2float(Psrc[(size_t)n * 64 + lane]);
    float acc1 = 0.f;

    int j = jb;
    for (; j + 1 < je; j += 2) {
        int s0 = idx[j], s1 = idx[j + 1];
        float2 a0 = *(const float2*)(a_s + (size_t)s0 * 2);
        float2 a1 = *(const float2*)(a_s + (size_t)s1 * 2);
        float h0 = __half2float(Psrc[(size_t)s0 * 64 + lane]);
        float h1 = __half2float(Psrc[(size_t)s1 * 64 + lane]);
        float p0 = __expf(lrelu((hi ? a0.y : a0.x) + adv) - m);
        float p1 = __expf(lrelu((hi ? a1.y : a1.x) + adv) - m);
        z0 += p0; acc0 = fmaf(p0, h0, acc0);
        z1 += p1; acc1 = fmaf(p1, h1, acc1);
    }
    if (j < je) {
        int s0 = idx[j];
        float2 a0 = *(const float2*)(a_s + (size_t)s0 * 2);
        float h0 = __half2float(Psrc[(size_t)s0 * 64 + lane]);
        float p0 = __expf(lrelu((hi ? a0.y : a0.x) + adv) - m);
        z0 += p0; acc0 = fmaf(p0, h0, acc0);
    }
    float z   = z0 + z1;
    float acc = acc0 + acc1;

    float escv = isbf ? bf2f(((const unsigned short*)esc)[0]) : ((const float*)esc)[0];
    float bv   = isbf ? bf2f(((const unsigned short*)bias)[lane]) : ((const float*)bias)[lane];
    float weighted = S[1] / S[0];
    float factor = 1.f + 0.5f * tanhf(escv) * (weighted - 1.f);
    float o = (acc / (z + 1e-16f) + bv) * factor;
    size_t oi = outOff + (size_t)n * 64 + lane;
    if (isbf) ((unsigned short*)out)[oi] = f2bf(o);
    else      ((float*)out)[oi] = o;
}

extern "C" void kernel_launch(void* const* d_in, const int* in_sizes, int n_in,
                              void* d_out, int out_size, void* d_ws, size_t ws_size,
                              hipStream_t stream)
{
    const void* hx      = d_in[0];
    const void* tx      = d_in[1];
    const int*  eidx    = (const int*)d_in[2];
    const void* ew      = d_in[3];
    const void* Wsrc    = d_in[4];
    const void* Wdst    = d_in[5];
    const void* att_src = d_in[6];
    const void* att_dst = d_in[7];
    const void* bias    = d_in[8];
    const void* esc     = d_in[9];

    const int HC = in_sizes[6];       // 64
    const int D  = in_sizes[4] / HC;  // 256
    const int N  = in_sizes[0] / D;   // 100000
    const int E  = in_sizes[3];       // 1600000
    const int* srce = eidx;
    const int* dste = eidx + E;

    const bool canM = (D == 256) && (HC == 64);

    char* wsb = (char*)d_ws;
    size_t o = 0;
    auto alloc = [&](size_t bytes) -> void* {
        void* p = wsb + o;
        o += (bytes + 255) & ~(size_t)255;
        return p;
    };
    __half* Pall  = (__half*)alloc((size_t)2 * N * 64 * 2);   // [Ph; Pt] hs-only, fp16
    float* as_all = (float*)alloc((size_t)2 * N * 2 * 4);
    float* ad_all = (float*)alloc((size_t)2 * N * 2 * 4);
    float* S      = (float*)alloc(2 * 4);
    unsigned int* gmax = (unsigned int*)alloc(4 * 4);
    int*   cnt    = (int*)alloc((size_t)2 * N * 4);
    int*   offp   = (int*)alloc(((size_t)2 * N + 1) * 4);
    int*   cur    = (int*)alloc((size_t)2 * N * 4);
    int*   idx    = (int*)alloc((size_t)2 * E * 4);
    int*   flag   = (int*)alloc(256);
    int*   bsum   = (int*)alloc(256 * 4);
    int*   boff   = (int*)alloc(256 * 4);
    unsigned short* Whi = (unsigned short*)alloc((size_t)8 * 8 * 64 * 8 * 2);  // 64KB
    unsigned short* Wlo = (unsigned short*)alloc((size_t)8 * 8 * 64 * 8 * 2);  // 64KB

    hipMemsetAsync(cnt, 0, (size_t)2 * N * 4, stream);
    hipMemsetAsync(cur, 0, (size_t)2 * N * 4, stream);
    hipMemsetAsync(S, 0, 2 * 4, stream);
    hipMemsetAsync(gmax, 0, 4 * 4, stream);   // encoded 0 == -inf identity

    detect_kernel<<<1, 256, 0, stream>>>((const unsigned int*)hx, 65536, flag);

    dim3 gGemm((N + 63) / 64, 2);
    if (canM) {
        wfrag_kernel<<<16, 256, 0, stream>>>(Wsrc, Wdst, flag, Whi, Wlo);
        gemm_fused_kernel<<<gGemm, 256, 0, stream>>>(hx, tx, Whi, Wlo,
                                                     att_src, att_dst, flag,
                                                     Pall, as_all, ad_all, N);
    } else {
        gemm_elu_kernel<<<gGemm, 256, 0, stream>>>(hx, tx, Wsrc, Wdst, att_src, att_dst,
                                                   flag, Pall, as_all, ad_all, N, D);
    }
    gmax_kernel<<<256, 256, 0, stream>>>(as_all, gmax, N);
    count_kernel<<<(E + 255) / 256, 256, 0, stream>>>(srce, dste, cnt, N, E);

    const int M = 2 * N;
    int chunk = (M + 255) / 256;
    chunk = (chunk + 255) & ~255;
    const int NB = (M + chunk - 1) / chunk;
    scan_bsum_kernel<<<NB, 256, 0, stream>>>(cnt, M, chunk, bsum);
    scan_boff_kernel<<<1, 256, 0, stream>>>(bsum, NB, boff);
    scan_write_kernel<<<NB, 256, 0, stream>>>(cnt, M, chunk, boff, offp);

    fill_kernel<<<(E + 255) / 256, 256, 0, stream>>>(srce, dste, offp, cur, idx, N, E);
    enrich_kernel<<<512, 256, 0, stream>>>(ew, flag, S, E);

    agg_kernel<<<(2 * N + 3) / 4, 256, 0, stream>>>(offp, idx, as_all, ad_all,
                                                    Pall, bias, S, gmax, esc, flag,
                                                    d_out, N);
}

// Round 8
// 884.021 us; speedup vs baseline: 1.2752x; 1.0860x over previous
//
#include <hip/hip_runtime.h>
#include <hip/hip_fp16.h>
#include <math.h>

typedef __attribute__((ext_vector_type(8))) short bf16x8;
typedef __attribute__((ext_vector_type(4))) float f32x4;

// ---------- bf16 helpers ----------
__device__ __forceinline__ float bf2f(unsigned short u) {
    union { unsigned int i; float f; } c;
    c.i = ((unsigned int)u) << 16;
    return c.f;
}
__device__ __forceinline__ unsigned short f2bf(float f) {
    union { float f; unsigned int i; } c;
    c.f = f;
    unsigned int b = c.i + 0x7FFFu + ((c.i >> 16) & 1u);  // round-nearest-even
    return (unsigned short)(b >> 16);
}
__device__ __forceinline__ float eluf(float v) {   // jax.nn.elu, alpha=1
    return v > 0.f ? v : (__expf(v) - 1.f);
}
__device__ __forceinline__ float lrelu(float v) {  // leaky_relu slope 0.2
    return v >= 0.f ? v : 0.2f * v;
}
// order-preserving float<->uint encoding for atomicMax
__device__ __forceinline__ unsigned int fenc(float f) {
    union { float f; unsigned int u; } c; c.f = f;
    return (c.u & 0x80000000u) ? ~c.u : (c.u | 0x80000000u);
}
__device__ __forceinline__ float fdec(unsigned int k) {
    union { float f; unsigned int u; } c;
    c.u = (k & 0x80000000u) ? (k ^ 0x80000000u) : ~k;
    return c.f;
}

// ---------- 0. input dtype detection: 1 = bf16, 0 = f32 ----------
__global__ void detect_kernel(const unsigned int* __restrict__ w, int nwords,
                              int* __restrict__ flag)
{
    __shared__ int cnt_s;
    if (threadIdx.x == 0) cnt_s = 0;
    __syncthreads();
    int sane = 0;
    for (int i = threadIdx.x; i < nwords; i += 256) {
        unsigned int lo = w[i] & 0xffffu;
        int e = (int)((lo >> 7) & 0xffu);
        if (e >= 114 && e <= 136) sane++;
    }
    atomicAdd(&cnt_s, sane);
    __syncthreads();
    if (threadIdx.x == 0) *flag = (2 * cnt_s > nwords) ? 1 : 0;
}

// ---------- 1a. W fragment pre-pack (hi/lo split for f32 inputs) ----------
__global__ __launch_bounds__(256) void wfrag_kernel(
    const void* __restrict__ Wsrc, const void* __restrict__ Wdst,
    const int* __restrict__ flag,
    unsigned short* __restrict__ Whi, unsigned short* __restrict__ Wlo)
{
    const int isbf = *flag;
    const int nch = 8 * 8 * 64;   // D=256 -> 8 K-steps
    for (int ch = blockIdx.x * 256 + threadIdx.x; ch < nch; ch += gridDim.x * 256) {
        int l  = ch & 63;
        int t  = (ch >> 6) & 7;
        int ks = ch >> 9;
        int col = t * 16 + (l & 15);
        int k0  = ks * 32 + (l >> 4) * 8;
        if (isbf) {
            const unsigned short* W = (col < 64)
                ? ((const unsigned short*)Wsrc + col)
                : ((const unsigned short*)Wdst + (col - 64));
#pragma unroll
            for (int j = 0; j < 8; ++j) {
                Whi[(size_t)ch * 8 + j] = W[(size_t)(k0 + j) * 64];
                Wlo[(size_t)ch * 8 + j] = 0;
            }
        } else {
            const float* W = (col < 64)
                ? ((const float*)Wsrc + col)
                : ((const float*)Wdst + (col - 64));
#pragma unroll
            for (int j = 0; j < 8; ++j) {
                float wv = W[(size_t)(k0 + j) * 64];
                unsigned short h = f2bf(wv);
                Whi[(size_t)ch * 8 + j] = h;
                Wlo[(size_t)ch * 8 + j] = f2bf(wv - bf2f(h));
            }
        }
    }
}

// ---------- 1. MFMA fused elu+GEMM+att-projection (both dtypes, D==256, HC==64) ----------
// av[dir][node] = float4(as0, as1, ad0, ad1).  P fp16 hs-half [N][64] per direction.
__global__ __launch_bounds__(256) void gemm_fused_kernel(
    const void* __restrict__ xh, const void* __restrict__ xt,
    const unsigned short* __restrict__ Whi, const unsigned short* __restrict__ Wlo,
    const void* __restrict__ att_src, const void* __restrict__ att_dst,
    const int* __restrict__ flag,
    __half* __restrict__ P, float4* __restrict__ av, int N)
{
    const int isbf = *flag;
    __half* Pout = P + (size_t)blockIdx.y * (size_t)N * 64u;
    float4* avO  = av + (size_t)blockIdx.y * (size_t)N;
    const int tid = threadIdx.x;
    const int w   = tid >> 6;
    const int l   = tid & 63;
    const int l15 = l & 15;
    const int lhi = l >> 4;
    const int rowA = blockIdx.x * 64 + w * 16 + l15;
    const bool rv = rowA < N;

    bf16x8 ahi[8], alo[8];
    if (isbf) {
        const unsigned short* xv = (const unsigned short*)((blockIdx.y == 0) ? xh : xt);
#pragma unroll
        for (int ks = 0; ks < 8; ++ks) {
            union { bf16x8 v; unsigned int u[4]; } o;
            if (rv) {
                uint4 raw = *(const uint4*)(xv + (size_t)rowA * 256 + ks * 32 + lhi * 8);
                unsigned int wsr[4] = {raw.x, raw.y, raw.z, raw.w};
#pragma unroll
                for (int i = 0; i < 4; ++i) {
                    float lo = eluf(bf2f((unsigned short)(wsr[i] & 0xffffu)));
                    float hi = eluf(bf2f((unsigned short)(wsr[i] >> 16)));
                    o.u[i] = (unsigned int)f2bf(lo) | ((unsigned int)f2bf(hi) << 16);
                }
            } else {
                o.u[0] = o.u[1] = o.u[2] = o.u[3] = 0u;
            }
            ahi[ks] = o.v;
            alo[ks] = o.v;   // unused on bf16 path
        }
    } else {
        const float* xv = (const float*)((blockIdx.y == 0) ? xh : xt);
#pragma unroll
        for (int ks = 0; ks < 8; ++ks) {
            union { bf16x8 v; unsigned int u[4]; } oh, ol;
            if (rv) {
                const float4* px = (const float4*)(xv + (size_t)rowA * 256 + ks * 32 + lhi * 8);
                float4 f0 = px[0], f1 = px[1];
                float v[8] = {f0.x, f0.y, f0.z, f0.w, f1.x, f1.y, f1.z, f1.w};
#pragma unroll
                for (int i = 0; i < 8; ++i) v[i] = eluf(v[i]);
#pragma unroll
                for (int i = 0; i < 4; ++i) {
                    unsigned short h0 = f2bf(v[2 * i]);
                    unsigned short h1 = f2bf(v[2 * i + 1]);
                    unsigned short l0 = f2bf(v[2 * i]     - bf2f(h0));
                    unsigned short l1 = f2bf(v[2 * i + 1] - bf2f(h1));
                    oh.u[i] = (unsigned int)h0 | ((unsigned int)h1 << 16);
                    ol.u[i] = (unsigned int)l0 | ((unsigned int)l1 << 16);
                }
            } else {
                oh.u[0] = oh.u[1] = oh.u[2] = oh.u[3] = 0u;
                ol.u[0] = ol.u[1] = ol.u[2] = ol.u[3] = 0u;
            }
            ahi[ks] = oh.v;
            alo[ks] = ol.v;
        }
    }

    f32x4 acc[8];
#pragma unroll
    for (int t = 0; t < 8; ++t) acc[t] = (f32x4){0.f, 0.f, 0.f, 0.f};

    const bf16x8* wfh = (const bf16x8*)Whi;
    const bf16x8* wfl = (const bf16x8*)Wlo;
    if (isbf) {
#pragma unroll
        for (int ks = 0; ks < 8; ++ks) {
#pragma unroll
            for (int t = 0; t < 8; ++t) {
                bf16x8 b = wfh[(ks * 8 + t) * 64 + l];
                acc[t] = __builtin_amdgcn_mfma_f32_16x16x32_bf16(ahi[ks], b, acc[t], 0, 0, 0);
            }
        }
    } else {
#pragma unroll
        for (int ks = 0; ks < 8; ++ks) {
#pragma unroll
            for (int t = 0; t < 8; ++t) {
                bf16x8 bh = wfh[(ks * 8 + t) * 64 + l];
                bf16x8 bl = wfl[(ks * 8 + t) * 64 + l];
                acc[t] = __builtin_amdgcn_mfma_f32_16x16x32_bf16(ahi[ks], bh, acc[t], 0, 0, 0);
                acc[t] = __builtin_amdgcn_mfma_f32_16x16x32_bf16(alo[ks], bh, acc[t], 0, 0, 0);
                acc[t] = __builtin_amdgcn_mfma_f32_16x16x32_bf16(ahi[ks], bl, acc[t], 0, 0, 0);
            }
        }
    }

    // epilogue: store hs half of P (fp16) + packed att projections (one float4/node)
    float asv[4], adv[4];
#pragma unroll
    for (int t = 0; t < 4; ++t) {
        if (isbf) {
            asv[t] = bf2f(((const unsigned short*)att_src)[t * 16 + l15]);
            adv[t] = bf2f(((const unsigned short*)att_dst)[t * 16 + l15]);
        } else {
            asv[t] = ((const float*)att_src)[t * 16 + l15];
            adv[t] = ((const float*)att_dst)[t * 16 + l15];
        }
    }
    const int rbase = blockIdx.x * 64 + w * 16 + lhi * 4;
#pragma unroll
    for (int reg = 0; reg < 4; ++reg) {
        int row = rbase + reg;
        bool ok = row < N;
        if (ok) {
            __half* p = Pout + (size_t)row * 64 + l15;
#pragma unroll
            for (int t = 0; t < 4; ++t) p[t * 16] = __float2half(acc[t][reg]);
        }
        float s0 = acc[0][reg] * asv[0] + acc[1][reg] * asv[1];
        float s1 = acc[2][reg] * asv[2] + acc[3][reg] * asv[3];
        float d0 = acc[4][reg] * adv[0] + acc[5][reg] * adv[1];
        float d1 = acc[6][reg] * adv[2] + acc[7][reg] * adv[3];
#pragma unroll
        for (int o2 = 8; o2 >= 1; o2 >>= 1) {
            s0 += __shfl_xor(s0, o2, 64);
            s1 += __shfl_xor(s1, o2, 64);
            d0 += __shfl_xor(d0, o2, 64);
            d1 += __shfl_xor(d1, o2, 64);
        }
        if (ok && l15 == 0) avO[row] = make_float4(s0, s1, d0, d1);
    }
}

// ---------- 1c. generic fallback (any D mult of 32), both dtypes ----------
__global__ __launch_bounds__(256) void gemm_elu_kernel(
    const void* __restrict__ xh, const void* __restrict__ xt,
    const void* __restrict__ Wsrc, const void* __restrict__ Wdst,
    const void* __restrict__ att_src, const void* __restrict__ att_dst,
    const int* __restrict__ flag,
    __half* __restrict__ P, float4* __restrict__ av, int N, int D)
{
    const int isbf = *flag;
    __shared__ float xs[64][33];
    __shared__ float wt[32][128];
    const void* xv = (blockIdx.y == 0) ? xh : xt;
    __half* Pout = P + (size_t)blockIdx.y * (size_t)N * 64u;
    float4* avO  = av + (size_t)blockIdx.y * (size_t)N;
    const int rowBase = blockIdx.x * 64;
    const int tid = threadIdx.x;
    const int tcx = tid & 15;
    const int tcy = tid >> 4;

    float acc[4][8];
#pragma unroll
    for (int r = 0; r < 4; ++r)
#pragma unroll
        for (int c = 0; c < 8; ++c) acc[r][c] = 0.f;

    for (int kc = 0; kc < D; kc += 32) {
        {
            int row = tid >> 2;
            int kq  = (tid & 3) * 8;
            int r = rowBase + row;
            float v[8];
            if (r < N) {
                if (isbf) {
                    const unsigned short* xb = (const unsigned short*)xv;
                    uint4 raw = *(const uint4*)(xb + (size_t)r * D + kc + kq);
                    unsigned int ws[4] = {raw.x, raw.y, raw.z, raw.w};
#pragma unroll
                    for (int i = 0; i < 4; ++i) {
                        v[2 * i]     = bf2f((unsigned short)(ws[i] & 0xffffu));
                        v[2 * i + 1] = bf2f((unsigned short)(ws[i] >> 16));
                    }
                } else {
                    const float* xf = (const float*)xv;
                    const float4* p4 = (const float4*)(xf + (size_t)r * D + kc + kq);
                    float4 f0 = p4[0], f1 = p4[1];
                    v[0] = f0.x; v[1] = f0.y; v[2] = f0.z; v[3] = f0.w;
                    v[4] = f1.x; v[5] = f1.y; v[6] = f1.z; v[7] = f1.w;
                }
#pragma unroll
                for (int i = 0; i < 8; ++i) v[i] = eluf(v[i]);
            } else {
#pragma unroll
                for (int i = 0; i < 8; ++i) v[i] = 0.f;
            }
#pragma unroll
            for (int i = 0; i < 8; ++i) xs[row][kq + i] = v[i];
        }
#pragma unroll
        for (int i = 0; i < 2; ++i) {
            int f = (tid + i * 256) * 8;
            int k = f >> 7;
            int c = f & 127;
            float v[8];
            if (isbf) {
                const unsigned short* Wp = (c < 64)
                    ? ((const unsigned short*)Wsrc + (size_t)(kc + k) * 64 + c)
                    : ((const unsigned short*)Wdst + (size_t)(kc + k) * 64 + (c - 64));
                uint4 raw = *(const uint4*)Wp;
                unsigned int ws[4] = {raw.x, raw.y, raw.z, raw.w};
#pragma unroll
                for (int q = 0; q < 4; ++q) {
                    v[2 * q]     = bf2f((unsigned short)(ws[q] & 0xffffu));
                    v[2 * q + 1] = bf2f((unsigned short)(ws[q] >> 16));
                }
            } else {
                const float* Wp = (c < 64)
                    ? ((const float*)Wsrc + (size_t)(kc + k) * 64 + c)
                    : ((const float*)Wdst + (size_t)(kc + k) * 64 + (c - 64));
                const float4* p4 = (const float4*)Wp;
                float4 f0 = p4[0], f1 = p4[1];
                v[0] = f0.x; v[1] = f0.y; v[2] = f0.z; v[3] = f0.w;
                v[4] = f1.x; v[5] = f1.y; v[6] = f1.z; v[7] = f1.w;
            }
#pragma unroll
            for (int q = 0; q < 8; ++q) wt[k][c + q] = v[q];
        }
        __syncthreads();
#pragma unroll 8
        for (int k = 0; k < 32; ++k) {
            float xr[4];
#pragma unroll
            for (int r = 0; r < 4; ++r) xr[r] = xs[tcy * 4 + r][k];
            float4 w0 = *(const float4*)&wt[k][tcx * 8];
            float4 w1 = *(const float4*)&wt[k][tcx * 8 + 4];
#pragma unroll
            for (int r = 0; r < 4; ++r) {
                acc[r][0] += xr[r] * w0.x; acc[r][1] += xr[r] * w0.y;
                acc[r][2] += xr[r] * w0.z; acc[r][3] += xr[r] * w0.w;
                acc[r][4] += xr[r] * w1.x; acc[r][5] += xr[r] * w1.y;
                acc[r][6] += xr[r] * w1.z; acc[r][7] += xr[r] * w1.w;
            }
        }
        __syncthreads();
    }

    float attv[8];
#pragma unroll
    for (int q = 0; q < 8; ++q) {
        int c = tcx * 8 + q;
        if (isbf) attv[q] = (c < 64) ? bf2f(((const unsigned short*)att_src)[c])
                                     : bf2f(((const unsigned short*)att_dst)[c - 64]);
        else      attv[q] = (c < 64) ? ((const float*)att_src)[c]
                                     : ((const float*)att_dst)[c - 64];
    }

#pragma unroll
    for (int r = 0; r < 4; ++r) {
        int row = rowBase + tcy * 4 + r;
        bool ok = row < N;
        if (ok && tcx < 8) {
            __half* p = Pout + (size_t)row * 64 + tcx * 8;
#pragma unroll
            for (int q = 0; q < 8; ++q) p[q] = __float2half(acc[r][q]);
        }
        float part = 0.f;
#pragma unroll
        for (int q = 0; q < 8; ++q) part += acc[r][q] * attv[q];
        part += __shfl_xor(part, 1, 64);
        part += __shfl_xor(part, 2, 64);
        if (ok && (tcx & 3) == 0)
            ((float*)&avO[row])[tcx >> 2] = part;   // comp 0..3 = as0,as1,ad0,ad1
    }
}

// ---------- 2. global per-(dir,head) max of as (av .x/.y) ----------
__global__ __launch_bounds__(256) void gmax_kernel(
    const float4* __restrict__ av, unsigned int* __restrict__ gmax, int N)
{
    unsigned int k0 = 0, k1 = 0, k2 = 0, k3 = 0;
    const int total = 2 * N;
    for (int i = blockIdx.x * 256 + threadIdx.x; i < total; i += gridDim.x * 256) {
        float4 v = av[i];
        unsigned int ex = fenc(v.x), ey = fenc(v.y);
        if (i < N) { k0 = max(k0, ex); k1 = max(k1, ey); }
        else       { k2 = max(k2, ex); k3 = max(k3, ey); }
    }
#pragma unroll
    for (int o = 32; o >= 1; o >>= 1) {
        k0 = max(k0, (unsigned int)__shfl_xor((int)k0, o, 64));
        k1 = max(k1, (unsigned int)__shfl_xor((int)k1, o, 64));
        k2 = max(k2, (unsigned int)__shfl_xor((int)k2, o, 64));
        k3 = max(k3, (unsigned int)__shfl_xor((int)k3, o, 64));
    }
    if ((threadIdx.x & 63) == 0) {
        atomicMax(&gmax[0], k0);
        atomicMax(&gmax[1], k1);
        atomicMax(&gmax[2], k2);
        atomicMax(&gmax[3], k3);
    }
}

// ---------- 3a. degree histogram (dir1 by dst, dir2 by src) ----------
__global__ void count_kernel(const int* __restrict__ srce, const int* __restrict__ dste,
                             int* __restrict__ cnt, int N, int E)
{
    int e = blockIdx.x * blockDim.x + threadIdx.x;
    if (e >= E) return;
    atomicAdd(&cnt[dste[e]], 1);
    atomicAdd(&cnt[N + srce[e]], 1);
}

// ---------- 3b. multi-block scan: stage 1 ----------
__global__ __launch_bounds__(256) void scan_bsum_kernel(
    const int* __restrict__ cnt, int M, int chunk, int* __restrict__ bsum)
{
    __shared__ int r[4];
    int beg = blockIdx.x * chunk;
    int end = beg + chunk; if (end > M) end = M;
    int s = 0;
    for (int i = beg + threadIdx.x; i < end; i += 256) s += cnt[i];
#pragma unroll
    for (int o = 32; o >= 1; o >>= 1) s += __shfl_down(s, o, 64);
    int lane = threadIdx.x & 63, wv = threadIdx.x >> 6;
    if (lane == 0) r[wv] = s;
    __syncthreads();
    if (threadIdx.x == 0) bsum[blockIdx.x] = r[0] + r[1] + r[2] + r[3];
}

// ---------- stage 2 ----------
__global__ __launch_bounds__(256) void scan_boff_kernel(
    const int* __restrict__ bsum, int NB, int* __restrict__ boff)
{
    __shared__ int s[256];
    int t = threadIdx.x;
    int v = (t < NB) ? bsum[t] : 0;
    s[t] = v;
    __syncthreads();
    for (int o = 1; o < 256; o <<= 1) {
        int x = (t >= o) ? s[t - o] : 0;
        __syncthreads();
        s[t] += x;
        __syncthreads();
    }
    if (t < NB) boff[t] = s[t] - v;
}

// ---------- stage 3 ----------
__global__ __launch_bounds__(256) void scan_write_kernel(
    const int* __restrict__ cnt, int M, int chunk,
    const int* __restrict__ boff, int* __restrict__ off)
{
    __shared__ int s[256];
    int t = threadIdx.x;
    int beg = blockIdx.x * chunk;
    int end = beg + chunk; if (end > M) end = M;
    if (beg >= M) return;
    int running = boff[blockIdx.x];
    for (int base = beg; base < end; base += 256) {
        int i = base + t;
        int v = (i < end) ? cnt[i] : 0;
        s[t] = v;
        __syncthreads();
        for (int o = 1; o < 256; o <<= 1) {
            int x = (t >= o) ? s[t - o] : 0;
            __syncthreads();
            s[t] += x;
            __syncthreads();
        }
        if (i < end) off[i] = running + s[t] - v;
        int total = s[255];
        __syncthreads();
        running += total;
    }
    if (end == M && t == 0) off[M] = running;
}

// ---------- 3c. CSR fill + per-edge softmax weights (both dirs, both heads) ----------
// epack[slot] = {src, bits(p_h0), bits(p_h1), 0}
__global__ void fill_kernel(const int* __restrict__ srce, const int* __restrict__ dste,
                            const int* __restrict__ off, int* __restrict__ cur,
                            const float4* __restrict__ av,
                            const unsigned int* __restrict__ gmax,
                            int4* __restrict__ epack, int N, int E)
{
    int e = blockIdx.x * blockDim.x + threadIdx.x;
    if (e >= E) return;
    int s = srce[e], d = dste[e];
    float4 ah = av[s];          // h-side of s: as0,as1,ad0,ad1
    float4 at = av[N + d];      // t-side of d
    float gm00 = fdec(gmax[0]), gm01 = fdec(gmax[1]);
    float gm10 = fdec(gmax[2]), gm11 = fdec(gmax[3]);
    // dir0 (h->t): src as_h[s], dst ad_t[d]; m = lrelu(gm0 + adv)
    float p00 = __expf(lrelu(ah.x + at.z) - lrelu(gm00 + at.z));
    float p01 = __expf(lrelu(ah.y + at.w) - lrelu(gm01 + at.w));
    // dir1 (t->h): src as_t[d], dst ad_h[s]; m = lrelu(gm1 + adv)
    float p10 = __expf(lrelu(at.x + ah.z) - lrelu(gm10 + ah.z));
    float p11 = __expf(lrelu(at.y + ah.w) - lrelu(gm11 + ah.w));
    int p  = atomicAdd(&cur[d], 1);
    epack[off[d] + p] = make_int4(s, __float_as_int(p00), __float_as_int(p01), 0);
    int p2 = atomicAdd(&cur[N + s], 1);
    epack[off[N + s] + p2] = make_int4(d, __float_as_int(p10), __float_as_int(p11), 0);
}

// ---------- 4. enrichment softmax sums ----------
__global__ __launch_bounds__(256) void enrich_kernel(
    const void* __restrict__ ew, const int* __restrict__ flag,
    float* __restrict__ S, int E)
{
    __shared__ float r1[4], r2[4];
    const int isbf = *flag;
    float e1 = 0.f, e2 = 0.f;
    for (int i = blockIdx.x * 256 + threadIdx.x; i < E; i += gridDim.x * 256) {
        float c = isbf ? bf2f(((const unsigned short*)ew)[i]) : ((const float*)ew)[i];
        c = fminf(fmaxf(c, 0.3f), 3.0f);
        float ex = __expf(c);
        e1 += ex;
        e2 += c * ex;
    }
#pragma unroll
    for (int o = 32; o >= 1; o >>= 1) {
        e1 += __shfl_down(e1, o, 64);
        e2 += __shfl_down(e2, o, 64);
    }
    int lane = threadIdx.x & 63;
    int wv = threadIdx.x >> 6;
    if (lane == 0) { r1[wv] = e1; r2[wv] = e2; }
    __syncthreads();
    if (threadIdx.x == 0) {
        atomicAdd(&S[0], r1[0] + r1[1] + r1[2] + r1[3]);
        atomicAdd(&S[1], r2[0] + r2[1] + r2[2] + r2[3]);
    }
}

// ---------- 5. aggregation with precomputed weights, both dirs ----------
__global__ __launch_bounds__(256) void agg_kernel(
    const int* __restrict__ off, const int4* __restrict__ epack,
    const float4* __restrict__ av, const __half* __restrict__ Pall,
    const void* __restrict__ bias,
    const float* __restrict__ S,
    const unsigned int* __restrict__ gmax,
    const void* __restrict__ esc,
    const int* __restrict__ flag,
    void* __restrict__ out, int N)
{
    const int isbf = *flag;
    int q = (blockIdx.x * 256 + threadIdx.x) >> 6;
    int lane = threadIdx.x & 63;     // lane = h*32 + c
    if (q >= 2 * N) return;
    int dir = (q >= N) ? 1 : 0;
    int n = q - dir * N;
    const __half* Psrc = Pall + (size_t)dir * (size_t)N * 64u;
    size_t outOff = dir ? 0u : (size_t)N * 64u;
    const int hi = lane >> 5;
    const int jb = off[q], je = off[q + 1];

    // self-loop
    float4 asrc = av[(size_t)dir * N + n];        // src-side row of n
    float4 adst = av[(size_t)(1 - dir) * N + n];  // dst-side row of n
    const float adv = hi ? adst.w : adst.z;
    const float m   = lrelu(fdec(gmax[dir * 2 + hi]) + adv);
    const float pSelf = __expf(lrelu((hi ? asrc.y : asrc.x) + adv) - m);

    float z0 = pSelf, z1 = 0.f, z2 = 0.f, z3 = 0.f;
    float a0 = pSelf * __half2float(Psrc[(size_t)n * 64 + lane]);
    float a1 = 0.f, a2 = 0.f, a3 = 0.f;

    int j = jb;
    for (; j + 3 < je; j += 4) {
        int4 e0 = epack[j], e1 = epack[j + 1], e2 = epack[j + 2], e3 = epack[j + 3];
        float h0 = __half2float(Psrc[(size_t)e0.x * 64 + lane]);
        float h1 = __half2float(Psrc[(size_t)e1.x * 64 + lane]);
        float h2 = __half2float(Psrc[(size_t)e2.x * 64 + lane]);
        float h3 = __half2float(Psrc[(size_t)e3.x * 64 + lane]);
        float p0 = __int_as_float(hi ? e0.z : e0.y);
        float p1 = __int_as_float(hi ? e1.z : e1.y);
        float p2 = __int_as_float(hi ? e2.z : e2.y);
        float p3 = __int_as_float(hi ? e3.z : e3.y);
        z0 += p0; a0 = fmaf(p0, h0, a0);
        z1 += p1; a1 = fmaf(p1, h1, a1);
        z2 += p2; a2 = fmaf(p2, h2, a2);
        z3 += p3; a3 = fmaf(p3, h3, a3);
    }
    for (; j < je; ++j) {
        int4 e0 = epack[j];
        float h0 = __half2float(Psrc[(size_t)e0.x * 64 + lane]);
        float p0 = __int_as_float(hi ? e0.z : e0.y);
        z0 += p0; a0 = fmaf(p0, h0, a0);
    }
    float z   = (z0 + z1) + (z2 + z3);
    float acc = (a0 + a1) + (a2 + a3);

    float escv = isbf ? bf2f(((const unsigned short*)esc)[0]) : ((const float*)esc)[0];
    float bv   = isbf ? bf2f(((const unsigned short*)bias)[lane]) : ((const float*)bias)[lane];
    float weighted = S[1] / S[0];
    float factor = 1.f + 0.5f * tanhf(escv) * (weighted - 1.f);
    float o = (acc / (z + 1e-16f) + bv) * factor;
    size_t oi = outOff + (size_t)n * 64 + lane;
    if (isbf) ((unsigned short*)out)[oi] = f2bf(o);
    else      ((float*)out)[oi] = o;
}

extern "C" void kernel_launch(void* const* d_in, const int* in_sizes, int n_in,
                              void* d_out, int out_size, void* d_ws, size_t ws_size,
                              hipStream_t stream)
{
    const void* hx      = d_in[0];
    const void* tx      = d_in[1];
    const int*  eidx    = (const int*)d_in[2];
    const void* ew      = d_in[3];
    const void* Wsrc    = d_in[4];
    const void* Wdst    = d_in[5];
    const void* att_src = d_in[6];
    const void* att_dst = d_in[7];
    const void* bias    = d_in[8];
    const void* esc     = d_in[9];

    const int HC = in_sizes[6];       // 64
    const int D  = in_sizes[4] / HC;  // 256
    const int N  = in_sizes[0] / D;   // 100000
    const int E  = in_sizes[3];       // 1600000
    const int* srce = eidx;
    const int* dste = eidx + E;

    const bool canM = (D == 256) && (HC == 64);

    char* wsb = (char*)d_ws;
    size_t o = 0;
    auto alloc = [&](size_t bytes) -> void* {
        void* p = wsb + o;
        o += (bytes + 255) & ~(size_t)255;
        return p;
    };
    __half* Pall  = (__half*)alloc((size_t)2 * N * 64 * 2);   // [Ph; Pt] hs-only, fp16
    float4* av    = (float4*)alloc((size_t)2 * N * 16);       // packed as/ad per node
    float* S      = (float*)alloc(2 * 4);
    unsigned int* gmax = (unsigned int*)alloc(4 * 4);
    int*   cnt    = (int*)alloc((size_t)2 * N * 4);
    int*   offp   = (int*)alloc(((size_t)2 * N + 1) * 4);
    int*   cur    = (int*)alloc((size_t)2 * N * 4);
    int4*  epack  = (int4*)alloc((size_t)2 * E * 16);
    int*   flag   = (int*)alloc(256);
    int*   bsum   = (int*)alloc(256 * 4);
    int*   boff   = (int*)alloc(256 * 4);
    unsigned short* Whi = (unsigned short*)alloc((size_t)8 * 8 * 64 * 8 * 2);  // 64KB
    unsigned short* Wlo = (unsigned short*)alloc((size_t)8 * 8 * 64 * 8 * 2);  // 64KB

    hipMemsetAsync(cnt, 0, (size_t)2 * N * 4, stream);
    hipMemsetAsync(cur, 0, (size_t)2 * N * 4, stream);
    hipMemsetAsync(S, 0, 2 * 4, stream);
    hipMemsetAsync(gmax, 0, 4 * 4, stream);

    detect_kernel<<<1, 256, 0, stream>>>((const unsigned int*)hx, 65536, flag);

    dim3 gGemm((N + 63) / 64, 2);
    if (canM) {
        wfrag_kernel<<<16, 256, 0, stream>>>(Wsrc, Wdst, flag, Whi, Wlo);
        gemm_fused_kernel<<<gGemm, 256, 0, stream>>>(hx, tx, Whi, Wlo,
                                                     att_src, att_dst, flag,
                                                     Pall, av, N);
    } else {
        gemm_elu_kernel<<<gGemm, 256, 0, stream>>>(hx, tx, Wsrc, Wdst, att_src, att_dst,
                                                   flag, Pall, av, N, D);
    }
    gmax_kernel<<<256, 256, 0, stream>>>(av, gmax, N);
    count_kernel<<<(E + 255) / 256, 256, 0, stream>>>(srce, dste, cnt, N, E);

    const int M = 2 * N;
    int chunk = (M + 255) / 256;
    chunk = (chunk + 255) & ~255;
    const int NB = (M + chunk - 1) / chunk;
    scan_bsum_kernel<<<NB, 256, 0, stream>>>(cnt, M, chunk, bsum);
    scan_boff_kernel<<<1, 256, 0, stream>>>(bsum, NB, boff);
    scan_write_kernel<<<NB, 256, 0, stream>>>(cnt, M, chunk, boff, offp);

    fill_kernel<<<(E + 255) / 256, 256, 0, stream>>>(srce, dste, offp, cur,
                                                     av, gmax, epack, N, E);
    enrich_kernel<<<512, 256, 0, stream>>>(ew, flag, S, E);

    agg_kernel<<<(2 * N + 3) / 4, 256, 0, stream>>>(offp, epack, av,
                                                    Pall, bias, S, gmax, esc, flag,
                                                    d_out, N);
}

// Round 9
// 874.383 us; speedup vs baseline: 1.2892x; 1.0110x over previous
//
#include <hip/hip_runtime.h>
#include <hip/hip_fp16.h>
#include <math.h>

typedef __attribute__((ext_vector_type(8))) short bf16x8;
typedef __attribute__((ext_vector_type(4))) float f32x4;

// ---------- bf16 helpers ----------
__device__ __forceinline__ float bf2f(unsigned short u) {
    union { unsigned int i; float f; } c;
    c.i = ((unsigned int)u) << 16;
    return c.f;
}
__device__ __forceinline__ unsigned short f2bf(float f) {
    union { float f; unsigned int i; } c;
    c.f = f;
    unsigned int b = c.i + 0x7FFFu + ((c.i >> 16) & 1u);  // round-nearest-even
    return (unsigned short)(b >> 16);
}
__device__ __forceinline__ float eluf(float v) {   // jax.nn.elu, alpha=1
    return v > 0.f ? v : (__expf(v) - 1.f);
}
__device__ __forceinline__ float lrelu(float v) {  // leaky_relu slope 0.2
    return v >= 0.f ? v : 0.2f * v;
}
// order-preserving float<->uint encoding for atomicMax
__device__ __forceinline__ unsigned int fenc(float f) {
    union { float f; unsigned int u; } c; c.f = f;
    return (c.u & 0x80000000u) ? ~c.u : (c.u | 0x80000000u);
}
__device__ __forceinline__ float fdec(unsigned int k) {
    union { float f; unsigned int u; } c;
    c.u = (k & 0x80000000u) ? (k ^ 0x80000000u) : ~k;
    return c.f;
}
__device__ __forceinline__ unsigned int packh2(float a, float b) {
    __half2 h = __floats2half2_rn(a, b);   // low = a, high = b
    union { __half2 h; unsigned int u; } c; c.h = h;
    return c.u;
}

// ---------- 0. input dtype detection: 1 = bf16, 0 = f32 ----------
__global__ void detect_kernel(const unsigned int* __restrict__ w, int nwords,
                              int* __restrict__ flag)
{
    __shared__ int cnt_s;
    if (threadIdx.x == 0) cnt_s = 0;
    __syncthreads();
    int sane = 0;
    for (int i = threadIdx.x; i < nwords; i += 256) {
        unsigned int lo = w[i] & 0xffffu;
        int e = (int)((lo >> 7) & 0xffu);
        if (e >= 114 && e <= 136) sane++;
    }
    atomicAdd(&cnt_s, sane);
    __syncthreads();
    if (threadIdx.x == 0) *flag = (2 * cnt_s > nwords) ? 1 : 0;
}

// ---------- 1a. W fragment pre-pack (hi/lo split for f32 inputs) ----------
__global__ __launch_bounds__(256) void wfrag_kernel(
    const void* __restrict__ Wsrc, const void* __restrict__ Wdst,
    const int* __restrict__ flag,
    unsigned short* __restrict__ Whi, unsigned short* __restrict__ Wlo)
{
    const int isbf = *flag;
    const int nch = 8 * 8 * 64;   // D=256 -> 8 K-steps
    for (int ch = blockIdx.x * 256 + threadIdx.x; ch < nch; ch += gridDim.x * 256) {
        int l  = ch & 63;
        int t  = (ch >> 6) & 7;
        int ks = ch >> 9;
        int col = t * 16 + (l & 15);
        int k0  = ks * 32 + (l >> 4) * 8;
        if (isbf) {
            const unsigned short* W = (col < 64)
                ? ((const unsigned short*)Wsrc + col)
                : ((const unsigned short*)Wdst + (col - 64));
#pragma unroll
            for (int j = 0; j < 8; ++j) {
                Whi[(size_t)ch * 8 + j] = W[(size_t)(k0 + j) * 64];
                Wlo[(size_t)ch * 8 + j] = 0;
            }
        } else {
            const float* W = (col < 64)
                ? ((const float*)Wsrc + col)
                : ((const float*)Wdst + (col - 64));
#pragma unroll
            for (int j = 0; j < 8; ++j) {
                float wv = W[(size_t)(k0 + j) * 64];
                unsigned short h = f2bf(wv);
                Whi[(size_t)ch * 8 + j] = h;
                Wlo[(size_t)ch * 8 + j] = f2bf(wv - bf2f(h));
            }
        }
    }
}

// ---------- 1. MFMA fused elu+GEMM+att-projection (both dtypes, D==256, HC==64) ----------
// av[dir][node] = float4(as0, as1, ad0, ad1).  P fp16 hs-half [N][64] per direction.
__global__ __launch_bounds__(256) void gemm_fused_kernel(
    const void* __restrict__ xh, const void* __restrict__ xt,
    const unsigned short* __restrict__ Whi, const unsigned short* __restrict__ Wlo,
    const void* __restrict__ att_src, const void* __restrict__ att_dst,
    const int* __restrict__ flag,
    __half* __restrict__ P, float4* __restrict__ av, int N)
{
    const int isbf = *flag;
    __half* Pout = P + (size_t)blockIdx.y * (size_t)N * 64u;
    float4* avO  = av + (size_t)blockIdx.y * (size_t)N;
    const int tid = threadIdx.x;
    const int w   = tid >> 6;
    const int l   = tid & 63;
    const int l15 = l & 15;
    const int lhi = l >> 4;
    const int rowA = blockIdx.x * 64 + w * 16 + l15;
    const bool rv = rowA < N;

    bf16x8 ahi[8], alo[8];
    if (isbf) {
        const unsigned short* xv = (const unsigned short*)((blockIdx.y == 0) ? xh : xt);
#pragma unroll
        for (int ks = 0; ks < 8; ++ks) {
            union { bf16x8 v; unsigned int u[4]; } o;
            if (rv) {
                uint4 raw = *(const uint4*)(xv + (size_t)rowA * 256 + ks * 32 + lhi * 8);
                unsigned int wsr[4] = {raw.x, raw.y, raw.z, raw.w};
#pragma unroll
                for (int i = 0; i < 4; ++i) {
                    float lo = eluf(bf2f((unsigned short)(wsr[i] & 0xffffu)));
                    float hi = eluf(bf2f((unsigned short)(wsr[i] >> 16)));
                    o.u[i] = (unsigned int)f2bf(lo) | ((unsigned int)f2bf(hi) << 16);
                }
            } else {
                o.u[0] = o.u[1] = o.u[2] = o.u[3] = 0u;
            }
            ahi[ks] = o.v;
            alo[ks] = o.v;   // unused on bf16 path
        }
    } else {
        const float* xv = (const float*)((blockIdx.y == 0) ? xh : xt);
#pragma unroll
        for (int ks = 0; ks < 8; ++ks) {
            union { bf16x8 v; unsigned int u[4]; } oh, ol;
            if (rv) {
                const float4* px = (const float4*)(xv + (size_t)rowA * 256 + ks * 32 + lhi * 8);
                float4 f0 = px[0], f1 = px[1];
                float v[8] = {f0.x, f0.y, f0.z, f0.w, f1.x, f1.y, f1.z, f1.w};
#pragma unroll
                for (int i = 0; i < 8; ++i) v[i] = eluf(v[i]);
#pragma unroll
                for (int i = 0; i < 4; ++i) {
                    unsigned short h0 = f2bf(v[2 * i]);
                    unsigned short h1 = f2bf(v[2 * i + 1]);
                    unsigned short l0 = f2bf(v[2 * i]     - bf2f(h0));
                    unsigned short l1 = f2bf(v[2 * i + 1] - bf2f(h1));
                    oh.u[i] = (unsigned int)h0 | ((unsigned int)h1 << 16);
                    ol.u[i] = (unsigned int)l0 | ((unsigned int)l1 << 16);
                }
            } else {
                oh.u[0] = oh.u[1] = oh.u[2] = oh.u[3] = 0u;
                ol.u[0] = ol.u[1] = ol.u[2] = ol.u[3] = 0u;
            }
            ahi[ks] = oh.v;
            alo[ks] = ol.v;
        }
    }

    f32x4 acc[8];
#pragma unroll
    for (int t = 0; t < 8; ++t) acc[t] = (f32x4){0.f, 0.f, 0.f, 0.f};

    const bf16x8* wfh = (const bf16x8*)Whi;
    const bf16x8* wfl = (const bf16x8*)Wlo;
    if (isbf) {
#pragma unroll
        for (int ks = 0; ks < 8; ++ks) {
#pragma unroll
            for (int t = 0; t < 8; ++t) {
                bf16x8 b = wfh[(ks * 8 + t) * 64 + l];
                acc[t] = __builtin_amdgcn_mfma_f32_16x16x32_bf16(ahi[ks], b, acc[t], 0, 0, 0);
            }
        }
    } else {
#pragma unroll
        for (int ks = 0; ks < 8; ++ks) {
#pragma unroll
            for (int t = 0; t < 8; ++t) {
                bf16x8 bh = wfh[(ks * 8 + t) * 64 + l];
                bf16x8 bl = wfl[(ks * 8 + t) * 64 + l];
                acc[t] = __builtin_amdgcn_mfma_f32_16x16x32_bf16(ahi[ks], bh, acc[t], 0, 0, 0);
                acc[t] = __builtin_amdgcn_mfma_f32_16x16x32_bf16(alo[ks], bh, acc[t], 0, 0, 0);
                acc[t] = __builtin_amdgcn_mfma_f32_16x16x32_bf16(ahi[ks], bl, acc[t], 0, 0, 0);
            }
        }
    }

    // epilogue: store hs half of P (fp16) + packed att projections (one float4/node)
    float asv[4], adv[4];
#pragma unroll
    for (int t = 0; t < 4; ++t) {
        if (isbf) {
            asv[t] = bf2f(((const unsigned short*)att_src)[t * 16 + l15]);
            adv[t] = bf2f(((const unsigned short*)att_dst)[t * 16 + l15]);
        } else {
            asv[t] = ((const float*)att_src)[t * 16 + l15];
            adv[t] = ((const float*)att_dst)[t * 16 + l15];
        }
    }
    const int rbase = blockIdx.x * 64 + w * 16 + lhi * 4;
#pragma unroll
    for (int reg = 0; reg < 4; ++reg) {
        int row = rbase + reg;
        bool ok = row < N;
        if (ok) {
            __half* p = Pout + (size_t)row * 64 + l15;
#pragma unroll
            for (int t = 0; t < 4; ++t) p[t * 16] = __float2half(acc[t][reg]);
        }
        float s0 = acc[0][reg] * asv[0] + acc[1][reg] * asv[1];
        float s1 = acc[2][reg] * asv[2] + acc[3][reg] * asv[3];
        float d0 = acc[4][reg] * adv[0] + acc[5][reg] * adv[1];
        float d1 = acc[6][reg] * adv[2] + acc[7][reg] * adv[3];
#pragma unroll
        for (int o2 = 8; o2 >= 1; o2 >>= 1) {
            s0 += __shfl_xor(s0, o2, 64);
            s1 += __shfl_xor(s1, o2, 64);
            d0 += __shfl_xor(d0, o2, 64);
            d1 += __shfl_xor(d1, o2, 64);
        }
        if (ok && l15 == 0) avO[row] = make_float4(s0, s1, d0, d1);
    }
}

// ---------- 1c. generic fallback (any D mult of 32), both dtypes ----------
__global__ __launch_bounds__(256) void gemm_elu_kernel(
    const void* __restrict__ xh, const void* __restrict__ xt,
    const void* __restrict__ Wsrc, const void* __restrict__ Wdst,
    const void* __restrict__ att_src, const void* __restrict__ att_dst,
    const int* __restrict__ flag,
    __half* __restrict__ P, float4* __restrict__ av, int N, int D)
{
    const int isbf = *flag;
    __shared__ float xs[64][33];
    __shared__ float wt[32][128];
    const void* xv = (blockIdx.y == 0) ? xh : xt;
    __half* Pout = P + (size_t)blockIdx.y * (size_t)N * 64u;
    float4* avO  = av + (size_t)blockIdx.y * (size_t)N;
    const int rowBase = blockIdx.x * 64;
    const int tid = threadIdx.x;
    const int tcx = tid & 15;
    const int tcy = tid >> 4;

    float acc[4][8];
#pragma unroll
    for (int r = 0; r < 4; ++r)
#pragma unroll
        for (int c = 0; c < 8; ++c) acc[r][c] = 0.f;

    for (int kc = 0; kc < D; kc += 32) {
        {
            int row = tid >> 2;
            int kq  = (tid & 3) * 8;
            int r = rowBase + row;
            float v[8];
            if (r < N) {
                if (isbf) {
                    const unsigned short* xb = (const unsigned short*)xv;
                    uint4 raw = *(const uint4*)(xb + (size_t)r * D + kc + kq);
                    unsigned int ws[4] = {raw.x, raw.y, raw.z, raw.w};
#pragma unroll
                    for (int i = 0; i < 4; ++i) {
                        v[2 * i]     = bf2f((unsigned short)(ws[i] & 0xffffu));
                        v[2 * i + 1] = bf2f((unsigned short)(ws[i] >> 16));
                    }
                } else {
                    const float* xf = (const float*)xv;
                    const float4* p4 = (const float4*)(xf + (size_t)r * D + kc + kq);
                    float4 f0 = p4[0], f1 = p4[1];
                    v[0] = f0.x; v[1] = f0.y; v[2] = f0.z; v[3] = f0.w;
                    v[4] = f1.x; v[5] = f1.y; v[6] = f1.z; v[7] = f1.w;
                }
#pragma unroll
                for (int i = 0; i < 8; ++i) v[i] = eluf(v[i]);
            } else {
#pragma unroll
                for (int i = 0; i < 8; ++i) v[i] = 0.f;
            }
#pragma unroll
            for (int i = 0; i < 8; ++i) xs[row][kq + i] = v[i];
        }
#pragma unroll
        for (int i = 0; i < 2; ++i) {
            int f = (tid + i * 256) * 8;
            int k = f >> 7;
            int c = f & 127;
            float v[8];
            if (isbf) {
                const unsigned short* Wp = (c < 64)
                    ? ((const unsigned short*)Wsrc + (size_t)(kc + k) * 64 + c)
                    : ((const unsigned short*)Wdst + (size_t)(kc + k) * 64 + (c - 64));
                uint4 raw = *(const uint4*)Wp;
                unsigned int ws[4] = {raw.x, raw.y, raw.z, raw.w};
#pragma unroll
                for (int q = 0; q < 4; ++q) {
                    v[2 * q]     = bf2f((unsigned short)(ws[q] & 0xffffu));
                    v[2 * q + 1] = bf2f((unsigned short)(ws[q] >> 16));
                }
            } else {
                const float* Wp = (c < 64)
                    ? ((const float*)Wsrc + (size_t)(kc + k) * 64 + c)
                    : ((const float*)Wdst + (size_t)(kc + k) * 64 + (c - 64));
                const float4* p4 = (const float4*)Wp;
                float4 f0 = p4[0], f1 = p4[1];
                v[0] = f0.x; v[1] = f0.y; v[2] = f0.z; v[3] = f0.w;
                v[4] = f1.x; v[5] = f1.y; v[6] = f1.z; v[7] = f1.w;
            }
#pragma unroll
            for (int q = 0; q < 8; ++q) wt[k][c + q] = v[q];
        }
        __syncthreads();
#pragma unroll 8
        for (int k = 0; k < 32; ++k) {
            float xr[4];
#pragma unroll
            for (int r = 0; r < 4; ++r) xr[r] = xs[tcy * 4 + r][k];
            float4 w0 = *(const float4*)&wt[k][tcx * 8];
            float4 w1 = *(const float4*)&wt[k][tcx * 8 + 4];
#pragma unroll
            for (int r = 0; r < 4; ++r) {
                acc[r][0] += xr[r] * w0.x; acc[r][1] += xr[r] * w0.y;
                acc[r][2] += xr[r] * w0.z; acc[r][3] += xr[r] * w0.w;
                acc[r][4] += xr[r] * w1.x; acc[r][5] += xr[r] * w1.y;
                acc[r][6] += xr[r] * w1.z; acc[r][7] += xr[r] * w1.w;
            }
        }
        __syncthreads();
    }

    float attv[8];
#pragma unroll
    for (int q = 0; q < 8; ++q) {
        int c = tcx * 8 + q;
        if (isbf) attv[q] = (c < 64) ? bf2f(((const unsigned short*)att_src)[c])
                                     : bf2f(((const unsigned short*)att_dst)[c - 64]);
        else      attv[q] = (c < 64) ? ((const float*)att_src)[c]
                                     : ((const float*)att_dst)[c - 64];
    }

#pragma unroll
    for (int r = 0; r < 4; ++r) {
        int row = rowBase + tcy * 4 + r;
        bool ok = row < N;
        if (ok && tcx < 8) {
            __half* p = Pout + (size_t)row * 64 + tcx * 8;
#pragma unroll
            for (int q = 0; q < 8; ++q) p[q] = __float2half(acc[r][q]);
        }
        float part = 0.f;
#pragma unroll
        for (int q = 0; q < 8; ++q) part += acc[r][q] * attv[q];
        part += __shfl_xor(part, 1, 64);
        part += __shfl_xor(part, 2, 64);
        if (ok && (tcx & 3) == 0)
            ((float*)&avO[row])[tcx >> 2] = part;   // comp 0..3 = as0,as1,ad0,ad1
    }
}

// ---------- 2. global per-(dir,head) max of as (av .x/.y) ----------
__global__ __launch_bounds__(256) void gmax_kernel(
    const float4* __restrict__ av, unsigned int* __restrict__ gmax, int N)
{
    unsigned int k0 = 0, k1 = 0, k2 = 0, k3 = 0;
    const int total = 2 * N;
    for (int i = blockIdx.x * 256 + threadIdx.x; i < total; i += gridDim.x * 256) {
        float4 v = av[i];
        unsigned int ex = fenc(v.x), ey = fenc(v.y);
        if (i < N) { k0 = max(k0, ex); k1 = max(k1, ey); }
        else       { k2 = max(k2, ex); k3 = max(k3, ey); }
    }
#pragma unroll
    for (int o = 32; o >= 1; o >>= 1) {
        k0 = max(k0, (unsigned int)__shfl_xor((int)k0, o, 64));
        k1 = max(k1, (unsigned int)__shfl_xor((int)k1, o, 64));
        k2 = max(k2, (unsigned int)__shfl_xor((int)k2, o, 64));
        k3 = max(k3, (unsigned int)__shfl_xor((int)k3, o, 64));
    }
    if ((threadIdx.x & 63) == 0) {
        atomicMax(&gmax[0], k0);
        atomicMax(&gmax[1], k1);
        atomicMax(&gmax[2], k2);
        atomicMax(&gmax[3], k3);
    }
}

// ---------- 3a. degree histogram + rank capture + enrichment sums (fused) ----------
// rank[e] = {rank within dst-list of dste[e], rank within src-list of srce[e]}
__global__ __launch_bounds__(256) void count_kernel(
    const int* __restrict__ srce, const int* __restrict__ dste,
    int* __restrict__ cnt, int2* __restrict__ rank,
    const void* __restrict__ ew, const int* __restrict__ flag,
    float* __restrict__ S, int N, int E)
{
    __shared__ float r1s[4], r2s[4];
    const int isbf = *flag;
    int e = blockIdx.x * 256 + threadIdx.x;
    float e1 = 0.f, e2 = 0.f;
    if (e < E) {
        int s = srce[e], d = dste[e];
        int r1 = atomicAdd(&cnt[d], 1);
        int r2 = atomicAdd(&cnt[N + s], 1);
        rank[e] = make_int2(r1, r2);
        float c = isbf ? bf2f(((const unsigned short*)ew)[e]) : ((const float*)ew)[e];
        c = fminf(fmaxf(c, 0.3f), 3.0f);
        float ex = __expf(c);
        e1 = ex;
        e2 = c * ex;
    }
#pragma unroll
    for (int o = 32; o >= 1; o >>= 1) {
        e1 += __shfl_down(e1, o, 64);
        e2 += __shfl_down(e2, o, 64);
    }
    int lane = threadIdx.x & 63;
    int wv = threadIdx.x >> 6;
    if (lane == 0) { r1s[wv] = e1; r2s[wv] = e2; }
    __syncthreads();
    if (threadIdx.x == 0) {
        atomicAdd(&S[0], r1s[0] + r1s[1] + r1s[2] + r1s[3]);
        atomicAdd(&S[1], r2s[0] + r2s[1] + r2s[2] + r2s[3]);
    }
}

// ---------- 3b. multi-block scan: stage 1 ----------
__global__ __launch_bounds__(256) void scan_bsum_kernel(
    const int* __restrict__ cnt, int M, int chunk, int* __restrict__ bsum)
{
    __shared__ int r[4];
    int beg = blockIdx.x * chunk;
    int end = beg + chunk; if (end > M) end = M;
    int s = 0;
    for (int i = beg + threadIdx.x; i < end; i += 256) s += cnt[i];
#pragma unroll
    for (int o = 32; o >= 1; o >>= 1) s += __shfl_down(s, o, 64);
    int lane = threadIdx.x & 63, wv = threadIdx.x >> 6;
    if (lane == 0) r[wv] = s;
    __syncthreads();
    if (threadIdx.x == 0) bsum[blockIdx.x] = r[0] + r[1] + r[2] + r[3];
}

// ---------- stage 2 ----------
__global__ __launch_bounds__(256) void scan_boff_kernel(
    const int* __restrict__ bsum, int NB, int* __restrict__ boff)
{
    __shared__ int s[256];
    int t = threadIdx.x;
    int v = (t < NB) ? bsum[t] : 0;
    s[t] = v;
    __syncthreads();
    for (int o = 1; o < 256; o <<= 1) {
        int x = (t >= o) ? s[t - o] : 0;
        __syncthreads();
        s[t] += x;
        __syncthreads();
    }
    if (t < NB) boff[t] = s[t] - v;
}

// ---------- stage 3 ----------
__global__ __launch_bounds__(256) void scan_write_kernel(
    const int* __restrict__ cnt, int M, int chunk,
    const int* __restrict__ boff, int* __restrict__ off)
{
    __shared__ int s[256];
    int t = threadIdx.x;
    int beg = blockIdx.x * chunk;
    int end = beg + chunk; if (end > M) end = M;
    if (beg >= M) return;
    int running = boff[blockIdx.x];
    for (int base = beg; base < end; base += 256) {
        int i = base + t;
        int v = (i < end) ? cnt[i] : 0;
        s[t] = v;
        __syncthreads();
        for (int o = 1; o < 256; o <<= 1) {
            int x = (t >= o) ? s[t - o] : 0;
            __syncthreads();
            s[t] += x;
            __syncthreads();
        }
        if (i < end) off[i] = running + s[t] - v;
        int total = s[255];
        __syncthreads();
        running += total;
    }
    if (end == M && t == 0) off[M] = running;
}

// ---------- 3c. CSR fill + per-edge softmax weights (atomic-free, 8B slots) ----------
// epack[slot] = {src, half2(p_h0, p_h1)}
__global__ void fill_kernel(const int* __restrict__ srce, const int* __restrict__ dste,
                            const int* __restrict__ off, const int2* __restrict__ rank,
                            const float4* __restrict__ av,
                            const unsigned int* __restrict__ gmax,
                            int2* __restrict__ epack, int N, int E)
{
    int e = blockIdx.x * blockDim.x + threadIdx.x;
    if (e >= E) return;
    int s = srce[e], d = dste[e];
    int2 rk = rank[e];
    float4 ah = av[s];          // h-side of s: as0,as1,ad0,ad1
    float4 at = av[N + d];      // t-side of d
    float gm00 = fdec(gmax[0]), gm01 = fdec(gmax[1]);
    float gm10 = fdec(gmax[2]), gm11 = fdec(gmax[3]);
    // dir0 (h->t): src as_h[s], dst ad_t[d]; m = lrelu(gm0 + adv)
    float p00 = __expf(lrelu(ah.x + at.z) - lrelu(gm00 + at.z));
    float p01 = __expf(lrelu(ah.y + at.w) - lrelu(gm01 + at.w));
    // dir1 (t->h): src as_t[d], dst ad_h[s]; m = lrelu(gm1 + adv)
    float p10 = __expf(lrelu(at.x + ah.z) - lrelu(gm10 + ah.z));
    float p11 = __expf(lrelu(at.y + ah.w) - lrelu(gm11 + ah.w));
    epack[off[d] + rk.x]     = make_int2(s, (int)packh2(p00, p01));
    epack[off[N + s] + rk.y] = make_int2(d, (int)packh2(p10, p11));
}

// ---------- 5. aggregation with precomputed fp16 weights, both dirs ----------
__global__ __launch_bounds__(256) void agg_kernel(
    const int* __restrict__ off, const int2* __restrict__ epack,
    const float4* __restrict__ av, const __half* __restrict__ Pall,
    const void* __restrict__ bias,
    const float* __restrict__ S,
    const unsigned int* __restrict__ gmax,
    const void* __restrict__ esc,
    const int* __restrict__ flag,
    void* __restrict__ out, int N)
{
    const int isbf = *flag;
    int q = (blockIdx.x * 256 + threadIdx.x) >> 6;
    int lane = threadIdx.x & 63;     // lane = h*32 + c
    if (q >= 2 * N) return;
    int dir = (q >= N) ? 1 : 0;
    int n = q - dir * N;
    const __half* Psrc = Pall + (size_t)dir * (size_t)N * 64u;
    size_t outOff = dir ? 0u : (size_t)N * 64u;
    const int hi = lane >> 5;
    const int sh = hi << 4;          // 0 or 16: which half of the packed weight
    const int jb = off[q], je = off[q + 1];

    // self-loop
    float4 asrc = av[(size_t)dir * N + n];        // src-side row of n
    float4 adst = av[(size_t)(1 - dir) * N + n];  // dst-side row of n
    const float adv = hi ? adst.w : adst.z;
    const float m   = lrelu(fdec(gmax[dir * 2 + hi]) + adv);
    const float pSelf = __expf(lrelu((hi ? asrc.y : asrc.x) + adv) - m);

    float z0 = pSelf, z1 = 0.f, z2 = 0.f, z3 = 0.f;
    float a0 = pSelf * __half2float(Psrc[(size_t)n * 64 + lane]);
    float a1 = 0.f, a2 = 0.f, a3 = 0.f;

    int j = jb;
    for (; j + 3 < je; j += 4) {
        int2 e0 = epack[j], e1 = epack[j + 1], e2 = epack[j + 2], e3 = epack[j + 3];
        float h0 = __half2float(Psrc[(size_t)e0.x * 64 + lane]);
        float h1 = __half2float(Psrc[(size_t)e1.x * 64 + lane]);
        float h2 = __half2float(Psrc[(size_t)e2.x * 64 + lane]);
        float h3 = __half2float(Psrc[(size_t)e3.x * 64 + lane]);
        float p0 = __half2float(__ushort_as_half((unsigned short)(((unsigned int)e0.y) >> sh)));
        float p1 = __half2float(__ushort_as_half((unsigned short)(((unsigned int)e1.y) >> sh)));
        float p2 = __half2float(__ushort_as_half((unsigned short)(((unsigned int)e2.y) >> sh)));
        float p3 = __half2float(__ushort_as_half((unsigned short)(((unsigned int)e3.y) >> sh)));
        z0 += p0; a0 = fmaf(p0, h0, a0);
        z1 += p1; a1 = fmaf(p1, h1, a1);
        z2 += p2; a2 = fmaf(p2, h2, a2);
        z3 += p3; a3 = fmaf(p3, h3, a3);
    }
    for (; j < je; ++j) {
        int2 e0 = epack[j];
        float h0 = __half2float(Psrc[(size_t)e0.x * 64 + lane]);
        float p0 = __half2float(__ushort_as_half((unsigned short)(((unsigned int)e0.y) >> sh)));
        z0 += p0; a0 = fmaf(p0, h0, a0);
    }
    float z   = (z0 + z1) + (z2 + z3);
    float acc = (a0 + a1) + (a2 + a3);

    float escv = isbf ? bf2f(((const unsigned short*)esc)[0]) : ((const float*)esc)[0];
    float bv   = isbf ? bf2f(((const unsigned short*)bias)[lane]) : ((const float*)bias)[lane];
    float weighted = S[1] / S[0];
    float factor = 1.f + 0.5f * tanhf(escv) * (weighted - 1.f);
    float o = (acc / (z + 1e-16f) + bv) * factor;
    size_t oi = outOff + (size_t)n * 64 + lane;
    if (isbf) ((unsigned short*)out)[oi] = f2bf(o);
    else      ((float*)out)[oi] = o;
}

extern "C" void kernel_launch(void* const* d_in, const int* in_sizes, int n_in,
                              void* d_out, int out_size, void* d_ws, size_t ws_size,
                              hipStream_t stream)
{
    const void* hx      = d_in[0];
    const void* tx      = d_in[1];
    const int*  eidx    = (const int*)d_in[2];
    const void* ew      = d_in[3];
    const void* Wsrc    = d_in[4];
    const void* Wdst    = d_in[5];
    const void* att_src = d_in[6];
    const void* att_dst = d_in[7];
    const void* bias    = d_in[8];
    const void* esc     = d_in[9];

    const int HC = in_sizes[6];       // 64
    const int D  = in_sizes[4] / HC;  // 256
    const int N  = in_sizes[0] / D;   // 100000
    const int E  = in_sizes[3];       // 1600000
    const int* srce = eidx;
    const int* dste = eidx + E;

    const bool canM = (D == 256) && (HC == 64);

    char* wsb = (char*)d_ws;
    size_t o = 0;
    auto alloc = [&](size_t bytes) -> void* {
        void* p = wsb + o;
        o += (bytes + 255) & ~(size_t)255;
        return p;
    };
    __half* Pall  = (__half*)alloc((size_t)2 * N * 64 * 2);   // [Ph; Pt] hs-only, fp16
    float4* av    = (float4*)alloc((size_t)2 * N * 16);       // packed as/ad per node
    float* S      = (float*)alloc(2 * 4);
    unsigned int* gmax = (unsigned int*)alloc(4 * 4);
    int*   cnt    = (int*)alloc((size_t)2 * N * 4);
    int*   offp   = (int*)alloc(((size_t)2 * N + 1) * 4);
    int2*  rank   = (int2*)alloc((size_t)E * 8);
    int2*  epack  = (int2*)alloc((size_t)2 * E * 8);
    int*   flag   = (int*)alloc(256);
    int*   bsum   = (int*)alloc(256 * 4);
    int*   boff   = (int*)alloc(256 * 4);
    unsigned short* Whi = (unsigned short*)alloc((size_t)8 * 8 * 64 * 8 * 2);  // 64KB
    unsigned short* Wlo = (unsigned short*)alloc((size_t)8 * 8 * 64 * 8 * 2);  // 64KB

    hipMemsetAsync(cnt, 0, (size_t)2 * N * 4, stream);
    hipMemsetAsync(S, 0, 2 * 4, stream);
    hipMemsetAsync(gmax, 0, 4 * 4, stream);

    detect_kernel<<<1, 256, 0, stream>>>((const unsigned int*)hx, 65536, flag);

    dim3 gGemm((N + 63) / 64, 2);
    if (canM) {
        wfrag_kernel<<<16, 256, 0, stream>>>(Wsrc, Wdst, flag, Whi, Wlo);
        gemm_fused_kernel<<<gGemm, 256, 0, stream>>>(hx, tx, Whi, Wlo,
                                                     att_src, att_dst, flag,
                                                     Pall, av, N);
    } else {
        gemm_elu_kernel<<<gGemm, 256, 0, stream>>>(hx, tx, Wsrc, Wdst, att_src, att_dst,
                                                   flag, Pall, av, N, D);
    }
    gmax_kernel<<<256, 256, 0, stream>>>(av, gmax, N);
    count_kernel<<<(E + 255) / 256, 256, 0, stream>>>(srce, dste, cnt, rank,
                                                      ew, flag, S, N, E);

    const int M = 2 * N;
    int chunk = (M + 255) / 256;
    chunk = (chunk + 255) & ~255;
    const int NB = (M + chunk - 1) / chunk;
    scan_bsum_kernel<<<NB, 256, 0, stream>>>(cnt, M, chunk, bsum);
    scan_boff_kernel<<<1, 256, 0, stream>>>(bsum, NB, boff);
    scan_write_kernel<<<NB, 256, 0, stream>>>(cnt, M, chunk, boff, offp);

    fill_kernel<<<(E + 255) / 256, 256, 0, stream>>>(srce, dste, offp, rank,
                                                     av, gmax, epack, N, E);

    agg_kernel<<<(2 * N + 3) / 4, 256, 0, stream>>>(offp, epack, av,
                                                    Pall, bias, S, gmax, esc, flag,
                                                    d_out, N);
}